// Round 2
// baseline (26627.081 us; speedup 1.0000x reference)
//
#include <hip/hip_runtime.h>
#include <math.h>

#define L4 4096

// ---------------- weight pack: wT[(i*3+k)*256 + o] = cw[o][i][1][k] ----------------
__global__ __launch_bounds__(256) void pack_w_kernel(const float* __restrict__ cw,
                                                     float* __restrict__ wT) {
  int idx = blockIdx.x * 256 + threadIdx.x;
  if (idx >= 257 * 3 * 256) return;
  int o = idx & 255;
  int rem = idx >> 8;          // i*3 + k
  int k = rem % 3;
  int i = rem / 3;
  wT[idx] = cw[(size_t)(o * 257 + i) * 9 + 3 + k];
}

// ---------------- stem conv1: 4 -> 64, k=3, pad 1 ----------------
__global__ __launch_bounds__(256) void conv1_kernel(const float* __restrict__ x,
                                                    const float* __restrict__ w,
                                                    const float* __restrict__ bias,
                                                    float* __restrict__ out) {
  int idx = blockIdx.x * 256 + threadIdx.x;  // 16*64*4096
  int l = idx & 4095;
  int c = (idx >> 12) & 63;
  int b = idx >> 18;
  const float* xb = x + (size_t)b * 4 * L4;
  const float* wc = w + c * 12;
  float acc = bias[c];
#pragma unroll
  for (int i = 0; i < 4; i++) {
    float x0 = (l > 0) ? xb[i * L4 + l - 1] : 0.f;
    float x1 = xb[i * L4 + l];
    float x2 = (l < 4095) ? xb[i * L4 + l + 1] : 0.f;
    acc += wc[i * 3] * x0 + wc[i * 3 + 1] * x1 + wc[i * 3 + 2] * x2;
  }
  out[idx] = acc;
}

// ---------------- stem conv2: 64 -> 256, k=3, pad 1 ----------------
__global__ __launch_bounds__(256) void conv2_kernel(const float* __restrict__ in,
                                                    const float* __restrict__ w,
                                                    const float* __restrict__ bias,
                                                    float* __restrict__ out) {
  int idx = blockIdx.x * 256 + threadIdx.x;  // 16*256*4096
  int l = idx & 4095;
  int o = (idx >> 12) & 255;
  int b = idx >> 20;
  const float* inb = in + (size_t)b * 64 * L4;
  const float* wo = w + o * 192;
  float acc = bias[o];
  for (int i = 0; i < 64; i++) {
    float x0 = (l > 0) ? inb[i * L4 + l - 1] : 0.f;
    float x1 = inb[i * L4 + l];
    float x2 = (l < 4095) ? inb[i * L4 + l + 1] : 0.f;
    acc += wo[i * 3] * x0 + wo[i * 3 + 1] * x1 + wo[i * 3 + 2] * x2;
  }
  out[idx] = acc;
}

// ---------------- generic mean/rstd stats (one block per unit) ----------------
__global__ __launch_bounds__(256) void stats_kernel(const float* __restrict__ in,
                                                    float* __restrict__ stats,
                                                    int unit_stride, int nrow,
                                                    int row_stride, int rowlen,
                                                    float inv_n) {
  int u = blockIdx.x;
  const float* base = in + (size_t)u * unit_stride;
  float s = 0.f, s2 = 0.f;
  for (int r = 0; r < nrow; r++) {
    const float* rowp = base + (size_t)r * row_stride;
    for (int j = threadIdx.x * 4; j < rowlen; j += 256 * 4) {
      float4 v = *(const float4*)(rowp + j);
      s += v.x + v.y + v.z + v.w;
      s2 += v.x * v.x + v.y * v.y + v.z * v.z + v.w * v.w;
    }
  }
  __shared__ float sh[512];
  sh[threadIdx.x] = s;
  sh[256 + threadIdx.x] = s2;
  __syncthreads();
  for (int off = 128; off > 0; off >>= 1) {
    if (threadIdx.x < off) {
      sh[threadIdx.x] += sh[threadIdx.x + off];
      sh[256 + threadIdx.x] += sh[256 + threadIdx.x + off];
    }
    __syncthreads();
  }
  if (threadIdx.x == 0) {
    float m = sh[0] * inv_n;
    float var = sh[256] * inv_n - m * m;
    stats[u * 2] = m;
    stats[u * 2 + 1] = rsqrtf(var + 1e-5f);
  }
}

// ---------------- BN apply: ACT 0=relu, 1=tanh (in/out may alias) ----------------
template <int ACT>
__global__ __launch_bounds__(256) void bn_apply(const float* __restrict__ in,
                                                const float* __restrict__ stats,
                                                const float* __restrict__ gamma,
                                                const float* __restrict__ beta,
                                                float* __restrict__ out, int cmask) {
  int idx4 = blockIdx.x * 256 + threadIdx.x;
  int flat = idx4 << 2;
  int c = (flat >> 12) & cmask;
  float m = stats[2 * c], rs = stats[2 * c + 1];
  float ga = gamma[c] * rs, be = beta[c] - m * ga;
  float4 v = ((const float4*)in)[idx4];
  float4 r;
  float a;
  a = v.x * ga + be; r.x = (ACT == 0) ? fmaxf(a, 0.f) : tanhf(a);
  a = v.y * ga + be; r.y = (ACT == 0) ? fmaxf(a, 0.f) : tanhf(a);
  a = v.z * ga + be; r.z = (ACT == 0) ? fmaxf(a, 0.f) : tanhf(a);
  a = v.w * ga + be; r.w = (ACT == 0) ? fmaxf(a, 0.f) : tanhf(a);
  ((float4*)out)[idx4] = r;
}

// ---------------- GN3 + predictor: fv=affine(conv2out); conv2out<-y+h*fv; y<-y+h/2*fv ----
__global__ __launch_bounds__(256) void pred_combine(float* __restrict__ convout,
                                                    const float* __restrict__ stats,
                                                    const float* __restrict__ gamma,
                                                    const float* __restrict__ beta,
                                                    float* __restrict__ y) {
  int idx4 = blockIdx.x * 256 + threadIdx.x;
  int flat = idx4 << 2;
  int c = (flat >> 12) & 255;
  int b = flat >> 20;
  int grp = (b << 5) + (c >> 3);
  float m = stats[2 * grp], rs = stats[2 * grp + 1];
  float ga = gamma[c] * rs, be = beta[c] - m * ga;
  float4 v = ((const float4*)convout)[idx4];
  float4 yv = ((const float4*)y)[idx4];
  float4 yn, yb;
  float f;
  f = v.x * ga + be; yn.x = yv.x + 0.125f * f; yb.x = yv.x + 0.0625f * f;
  f = v.y * ga + be; yn.y = yv.y + 0.125f * f; yb.y = yv.y + 0.0625f * f;
  f = v.z * ga + be; yn.z = yv.z + 0.125f * f; yb.z = yv.z + 0.0625f * f;
  f = v.w * ga + be; yn.w = yv.w + 0.125f * f; yb.w = yv.w + 0.0625f * f;
  ((float4*)convout)[idx4] = yn;   // y1 (next f-eval input)
  ((float4*)y)[idx4] = yb;         // ybase = y + h/2*f0
}

// ---------------- GN3 + corrector: conv2out <- ybase + h/2*affine(conv2out) ----------
__global__ __launch_bounds__(256) void corr_combine(float* __restrict__ convout,
                                                    const float* __restrict__ stats,
                                                    const float* __restrict__ gamma,
                                                    const float* __restrict__ beta,
                                                    const float* __restrict__ ybase) {
  int idx4 = blockIdx.x * 256 + threadIdx.x;
  int flat = idx4 << 2;
  int c = (flat >> 12) & 255;
  int b = flat >> 20;
  int grp = (b << 5) + (c >> 3);
  float m = stats[2 * grp], rs = stats[2 * grp + 1];
  float ga = gamma[c] * rs, be = beta[c] - m * ga;
  float4 v = ((const float4*)convout)[idx4];
  float4 yb = ((const float4*)ybase)[idx4];
  float4 yn;
  yn.x = yb.x + 0.0625f * (v.x * ga + be);
  yn.y = yb.y + 0.0625f * (v.y * ga + be);
  yn.z = yb.z + 0.0625f * (v.z * ga + be);
  yn.w = yb.w + 0.0625f * (v.w * ga + be);
  ((float4*)convout)[idx4] = yn;
}

// ---------------- big conv with fused input GN(affine)+activation ----------------
// ACT: 0 = relu, 1 = elu. Input is PRE-GroupNorm; stats/gamma/beta applied on staging.
// Zero padding is applied AFTER activation (true zeros at sequence edges).
// grid: (1024 position tiles, 4 o-tiles); block 256. tile = 64 o x 64 l.
template <int ACT>
__global__ __launch_bounds__(256) void conv_big(const float* __restrict__ in,   // [16][256][4096]
                                                const float* __restrict__ stats,
                                                const float* __restrict__ gamma,
                                                const float* __restrict__ beta,
                                                const float* __restrict__ wT,   // [257][3][256]
                                                const float* __restrict__ bias, // [256]
                                                float tval,
                                                float* __restrict__ out) {
  int ptile = blockIdx.x;      // 0..1023
  int b = ptile >> 6;
  int l0 = (ptile & 63) << 6;
  int o_base = blockIdx.y << 6;

  __shared__ float xs[16][68];
  __shared__ float ws[16][3][64];

  int tid = threadIdx.x;
  int lo4 = (tid & 15) << 2;   // position offset 0..60 (fast across lanes -> coalesced stores)
  int oo = (tid >> 4) << 2;    // o offset 0..60

  float acc[4][4];
#pragma unroll
  for (int a = 0; a < 4; a++)
#pragma unroll
    for (int p = 0; p < 4; p++) acc[a][p] = 0.f;

  const float* inb = in + (size_t)b * 256 * L4;

  for (int ib = 0; ib < 256; ib += 16) {
    for (int idx = tid; idx < 16 * 66; idx += 256) {
      int i = idx / 66, j = idx % 66;
      int c = ib + i;
      int grp = (b << 5) + (c >> 3);
      float m = stats[2 * grp], rs = stats[2 * grp + 1];
      float ga = gamma[c] * rs, be = beta[c] - m * ga;
      int gl = l0 - 1 + j;
      float v = 0.f;
      if (gl >= 0 && gl < L4) {
        float a = inb[(size_t)c * L4 + gl] * ga + be;
        v = (ACT == 0) ? fmaxf(a, 0.f) : (a > 0.f ? a : expm1f(a));
      }
      xs[i][j] = v;
    }
    for (int idx = tid; idx < 16 * 192; idx += 256) {
      int i = idx / 192;
      int r = idx % 192;
      int k = r >> 6;
      int o = r & 63;
      ws[i][k][o] = wT[((size_t)(ib + i + 1) * 3 + k) * 256 + o_base + o];
    }
    __syncthreads();
#pragma unroll
    for (int i = 0; i < 16; i++) {
      float xv[6];
#pragma unroll
      for (int j = 0; j < 6; j++) xv[j] = xs[i][lo4 + j];
#pragma unroll
      for (int k = 0; k < 3; k++) {
        float w0 = ws[i][k][oo], w1 = ws[i][k][oo + 1];
        float w2 = ws[i][k][oo + 2], w3 = ws[i][k][oo + 3];
#pragma unroll
        for (int p = 0; p < 4; p++) {
          float xvv = xv[p + k];
          acc[0][p] += w0 * xvv;
          acc[1][p] += w1 * xvv;
          acc[2][p] += w2 * xvv;
          acc[3][p] += w3 * xvv;
        }
      }
    }
    __syncthreads();
  }

#pragma unroll
  for (int a = 0; a < 4; a++) {
    int o = o_base + oo + a;
    float w00 = wT[0 * 256 + o];   // t-channel, k=0
    float w01 = wT[1 * 256 + o];   // k=1
    float w02 = wT[2 * 256 + o];   // k=2
    float base = bias[o];
    float4 res;
    float* rp = &res.x;
#pragma unroll
    for (int p = 0; p < 4; p++) {
      int l = l0 + lo4 + p;
      float tc = w01 + (l > 0 ? w00 : 0.f) + (l < L4 - 1 ? w02 : 0.f);
      rp[p] = acc[a][p] + base + tval * tc;
    }
    *(float4*)&out[((size_t)b * 256 + o) * L4 + l0 + lo4] = res;
  }
}

extern "C" void kernel_launch(void* const* d_in, const int* in_sizes, int n_in,
                              void* d_out, int out_size, void* d_ws, size_t ws_size,
                              hipStream_t stream) {
  const float* x = (const float*)d_in[0];
  const float* w1 = (const float*)d_in[1];
  const float* b1 = (const float*)d_in[2];
  const float* bn1_g = (const float*)d_in[3];
  const float* bn1_b = (const float*)d_in[4];
  const float* w2 = (const float*)d_in[5];
  const float* b2 = (const float*)d_in[6];
  const float* bn2_g = (const float*)d_in[7];
  const float* bn2_b = (const float*)d_in[8];
  const float* cw1 = (const float*)d_in[9];
  const float* cb1 = (const float*)d_in[10];
  const float* gn1_g = (const float*)d_in[11];
  const float* gn1_b = (const float*)d_in[12];
  const float* gn2_g = (const float*)d_in[13];
  const float* gn2_b = (const float*)d_in[14];
  const float* cw2 = (const float*)d_in[15];
  const float* cb2 = (const float*)d_in[16];
  const float* gn3_g = (const float*)d_in[17];
  const float* gn3_b = (const float*)d_in[18];

  float* out = (float*)d_out;
  float* ws = (float*)d_ws;

  const size_t SZ = (size_t)16 * 256 * 4096;      // 16,777,216 floats (64 MB)
  float* A = ws;                                   // temp (conv1 output)
  float* Q = ws + SZ;                              // ping-pong partner of d_out
  float* WT1 = ws + 2 * SZ;
  float* WT2 = WT1 + 257 * 3 * 256;
  float* STATS = WT2 + 257 * 3 * 256;
  // total ws use: 2*SZ + 2*197376 + 1024 floats  ~= 136 MB

  const int EW_BLOCKS = (int)(SZ / 4 / 256);      // 16384 (float4 elementwise over SZ)

  // ---- pack conv weights (middle 3x3 row, transposed for coalesced LDS staging) ----
  pack_w_kernel<<<771, 256, 0, stream>>>(cw1, WT1);
  pack_w_kernel<<<771, 256, 0, stream>>>(cw2, WT2);

  // ---- stem ----
  conv1_kernel<<<16384, 256, 0, stream>>>(x, w1, b1, A);
  stats_kernel<<<64, 256, 0, stream>>>(A, STATS, 4096, 16, 64 * 4096, 4096, 1.f / 65536.f);
  bn_apply<0><<<4096, 256, 0, stream>>>(A, STATS, bn1_g, bn1_b, A, 63);
  conv2_kernel<<<65536, 256, 0, stream>>>(A, w2, b2, Q);
  stats_kernel<<<256, 256, 0, stream>>>(Q, STATS, 4096, 16, 256 * 4096, 4096, 1.f / 65536.f);
  bn_apply<1><<<16384, 256, 0, stream>>>(Q, STATS, bn2_g, bn2_b, out, 255);

  // ---- ODE: 8 steps, predictor + 2 correctors ----
  // f-eval front (input xin pre-GN1): GN1 stats -> conv1(fused relu) -> GN2 stats ->
  // conv2(fused elu) -> GN3 stats. conv2 output lands in `dst`.
  auto run_f_front = [&](const float* xin, float* dst, float tval) {
    stats_kernel<<<512, 256, 0, stream>>>(xin, STATS, 32768, 1, 0, 32768, 1.f / 32768.f);
    conv_big<0><<<dim3(1024, 4), 256, 0, stream>>>(xin, STATS, gn1_g, gn1_b, WT1, cb1, tval, A);
    stats_kernel<<<512, 256, 0, stream>>>(A, STATS, 32768, 1, 0, 32768, 1.f / 32768.f);
    conv_big<1><<<dim3(1024, 4), 256, 0, stream>>>(A, STATS, gn2_g, gn2_b, WT2, cb2, tval, dst);
    stats_kernel<<<512, 256, 0, stream>>>(dst, STATS, 32768, 1, 0, 32768, 1.f / 32768.f);
  };

  float* ycur = out;
  float* yoth = Q;
  const float H = 0.125f;
  for (int i = 0; i < 8; i++) {
    float t = i * H;
    // predictor: f0 = f(t,y); yoth <- y + h*f0; ycur <- ybase = y + h/2*f0
    run_f_front(ycur, yoth, t);
    pred_combine<<<EW_BLOCKS, 256, 0, stream>>>(yoth, STATS, gn3_g, gn3_b, ycur);
    // correctors: y1 <- ybase + h/2 * f(t+h, y1)
    for (int c = 0; c < 2; c++) {
      run_f_front(yoth, yoth, t + H);
      corr_combine<<<EW_BLOCKS, 256, 0, stream>>>(yoth, STATS, gn3_g, gn3_b, ycur);
    }
    float* tmp = ycur;   // new y is in yoth; old ycur (ybase) becomes scratch
    ycur = yoth;
    yoth = tmp;
  }
  // after 8 steps (even number of swaps) the final state is in d_out
}

// Round 3
// 6021.318 us; speedup vs baseline: 4.4221x; 4.4221x over previous
//
#include <hip/hip_runtime.h>
#include <math.h>

#define L4 4096

typedef short bf16x8 __attribute__((ext_vector_type(8)));
typedef float f32x4 __attribute__((ext_vector_type(4)));

__device__ __forceinline__ unsigned short f2bf(float f) {
  unsigned u = __builtin_bit_cast(unsigned, f);
  return (unsigned short)((u + 0x7FFFu + ((u >> 16) & 1u)) >> 16);
}
__device__ __forceinline__ float bf2f(unsigned short h) {
  unsigned u = ((unsigned)h) << 16;
  return __builtin_bit_cast(float, u);
}

// ---------------- pack big conv weights into A-fragment layout + t-channel ----------------
// Apack[((frow*24+ks)*64+lane)*8+e] = bf16(cw[o][i+1][1][tap]), o=frow*16+(lane&15),
// tap=ks>>3, i=(ks&7)*32+(lane>>4)*8+e.  Tpack[tap*256+o] = cw[o][0][1][tap] (fp32).
__global__ __launch_bounds__(256) void pack_big(const float* __restrict__ cw,
                                                unsigned short* __restrict__ Apack,
                                                float* __restrict__ Tpack) {
  int gid = blockIdx.x * 256 + threadIdx.x;
  if (gid < 768) {
    int o = gid & 255, tap = gid >> 8;
    Tpack[tap * 256 + o] = cw[((size_t)o * 257) * 9 + 3 + tap];
  }
  if (gid >= 16 * 24 * 64) return;
  int frow = gid / 1536;
  int rem = gid - frow * 1536;
  int ks = rem >> 6;
  int lane = rem & 63;
  int o = frow * 16 + (lane & 15);
  int tap = ks >> 3;
  int ib = ((ks & 7) << 5) + ((lane >> 4) << 3);
#pragma unroll
  for (int e = 0; e < 8; e++) {
    int i = ib + e;
    Apack[(size_t)gid * 8 + e] = f2bf(cw[((size_t)o * 257 + (i + 1)) * 9 + 3 + tap]);
  }
}

// ---------------- pack stem conv2 weights (64 in-ch, no t-channel) ----------------
__global__ __launch_bounds__(256) void pack_stem(const float* __restrict__ w2,
                                                 unsigned short* __restrict__ Apack) {
  int gid = blockIdx.x * 256 + threadIdx.x;
  if (gid >= 16 * 6 * 64) return;
  int frow = gid / 384;
  int rem = gid - frow * 384;
  int ks = rem >> 6;
  int lane = rem & 63;
  int o = frow * 16 + (lane & 15);
  int tap = ks >> 1;
  int ib = ((ks & 1) << 5) + ((lane >> 4) << 3);
#pragma unroll
  for (int e = 0; e < 8; e++) {
    int i = ib + e;
    Apack[(size_t)gid * 8 + e] = f2bf(w2[((size_t)o * 64 + i) * 3 + tap]);
  }
}

// ---------------- stem conv1: 4 -> 64, k=3, pad 1 (bf16 out) ----------------
__global__ __launch_bounds__(256) void conv1_kernel(const float* __restrict__ x,
                                                    const float* __restrict__ w,
                                                    const float* __restrict__ bias,
                                                    unsigned short* __restrict__ out) {
  int idx = blockIdx.x * 256 + threadIdx.x;  // 16*64*4096
  int l = idx & 4095;
  int c = (idx >> 12) & 63;
  int b = idx >> 18;
  const float* xb = x + (size_t)b * 4 * L4;
  const float* wc = w + c * 12;
  float acc = bias[c];
#pragma unroll
  for (int i = 0; i < 4; i++) {
    float x0 = (l > 0) ? xb[i * L4 + l - 1] : 0.f;
    float x1 = xb[i * L4 + l];
    float x2 = (l < 4095) ? xb[i * L4 + l + 1] : 0.f;
    acc += wc[i * 3] * x0 + wc[i * 3 + 1] * x1 + wc[i * 3 + 2] * x2;
  }
  out[idx] = f2bf(acc);
}

// ---------------- mean/rstd stats, fp32 input ----------------
__global__ __launch_bounds__(256) void stats_kernel(const float* __restrict__ in,
                                                    float* __restrict__ stats,
                                                    int unit_stride, int nrow,
                                                    int row_stride, int rowlen,
                                                    float inv_n) {
  int u = blockIdx.x;
  const float* base = in + (size_t)u * unit_stride;
  float s = 0.f, s2 = 0.f;
  for (int r = 0; r < nrow; r++) {
    const float* rowp = base + (size_t)r * row_stride;
    for (int j = threadIdx.x * 4; j < rowlen; j += 256 * 4) {
      float4 v = *(const float4*)(rowp + j);
      s += v.x + v.y + v.z + v.w;
      s2 += v.x * v.x + v.y * v.y + v.z * v.z + v.w * v.w;
    }
  }
  __shared__ float sh[512];
  sh[threadIdx.x] = s;
  sh[256 + threadIdx.x] = s2;
  __syncthreads();
  for (int off = 128; off > 0; off >>= 1) {
    if (threadIdx.x < off) {
      sh[threadIdx.x] += sh[threadIdx.x + off];
      sh[256 + threadIdx.x] += sh[256 + threadIdx.x + off];
    }
    __syncthreads();
  }
  if (threadIdx.x == 0) {
    float m = sh[0] * inv_n;
    float var = sh[256] * inv_n - m * m;
    stats[u * 2] = m;
    stats[u * 2 + 1] = rsqrtf(var + 1e-5f);
  }
}

// ---------------- mean/rstd stats, bf16 input ----------------
__global__ __launch_bounds__(256) void stats_bf16_kernel(const unsigned short* __restrict__ in,
                                                         float* __restrict__ stats,
                                                         int unit_stride, int nrow,
                                                         int row_stride, int rowlen,
                                                         float inv_n) {
  int u = blockIdx.x;
  const unsigned short* base = in + (size_t)u * unit_stride;
  float s = 0.f, s2 = 0.f;
  for (int r = 0; r < nrow; r++) {
    const unsigned short* rowp = base + (size_t)r * row_stride;
    for (int j = threadIdx.x * 4; j < rowlen; j += 256 * 4) {
      ushort4 v = *(const ushort4*)(rowp + j);
      float va = bf2f(v.x), vb = bf2f(v.y), vc = bf2f(v.z), vd = bf2f(v.w);
      s += va + vb + vc + vd;
      s2 += va * va + vb * vb + vc * vc + vd * vd;
    }
  }
  __shared__ float sh[512];
  sh[threadIdx.x] = s;
  sh[256 + threadIdx.x] = s2;
  __syncthreads();
  for (int off = 128; off > 0; off >>= 1) {
    if (threadIdx.x < off) {
      sh[threadIdx.x] += sh[threadIdx.x + off];
      sh[256 + threadIdx.x] += sh[256 + threadIdx.x + off];
    }
    __syncthreads();
  }
  if (threadIdx.x == 0) {
    float m = sh[0] * inv_n;
    float var = sh[256] * inv_n - m * m;
    stats[u * 2] = m;
    stats[u * 2 + 1] = rsqrtf(var + 1e-5f);
  }
}

// ---------------- BN apply, tanh ----------------
template <int ACT>
__global__ __launch_bounds__(256) void bn_apply(const float* __restrict__ in,
                                                const float* __restrict__ stats,
                                                const float* __restrict__ gamma,
                                                const float* __restrict__ beta,
                                                float* __restrict__ out, int cmask) {
  int idx4 = blockIdx.x * 256 + threadIdx.x;
  int flat = idx4 << 2;
  int c = (flat >> 12) & cmask;
  float m = stats[2 * c], rs = stats[2 * c + 1];
  float ga = gamma[c] * rs, be = beta[c] - m * ga;
  float4 v = ((const float4*)in)[idx4];
  float4 r;
  float a;
  a = v.x * ga + be; r.x = (ACT == 0) ? fmaxf(a, 0.f) : tanhf(a);
  a = v.y * ga + be; r.y = (ACT == 0) ? fmaxf(a, 0.f) : tanhf(a);
  a = v.z * ga + be; r.z = (ACT == 0) ? fmaxf(a, 0.f) : tanhf(a);
  a = v.w * ga + be; r.w = (ACT == 0) ? fmaxf(a, 0.f) : tanhf(a);
  ((float4*)out)[idx4] = r;
}

// ---------------- fused norm-affine + activation + bf16 + transpose ----------------
// in: [16][C][4096] (fp32 or bf16); out Xt: [16][4098][C] bf16, rows 0 & 4097 zero.
// SMODE 0: GN stats[b*32 + c/(C/32)] (C=256); SMODE 1: per-channel stats[c].
// ACT 0: relu, 1: elu.
template <int C, int SMODE, int ACT, bool INBF>
__global__ __launch_bounds__(256) void act_transpose(const void* __restrict__ inv,
                                                     const float* __restrict__ stats,
                                                     const float* __restrict__ gamma,
                                                     const float* __restrict__ beta,
                                                     unsigned short* __restrict__ Xt) {
  __shared__ unsigned short tile[64 * C];
  int bidx = blockIdx.x;
  int b = bidx >> 6;
  int lt = bidx & 63;
  int l0 = lt << 6;
  int t = threadIdx.x;
  int lanel = t & 63;
  int cq = t >> 6;
  for (int cp = 0; cp < C / 4; cp++) {
    int c = cp * 4 + cq;
    float m, rs;
    if (SMODE == 0) {
      int grp = (b << 5) + (c >> 3);
      m = stats[2 * grp]; rs = stats[2 * grp + 1];
    } else {
      m = stats[2 * c]; rs = stats[2 * c + 1];
    }
    float ga = gamma[c] * rs, be = beta[c] - m * ga;
    size_t gidx = ((size_t)b * C + c) * 4096 + l0 + lanel;
    float v = INBF ? bf2f(((const unsigned short*)inv)[gidx]) : ((const float*)inv)[gidx];
    float a = v * ga + be;
    float r = (ACT == 0) ? fmaxf(a, 0.f) : (a > 0.f ? a : expm1f(a));
    int sw = (C == 256) ? ((lanel & 31) << 3) : ((lanel & 15) << 2);
    tile[lanel * C + (c ^ sw)] = f2bf(r);
  }
  __syncthreads();
  constexpr int CH = C / 4;           // ushort4 chunks per row
  constexpr int RPP = 256 / CH;       // rows per pass
  for (int p = 0; p < 64 / RPP; p++) {
    int r = p * RPP + t / CH;
    int ch = t % CH;
    int sw = (C == 256) ? ((r & 31) << 3) : ((r & 15) << 2);
    ushort4 v = *(const ushort4*)&tile[r * C + ((ch * 4) ^ sw)];
    *(ushort4*)&Xt[((size_t)b * 4098 + 1 + l0 + r) * C + ch * 4] = v;
  }
  if (lt == 0) {
    if (t < C / 4) *(ushort4*)&Xt[((size_t)b * 4098 + 0) * C + t * 4] = make_ushort4(0, 0, 0, 0);
  } else if (lt == 63) {
    if (t < C / 4) *(ushort4*)&Xt[((size_t)b * 4098 + 4097) * C + t * 4] = make_ushort4(0, 0, 0, 0);
  }
}

// ---------------- MFMA conv-GEMM: out[b][o][l] = sum_{tap,i} W[o][i,tap]*Xt[b][l+tap][i] ----
// block = 256 thr (4 waves), tile 128o x 128l; wave = 64o x 64l = 4x4 frags of 16x16.
// grid: (16b * 32 ltiles, 2 otiles).
template <int NKS, int KLG, int CIN, bool TCH, bool OBF>
__global__ __launch_bounds__(256) void gemm_conv(const unsigned short* __restrict__ Xt,
                                                 const unsigned short* __restrict__ Apack,
                                                 const float* __restrict__ Tpack,
                                                 const float* __restrict__ bias,
                                                 float tval,
                                                 void* __restrict__ outv) {
  int tid = threadIdx.x;
  int lane = tid & 63;
  int wv = tid >> 6;
  int b = blockIdx.x >> 5;
  int l_base = (blockIdx.x & 31) << 7;
  int o_base = blockIdx.y << 7;
  int wo0 = (wv >> 1) << 6;
  int wl0 = (wv & 1) << 6;
  int col = lane & 15;
  int grp = lane >> 4;

  const unsigned short* xb = Xt + (size_t)b * 4098 * CIN;
  int frow0 = (o_base + wo0) >> 4;
  int lrow = l_base + wl0 + col;

  f32x4 acc[4][4];
#pragma unroll
  for (int i = 0; i < 4; i++)
#pragma unroll
    for (int j = 0; j < 4; j++) acc[i][j] = (f32x4){0.f, 0.f, 0.f, 0.f};

  for (int ks = 0; ks < NKS; ks++) {
    int tap = ks >> KLG;
    int i0 = (ks & ((1 << KLG) - 1)) << 5;
    const unsigned short* bb = xb + (size_t)(lrow + tap) * CIN + i0 + grp * 8;
    bf16x8 bfr[4], afr[4];
#pragma unroll
    for (int fc = 0; fc < 4; fc++) bfr[fc] = *(const bf16x8*)(bb + (size_t)fc * 16 * CIN);
#pragma unroll
    for (int fo = 0; fo < 4; fo++)
      afr[fo] = *(const bf16x8*)(Apack + ((((size_t)(frow0 + fo)) * NKS + ks) * 64 + lane) * 8);
#pragma unroll
    for (int fo = 0; fo < 4; fo++)
#pragma unroll
      for (int fc = 0; fc < 4; fc++)
        acc[fo][fc] = __builtin_amdgcn_mfma_f32_16x16x32_bf16(afr[fo], bfr[fc], acc[fo][fc], 0, 0, 0);
  }

#pragma unroll
  for (int fo = 0; fo < 4; fo++) {
#pragma unroll
    for (int r = 0; r < 4; r++) {
      int o = o_base + wo0 + fo * 16 + grp * 4 + r;
      float bs = bias[o];
      float w0t = 0.f, w1t = 0.f, w2t = 0.f;
      if (TCH) { w0t = Tpack[o]; w1t = Tpack[256 + o]; w2t = Tpack[512 + o]; }
#pragma unroll
      for (int fc = 0; fc < 4; fc++) {
        int l = l_base + wl0 + fc * 16 + col;
        float v = acc[fo][fc][r] + bs;
        if (TCH) {
          float tc = w1t + (l > 0 ? w0t : 0.f) + (l < 4095 ? w2t : 0.f);
          v += tval * tc;
        }
        size_t oi = ((size_t)b * 256 + o) * 4096 + l;
        if (OBF) ((unsigned short*)outv)[oi] = f2bf(v);
        else ((float*)outv)[oi] = v;
      }
    }
  }
}

// ---------------- GN3 + predictor: convout<-y+h*f; y<-y+h/2*f ----------------
__global__ __launch_bounds__(256) void pred_combine(float* __restrict__ convout,
                                                    const float* __restrict__ stats,
                                                    const float* __restrict__ gamma,
                                                    const float* __restrict__ beta,
                                                    float* __restrict__ y) {
  int idx4 = blockIdx.x * 256 + threadIdx.x;
  int flat = idx4 << 2;
  int c = (flat >> 12) & 255;
  int b = flat >> 20;
  int grp = (b << 5) + (c >> 3);
  float m = stats[2 * grp], rs = stats[2 * grp + 1];
  float ga = gamma[c] * rs, be = beta[c] - m * ga;
  float4 v = ((const float4*)convout)[idx4];
  float4 yv = ((const float4*)y)[idx4];
  float4 yn, yb;
  float f;
  f = v.x * ga + be; yn.x = yv.x + 0.125f * f; yb.x = yv.x + 0.0625f * f;
  f = v.y * ga + be; yn.y = yv.y + 0.125f * f; yb.y = yv.y + 0.0625f * f;
  f = v.z * ga + be; yn.z = yv.z + 0.125f * f; yb.z = yv.z + 0.0625f * f;
  f = v.w * ga + be; yn.w = yv.w + 0.125f * f; yb.w = yv.w + 0.0625f * f;
  ((float4*)convout)[idx4] = yn;
  ((float4*)y)[idx4] = yb;
}

// ---------------- GN3 + corrector: convout <- ybase + h/2*affine(convout) ----------------
__global__ __launch_bounds__(256) void corr_combine(float* __restrict__ convout,
                                                    const float* __restrict__ stats,
                                                    const float* __restrict__ gamma,
                                                    const float* __restrict__ beta,
                                                    const float* __restrict__ ybase) {
  int idx4 = blockIdx.x * 256 + threadIdx.x;
  int flat = idx4 << 2;
  int c = (flat >> 12) & 255;
  int b = flat >> 20;
  int grp = (b << 5) + (c >> 3);
  float m = stats[2 * grp], rs = stats[2 * grp + 1];
  float ga = gamma[c] * rs, be = beta[c] - m * ga;
  float4 v = ((const float4*)convout)[idx4];
  float4 yb = ((const float4*)ybase)[idx4];
  float4 yn;
  yn.x = yb.x + 0.0625f * (v.x * ga + be);
  yn.y = yb.y + 0.0625f * (v.y * ga + be);
  yn.z = yb.z + 0.0625f * (v.z * ga + be);
  yn.w = yb.w + 0.0625f * (v.w * ga + be);
  ((float4*)convout)[idx4] = yn;
}

extern "C" void kernel_launch(void* const* d_in, const int* in_sizes, int n_in,
                              void* d_out, int out_size, void* d_ws, size_t ws_size,
                              hipStream_t stream) {
  const float* x = (const float*)d_in[0];
  const float* w1 = (const float*)d_in[1];
  const float* b1 = (const float*)d_in[2];
  const float* bn1_g = (const float*)d_in[3];
  const float* bn1_b = (const float*)d_in[4];
  const float* w2 = (const float*)d_in[5];
  const float* b2 = (const float*)d_in[6];
  const float* bn2_g = (const float*)d_in[7];
  const float* bn2_b = (const float*)d_in[8];
  const float* cw1 = (const float*)d_in[9];
  const float* cb1 = (const float*)d_in[10];
  const float* gn1_g = (const float*)d_in[11];
  const float* gn1_b = (const float*)d_in[12];
  const float* gn2_g = (const float*)d_in[13];
  const float* gn2_b = (const float*)d_in[14];
  const float* cw2 = (const float*)d_in[15];
  const float* cb2 = (const float*)d_in[16];
  const float* gn3_g = (const float*)d_in[17];
  const float* gn3_b = (const float*)d_in[18];

  float* out = (float*)d_out;
  float* ws = (float*)d_ws;

  const size_t SZ = (size_t)16 * 256 * 4096;   // elements of one full state
  unsigned short* Abf = (unsigned short*)ws;   // SZ ushorts (bf16 conv1-out scratch)
  float* Q = ws + SZ / 2;                      // SZ floats (ping-pong state)
  unsigned short* XT = (unsigned short*)(ws + SZ / 2 + SZ);  // 16*4098*256 ushorts
  const size_t XTU = (size_t)16 * 4098 * 256;
  unsigned short* APK1 = XT + XTU;             // 16*24*64*8 ushorts
  unsigned short* APK2 = APK1 + 16 * 24 * 64 * 8;
  unsigned short* APKS = APK2 + 16 * 24 * 64 * 8;
  float* TP1 = (float*)(APKS + 16 * 6 * 64 * 8);
  float* TP2 = TP1 + 768;
  float* STATS = TP2 + 768;
  // total ws: ~135.1 MB (<= previously working 135.8 MB)

  const int EW_BLOCKS = (int)(SZ / 4 / 256);

  // ---- weight packing ----
  pack_big<<<96, 256, 0, stream>>>(cw1, APK1, TP1);
  pack_big<<<96, 256, 0, stream>>>(cw2, APK2, TP2);
  pack_stem<<<24, 256, 0, stream>>>(w2, APKS);

  // ---- stem ----
  conv1_kernel<<<16384, 256, 0, stream>>>(x, w1, b1, Abf);
  stats_bf16_kernel<<<64, 256, 0, stream>>>(Abf, STATS, 4096, 16, 64 * 4096, 4096, 1.f / 65536.f);
  act_transpose<64, 1, 0, true><<<1024, 256, 0, stream>>>(Abf, STATS, bn1_g, bn1_b, XT);
  gemm_conv<6, 1, 64, false, false><<<dim3(512, 2), 256, 0, stream>>>(XT, APKS, nullptr, b2, 0.f, Q);
  stats_kernel<<<256, 256, 0, stream>>>(Q, STATS, 4096, 16, 256 * 4096, 4096, 1.f / 65536.f);
  bn_apply<1><<<16384, 256, 0, stream>>>(Q, STATS, bn2_g, bn2_b, out, 255);

  // ---- ODE f-eval front: GN1 stats -> act/T -> conv1 -> GN2 stats -> act/T -> conv2 -> GN3 stats
  auto run_f_front = [&](const float* xin, float* dst, float tval) {
    stats_kernel<<<512, 256, 0, stream>>>(xin, STATS, 32768, 1, 0, 32768, 1.f / 32768.f);
    act_transpose<256, 0, 0, false><<<1024, 256, 0, stream>>>(xin, STATS, gn1_g, gn1_b, XT);
    gemm_conv<24, 3, 256, true, true><<<dim3(512, 2), 256, 0, stream>>>(XT, APK1, TP1, cb1, tval, Abf);
    stats_bf16_kernel<<<512, 256, 0, stream>>>(Abf, STATS, 32768, 1, 0, 32768, 1.f / 32768.f);
    act_transpose<256, 0, 1, true><<<1024, 256, 0, stream>>>(Abf, STATS, gn2_g, gn2_b, XT);
    gemm_conv<24, 3, 256, true, false><<<dim3(512, 2), 256, 0, stream>>>(XT, APK2, TP2, cb2, tval, dst);
    stats_kernel<<<512, 256, 0, stream>>>(dst, STATS, 32768, 1, 0, 32768, 1.f / 32768.f);
  };

  float* ycur = out;
  float* yoth = Q;
  const float H = 0.125f;
  for (int i = 0; i < 8; i++) {
    float t = i * H;
    run_f_front(ycur, yoth, t);
    pred_combine<<<EW_BLOCKS, 256, 0, stream>>>(yoth, STATS, gn3_g, gn3_b, ycur);
    for (int c = 0; c < 2; c++) {
      run_f_front(yoth, yoth, t + H);
      corr_combine<<<EW_BLOCKS, 256, 0, stream>>>(yoth, STATS, gn3_g, gn3_b, ycur);
    }
    float* tmp = ycur;
    ycur = yoth;
    yoth = tmp;
  }
  // after 8 steps (even number of swaps) the final state is in d_out
}

// Round 4
// 5673.116 us; speedup vs baseline: 4.6936x; 1.0614x over previous
//
#include <hip/hip_runtime.h>
#include <math.h>

#define L4 4096

typedef short bf16x8 __attribute__((ext_vector_type(8)));
typedef float f32x4 __attribute__((ext_vector_type(4)));

__device__ __forceinline__ unsigned short f2bf(float f) {
  unsigned u = __builtin_bit_cast(unsigned, f);
  return (unsigned short)((u + 0x7FFFu + ((u >> 16) & 1u)) >> 16);
}
__device__ __forceinline__ float bf2f(unsigned short h) {
  unsigned u = ((unsigned)h) << 16;
  return __builtin_bit_cast(float, u);
}

// ---------------- pack big conv weights into A-fragment layout + t-channel ----------------
__global__ __launch_bounds__(256) void pack_big(const float* __restrict__ cw,
                                                unsigned short* __restrict__ Apack,
                                                float* __restrict__ Tpack) {
  int gid = blockIdx.x * 256 + threadIdx.x;
  if (gid < 768) {
    int o = gid & 255, tap = gid >> 8;
    Tpack[tap * 256 + o] = cw[((size_t)o * 257) * 9 + 3 + tap];
  }
  if (gid >= 16 * 24 * 64) return;
  int frow = gid / 1536;
  int rem = gid - frow * 1536;
  int ks = rem >> 6;
  int lane = rem & 63;
  int o = frow * 16 + (lane & 15);
  int tap = ks >> 3;
  int ib = ((ks & 7) << 5) + ((lane >> 4) << 3);
#pragma unroll
  for (int e = 0; e < 8; e++) {
    int i = ib + e;
    Apack[(size_t)gid * 8 + e] = f2bf(cw[((size_t)o * 257 + (i + 1)) * 9 + 3 + tap]);
  }
}

// ---------------- pack stem conv2 weights (64 in-ch, no t-channel) ----------------
__global__ __launch_bounds__(256) void pack_stem(const float* __restrict__ w2,
                                                 unsigned short* __restrict__ Apack) {
  int gid = blockIdx.x * 256 + threadIdx.x;
  if (gid >= 16 * 6 * 64) return;
  int frow = gid / 384;
  int rem = gid - frow * 384;
  int ks = rem >> 6;
  int lane = rem & 63;
  int o = frow * 16 + (lane & 15);
  int tap = ks >> 1;
  int ib = ((ks & 1) << 5) + ((lane >> 4) << 3);
#pragma unroll
  for (int e = 0; e < 8; e++) {
    int i = ib + e;
    Apack[(size_t)gid * 8 + e] = f2bf(w2[((size_t)o * 64 + i) * 3 + tap]);
  }
}

// ---------------- stem conv1: 4 -> 64, k=3, pad 1 (bf16 out) ----------------
__global__ __launch_bounds__(256) void conv1_kernel(const float* __restrict__ x,
                                                    const float* __restrict__ w,
                                                    const float* __restrict__ bias,
                                                    unsigned short* __restrict__ out) {
  int idx = blockIdx.x * 256 + threadIdx.x;
  int l = idx & 4095;
  int c = (idx >> 12) & 63;
  int b = idx >> 18;
  const float* xb = x + (size_t)b * 4 * L4;
  const float* wc = w + c * 12;
  float acc = bias[c];
#pragma unroll
  for (int i = 0; i < 4; i++) {
    float x0 = (l > 0) ? xb[i * L4 + l - 1] : 0.f;
    float x1 = xb[i * L4 + l];
    float x2 = (l < 4095) ? xb[i * L4 + l + 1] : 0.f;
    acc += wc[i * 3] * x0 + wc[i * 3 + 1] * x1 + wc[i * 3 + 2] * x2;
  }
  out[idx] = f2bf(acc);
}

// ---------------- mean/rstd stats (stem only), fp32 ----------------
__global__ __launch_bounds__(256) void stats_kernel(const float* __restrict__ in,
                                                    float* __restrict__ stats,
                                                    int unit_stride, int nrow,
                                                    int row_stride, int rowlen,
                                                    float inv_n) {
  int u = blockIdx.x;
  const float* base = in + (size_t)u * unit_stride;
  float s = 0.f, s2 = 0.f;
  for (int r = 0; r < nrow; r++) {
    const float* rowp = base + (size_t)r * row_stride;
    for (int j = threadIdx.x * 4; j < rowlen; j += 256 * 4) {
      float4 v = *(const float4*)(rowp + j);
      s += v.x + v.y + v.z + v.w;
      s2 += v.x * v.x + v.y * v.y + v.z * v.z + v.w * v.w;
    }
  }
  __shared__ float sh[512];
  sh[threadIdx.x] = s;
  sh[256 + threadIdx.x] = s2;
  __syncthreads();
  for (int off = 128; off > 0; off >>= 1) {
    if (threadIdx.x < off) {
      sh[threadIdx.x] += sh[threadIdx.x + off];
      sh[256 + threadIdx.x] += sh[256 + threadIdx.x + off];
    }
    __syncthreads();
  }
  if (threadIdx.x == 0) {
    float m = sh[0] * inv_n;
    float var = sh[256] * inv_n - m * m;
    stats[u * 2] = m;
    stats[u * 2 + 1] = rsqrtf(var + 1e-5f);
  }
}

// ---------------- mean/rstd stats (stem only), bf16 ----------------
__global__ __launch_bounds__(256) void stats_bf16_kernel(const unsigned short* __restrict__ in,
                                                         float* __restrict__ stats,
                                                         int unit_stride, int nrow,
                                                         int row_stride, int rowlen,
                                                         float inv_n) {
  int u = blockIdx.x;
  const unsigned short* base = in + (size_t)u * unit_stride;
  float s = 0.f, s2 = 0.f;
  for (int r = 0; r < nrow; r++) {
    const unsigned short* rowp = base + (size_t)r * row_stride;
    for (int j = threadIdx.x * 4; j < rowlen; j += 256 * 4) {
      ushort4 v = *(const ushort4*)(rowp + j);
      float va = bf2f(v.x), vb = bf2f(v.y), vc = bf2f(v.z), vd = bf2f(v.w);
      s += va + vb + vc + vd;
      s2 += va * va + vb * vb + vc * vc + vd * vd;
    }
  }
  __shared__ float sh[512];
  sh[threadIdx.x] = s;
  sh[256 + threadIdx.x] = s2;
  __syncthreads();
  for (int off = 128; off > 0; off >>= 1) {
    if (threadIdx.x < off) {
      sh[threadIdx.x] += sh[threadIdx.x + off];
      sh[256 + threadIdx.x] += sh[256 + threadIdx.x + off];
    }
    __syncthreads();
  }
  if (threadIdx.x == 0) {
    float m = sh[0] * inv_n;
    float var = sh[256] * inv_n - m * m;
    stats[u * 2] = m;
    stats[u * 2 + 1] = rsqrtf(var + 1e-5f);
  }
}

// ---------------- BN apply (stem): ACT 0=relu, 1=tanh; WP -> write GN1 partials of out ----
template <int ACT, bool WP>
__global__ __launch_bounds__(256) void bn_apply(const float* __restrict__ in,
                                                const float* __restrict__ stats,
                                                const float* __restrict__ gamma,
                                                const float* __restrict__ beta,
                                                float* __restrict__ out, int cmask,
                                                float* __restrict__ P1) {
  int tid = threadIdx.x;
  int idx4 = blockIdx.x * 256 + tid;
  int flat = idx4 << 2;
  int c = (flat >> 12) & cmask;
  float m = stats[2 * c], rs = stats[2 * c + 1];
  float ga = gamma[c] * rs, be = beta[c] - m * ga;
  float4 v = ((const float4*)in)[idx4];
  float4 r;
  float a;
  a = v.x * ga + be; r.x = (ACT == 0) ? fmaxf(a, 0.f) : tanhf(a);
  a = v.y * ga + be; r.y = (ACT == 0) ? fmaxf(a, 0.f) : tanhf(a);
  a = v.z * ga + be; r.z = (ACT == 0) ? fmaxf(a, 0.f) : tanhf(a);
  a = v.w * ga + be; r.w = (ACT == 0) ? fmaxf(a, 0.f) : tanhf(a);
  ((float4*)out)[idx4] = r;
  if (WP) {
    float s = r.x + r.y + r.z + r.w;
    float s2 = r.x * r.x + r.y * r.y + r.z * r.z + r.w * r.w;
    __shared__ float sh[512];
    sh[tid] = s; sh[256 + tid] = s2;
    __syncthreads();
    for (int off = 128; off > 0; off >>= 1) {
      if (tid < off) { sh[tid] += sh[tid + off]; sh[256 + tid] += sh[256 + tid + off]; }
      __syncthreads();
    }
    if (tid == 0) { P1[(size_t)blockIdx.x * 2] = sh[0]; P1[(size_t)blockIdx.x * 2 + 1] = sh[256]; }
  }
}

// ---------------- fused norm-affine + act + bf16 + transpose ----------------
// PART: stats ptr holds raw (sum,sumsq) partials [b][32g][32chunk][2]; reduce per block.
template <int C, int SMODE, int ACT, bool INBF, bool PART>
__global__ __launch_bounds__(256) void act_transpose(const void* __restrict__ inv,
                                                     const float* __restrict__ stats,
                                                     const float* __restrict__ gamma,
                                                     const float* __restrict__ beta,
                                                     unsigned short* __restrict__ Xt) {
  __shared__ unsigned short tile[64 * C];
  __shared__ float gsm[32][2];
  int bidx = blockIdx.x;
  int b = bidx >> 6;
  int lt = bidx & 63;
  int l0 = lt << 6;
  int t = threadIdx.x;
  int lanel = t & 63;
  int cq = t >> 6;
  if (PART) {
    if (t < 32) {
      const float* Pb = stats + (size_t)b * 2048 + (size_t)t * 64;
      float s = 0.f, s2 = 0.f;
      for (int j = 0; j < 32; j++) { s += Pb[j * 2]; s2 += Pb[j * 2 + 1]; }
      float m = s * (1.f / 32768.f);
      float var = s2 * (1.f / 32768.f) - m * m;
      gsm[t][0] = m;
      gsm[t][1] = rsqrtf(var + 1e-5f);
    }
    __syncthreads();
  }
  for (int cp = 0; cp < C / 4; cp++) {
    int c = cp * 4 + cq;
    float m, rs;
    if (PART) {
      m = gsm[c >> 3][0]; rs = gsm[c >> 3][1];
    } else if (SMODE == 0) {
      int grp = (b << 5) + (c >> 3);
      m = stats[2 * grp]; rs = stats[2 * grp + 1];
    } else {
      m = stats[2 * c]; rs = stats[2 * c + 1];
    }
    float ga = gamma[c] * rs, be = beta[c] - m * ga;
    size_t gidx = ((size_t)b * C + c) * 4096 + l0 + lanel;
    float v = INBF ? bf2f(((const unsigned short*)inv)[gidx]) : ((const float*)inv)[gidx];
    float a = v * ga + be;
    float r = (ACT == 0) ? fmaxf(a, 0.f) : (a > 0.f ? a : expm1f(a));
    int sw = (C == 256) ? ((lanel & 31) << 3) : ((lanel & 15) << 2);
    tile[lanel * C + (c ^ sw)] = f2bf(r);
  }
  __syncthreads();
  constexpr int CH = C / 4;
  constexpr int RPP = 256 / CH;
  for (int p = 0; p < 64 / RPP; p++) {
    int r = p * RPP + t / CH;
    int ch = t % CH;
    int sw = (C == 256) ? ((r & 31) << 3) : ((r & 15) << 2);
    ushort4 v = *(const ushort4*)&tile[r * C + ((ch * 4) ^ sw)];
    *(ushort4*)&Xt[((size_t)b * 4098 + 1 + l0 + r) * C + ch * 4] = v;
  }
  if (lt == 0) {
    if (t < C / 4) *(ushort4*)&Xt[((size_t)b * 4098 + 0) * C + t * 4] = make_ushort4(0, 0, 0, 0);
  } else if (lt == 63) {
    if (t < C / 4) *(ushort4*)&Xt[((size_t)b * 4098 + 4097) * C + t * 4] = make_ushort4(0, 0, 0, 0);
  }
}

// ---------------- MFMA conv-GEMM, software-pipelined; optional output-stats partials ----
template <int NKS, int KLG, int CIN, bool TCH, bool OBF, bool WP>
__global__ __launch_bounds__(256, 3) void gemm_conv(const unsigned short* __restrict__ Xt,
                                                    const unsigned short* __restrict__ Apack,
                                                    const float* __restrict__ Tpack,
                                                    const float* __restrict__ bias,
                                                    float tval,
                                                    void* __restrict__ outv,
                                                    float* __restrict__ P) {
  int tid = threadIdx.x;
  int lane = tid & 63;
  int wv = tid >> 6;
  int b = blockIdx.x >> 5;
  int l_base = (blockIdx.x & 31) << 7;
  int o_base = blockIdx.y << 7;
  int wo0 = (wv >> 1) << 6;
  int wl0 = (wv & 1) << 6;
  int col = lane & 15;
  int grp = lane >> 4;

  const unsigned short* xb = Xt + (size_t)b * 4098 * CIN;
  const unsigned short* apk = Apack + ((size_t)((o_base + wo0) >> 4) * NKS) * 512 + (size_t)lane * 8;
  int lrow = l_base + wl0 + col;

  f32x4 acc[4][4];
#pragma unroll
  for (int i = 0; i < 4; i++)
#pragma unroll
    for (int j = 0; j < 4; j++) acc[i][j] = (f32x4){0.f, 0.f, 0.f, 0.f};

#define LOADKS(KS, AFR, BFR)                                                        \
  {                                                                                 \
    int tap_ = (KS) >> KLG;                                                         \
    int i0_ = ((KS) & ((1 << KLG) - 1)) << 5;                                       \
    const unsigned short* bb_ = xb + (size_t)(lrow + tap_) * CIN + i0_ + grp * 8;   \
    _Pragma("unroll") for (int fc = 0; fc < 4; fc++)                                \
        BFR[fc] = *(const bf16x8*)(bb_ + (size_t)fc * 16 * CIN);                    \
    _Pragma("unroll") for (int fo = 0; fo < 4; fo++)                                \
        AFR[fo] = *(const bf16x8*)(apk + ((size_t)fo * NKS + (KS)) * 512);          \
  }
#define DOMFMA(AFR, BFR)                                                            \
  _Pragma("unroll") for (int fo = 0; fo < 4; fo++)                                  \
      _Pragma("unroll") for (int fc = 0; fc < 4; fc++)                              \
          acc[fo][fc] = __builtin_amdgcn_mfma_f32_16x16x32_bf16(AFR[fo], BFR[fc], acc[fo][fc], 0, 0, 0);

  bf16x8 aA[4], bA[4], aB[4], bB[4];
  LOADKS(0, aA, bA);
  for (int ks = 0; ks + 2 < NKS; ks += 2) {
    LOADKS(ks + 1, aB, bB);
    DOMFMA(aA, bA);
    LOADKS(ks + 2, aA, bA);
    DOMFMA(aB, bB);
  }
  LOADKS(NKS - 1, aB, bB);
  DOMFMA(aA, bA);
  DOMFMA(aB, bB);
#undef LOADKS
#undef DOMFMA

  float ps_[4], ps2_[4];
#pragma unroll
  for (int fo = 0; fo < 4; fo++) { ps_[fo] = 0.f; ps2_[fo] = 0.f; }

#pragma unroll
  for (int fo = 0; fo < 4; fo++) {
#pragma unroll
    for (int r = 0; r < 4; r++) {
      int o = o_base + wo0 + fo * 16 + grp * 4 + r;
      float bs = bias[o];
      float w0t = 0.f, w1t = 0.f, w2t = 0.f;
      if (TCH) { w0t = Tpack[o]; w1t = Tpack[256 + o]; w2t = Tpack[512 + o]; }
#pragma unroll
      for (int fc = 0; fc < 4; fc++) {
        int l = l_base + wl0 + fc * 16 + col;
        float v = acc[fo][fc][r] + bs;
        if (TCH) {
          float tc = w1t + (l > 0 ? w0t : 0.f) + (l < 4095 ? w2t : 0.f);
          v += tval * tc;
        }
        if (WP) { ps_[fo] += v; ps2_[fo] += v * v; }
        size_t oi = ((size_t)b * 256 + o) * 4096 + l;
        if (OBF) ((unsigned short*)outv)[oi] = f2bf(v);
        else ((float*)outv)[oi] = v;
      }
    }
  }

  if (WP) {
    __shared__ float psh[16][2];
    if (tid < 16) { psh[tid][0] = 0.f; psh[tid][1] = 0.f; }
    __syncthreads();
#pragma unroll
    for (int fo = 0; fo < 4; fo++) {
      float s = ps_[fo], s2 = ps2_[fo];
#pragma unroll
      for (int off = 8; off; off >>= 1) {
        s += __shfl_down(s, off, 16);
        s2 += __shfl_down(s2, off, 16);
      }
      if ((lane & 15) == 0) {
        int g = (wo0 >> 3) + fo * 2 + (grp >> 1);
        atomicAdd(&psh[g][0], s);
        atomicAdd(&psh[g][1], s2);
      }
    }
    __syncthreads();
    if (tid < 16) {
      int g = (o_base >> 3) + tid;
      size_t pi = ((size_t)b * 32 + g) * 64 + (size_t)(blockIdx.x & 31) * 2;
      P[pi] = psh[tid][0];
      P[pi + 1] = psh[tid][1];
    }
  }
}

// ---------------- combines: GN3-affine(f) with partial stats, Heun update ----------------
// pred: y1 = y + h*f (bf16), ybase = y + h/2*f (fp32, in-place y); writes P1 of y1.
__global__ __launch_bounds__(256) void pred_combine(const unsigned short* __restrict__ f,
                                                    const float* __restrict__ P3,
                                                    const float* __restrict__ gamma,
                                                    const float* __restrict__ beta,
                                                    float* __restrict__ y,
                                                    unsigned short* __restrict__ y1,
                                                    float* __restrict__ P1) {
  int tid = threadIdx.x;
  int idx4 = blockIdx.x * 256 + tid;
  int flat = idx4 << 2;
  int c = (flat >> 12) & 255;
  int b = flat >> 20;
  __shared__ float smr[2];
  {
    const float* Pg = P3 + ((size_t)b * 32 + (c >> 3)) * 64;
    float s = (tid < 32) ? Pg[tid * 2] : 0.f;
    float s2 = (tid < 32) ? Pg[tid * 2 + 1] : 0.f;
#pragma unroll
    for (int off = 16; off; off >>= 1) { s += __shfl_down(s, off, 32); s2 += __shfl_down(s2, off, 32); }
    if (tid == 0) {
      float m = s * (1.f / 32768.f);
      float var = s2 * (1.f / 32768.f) - m * m;
      smr[0] = m; smr[1] = rsqrtf(var + 1e-5f);
    }
  }
  __syncthreads();
  float ga = gamma[c] * smr[1], be = beta[c] - smr[0] * ga;
  ushort4 fv = ((const ushort4*)f)[idx4];
  float4 yv = ((const float4*)y)[idx4];
  float4 yb;
  ushort4 yo;
  float fa, yn, s = 0.f, s2 = 0.f;
  fa = bf2f(fv.x) * ga + be; yn = yv.x + 0.125f * fa; yb.x = yv.x + 0.0625f * fa; yo.x = f2bf(yn); s += yn; s2 += yn * yn;
  fa = bf2f(fv.y) * ga + be; yn = yv.y + 0.125f * fa; yb.y = yv.y + 0.0625f * fa; yo.y = f2bf(yn); s += yn; s2 += yn * yn;
  fa = bf2f(fv.z) * ga + be; yn = yv.z + 0.125f * fa; yb.z = yv.z + 0.0625f * fa; yo.z = f2bf(yn); s += yn; s2 += yn * yn;
  fa = bf2f(fv.w) * ga + be; yn = yv.w + 0.125f * fa; yb.w = yv.w + 0.0625f * fa; yo.w = f2bf(yn); s += yn; s2 += yn * yn;
  ((float4*)y)[idx4] = yb;
  ((ushort4*)y1)[idx4] = yo;
  __shared__ float sh[512];
  sh[tid] = s; sh[256 + tid] = s2;
  __syncthreads();
  for (int off = 128; off > 0; off >>= 1) {
    if (tid < off) { sh[tid] += sh[tid + off]; sh[256 + tid] += sh[256 + tid + off]; }
    __syncthreads();
  }
  if (tid == 0) { P1[(size_t)blockIdx.x * 2] = sh[0]; P1[(size_t)blockIdx.x * 2 + 1] = sh[256]; }
}

// corr: yn = ybase + h/2*f.  FIN=false -> bf16 y1 out; FIN=true -> fp32 out. Writes P1.
template <bool FIN>
__global__ __launch_bounds__(256) void corr_combine(const unsigned short* __restrict__ f,
                                                    const float* __restrict__ P3,
                                                    const float* __restrict__ gamma,
                                                    const float* __restrict__ beta,
                                                    const float* __restrict__ ybase,
                                                    void* __restrict__ yout,
                                                    float* __restrict__ P1) {
  int tid = threadIdx.x;
  int idx4 = blockIdx.x * 256 + tid;
  int flat = idx4 << 2;
  int c = (flat >> 12) & 255;
  int b = flat >> 20;
  __shared__ float smr[2];
  {
    const float* Pg = P3 + ((size_t)b * 32 + (c >> 3)) * 64;
    float s = (tid < 32) ? Pg[tid * 2] : 0.f;
    float s2 = (tid < 32) ? Pg[tid * 2 + 1] : 0.f;
#pragma unroll
    for (int off = 16; off; off >>= 1) { s += __shfl_down(s, off, 32); s2 += __shfl_down(s2, off, 32); }
    if (tid == 0) {
      float m = s * (1.f / 32768.f);
      float var = s2 * (1.f / 32768.f) - m * m;
      smr[0] = m; smr[1] = rsqrtf(var + 1e-5f);
    }
  }
  __syncthreads();
  float ga = gamma[c] * smr[1], be = beta[c] - smr[0] * ga;
  ushort4 fv = ((const ushort4*)f)[idx4];
  float4 yb = ((const float4*)ybase)[idx4];
  float4 yn;
  yn.x = yb.x + 0.0625f * (bf2f(fv.x) * ga + be);
  yn.y = yb.y + 0.0625f * (bf2f(fv.y) * ga + be);
  yn.z = yb.z + 0.0625f * (bf2f(fv.z) * ga + be);
  yn.w = yb.w + 0.0625f * (bf2f(fv.w) * ga + be);
  if (FIN) {
    ((float4*)yout)[idx4] = yn;
  } else {
    ushort4 yo;
    yo.x = f2bf(yn.x); yo.y = f2bf(yn.y); yo.z = f2bf(yn.z); yo.w = f2bf(yn.w);
    ((ushort4*)yout)[idx4] = yo;
  }
  float s = yn.x + yn.y + yn.z + yn.w;
  float s2 = yn.x * yn.x + yn.y * yn.y + yn.z * yn.z + yn.w * yn.w;
  __shared__ float sh[512];
  sh[tid] = s; sh[256 + tid] = s2;
  __syncthreads();
  for (int off = 128; off > 0; off >>= 1) {
    if (tid < off) { sh[tid] += sh[tid + off]; sh[256 + tid] += sh[256 + tid + off]; }
    __syncthreads();
  }
  if (tid == 0) { P1[(size_t)blockIdx.x * 2] = sh[0]; P1[(size_t)blockIdx.x * 2 + 1] = sh[256]; }
}

extern "C" void kernel_launch(void* const* d_in, const int* in_sizes, int n_in,
                              void* d_out, int out_size, void* d_ws, size_t ws_size,
                              hipStream_t stream) {
  const float* x = (const float*)d_in[0];
  const float* w1 = (const float*)d_in[1];
  const float* b1 = (const float*)d_in[2];
  const float* bn1_g = (const float*)d_in[3];
  const float* bn1_b = (const float*)d_in[4];
  const float* w2 = (const float*)d_in[5];
  const float* b2 = (const float*)d_in[6];
  const float* bn2_g = (const float*)d_in[7];
  const float* bn2_b = (const float*)d_in[8];
  const float* cw1 = (const float*)d_in[9];
  const float* cb1 = (const float*)d_in[10];
  const float* gn1_g = (const float*)d_in[11];
  const float* gn1_b = (const float*)d_in[12];
  const float* gn2_g = (const float*)d_in[13];
  const float* gn2_b = (const float*)d_in[14];
  const float* cw2 = (const float*)d_in[15];
  const float* cb2 = (const float*)d_in[16];
  const float* gn3_g = (const float*)d_in[17];
  const float* gn3_b = (const float*)d_in[18];

  float* out = (float*)d_out;
  const size_t SZ = (size_t)16 * 256 * 4096;

  char* p = (char*)d_ws;
  unsigned short* Abf = (unsigned short*)p;  p += SZ * 2;
  float* Q = (float*)p;                      p += SZ * 4;
  unsigned short* XT = (unsigned short*)p;   p += (size_t)16 * 4098 * 256 * 2;
  unsigned short* APK1 = (unsigned short*)p; p += (size_t)16 * 24 * 64 * 8 * 2;
  unsigned short* APK2 = (unsigned short*)p; p += (size_t)16 * 24 * 64 * 8 * 2;
  unsigned short* APKS = (unsigned short*)p; p += (size_t)16 * 6 * 64 * 8 * 2;
  float* TP1 = (float*)p;                    p += 768 * 4;
  float* TP2 = (float*)p;                    p += 768 * 4;
  float* STATS = (float*)p;                  p += 1024 * 4;
  float* P1 = (float*)p;                     p += 32768 * 4;
  float* P2 = (float*)p;                     p += 32768 * 4;
  float* P3 = (float*)p;                     p += 32768 * 4;
  // total ~135.4 MB

  const int EW_BLOCKS = (int)(SZ / 4 / 256);  // 16384

  // ---- weight packing ----
  pack_big<<<96, 256, 0, stream>>>(cw1, APK1, TP1);
  pack_big<<<96, 256, 0, stream>>>(cw2, APK2, TP2);
  pack_stem<<<24, 256, 0, stream>>>(w2, APKS);

  // ---- stem ----
  conv1_kernel<<<16384, 256, 0, stream>>>(x, w1, b1, Abf);
  stats_bf16_kernel<<<64, 256, 0, stream>>>(Abf, STATS, 4096, 16, 64 * 4096, 4096, 1.f / 65536.f);
  act_transpose<64, 1, 0, true, false><<<1024, 256, 0, stream>>>(Abf, STATS, bn1_g, bn1_b, XT);
  gemm_conv<6, 1, 64, false, false, false><<<dim3(512, 2), 256, 0, stream>>>(XT, APKS, nullptr, b2, 0.f, Q, nullptr);
  stats_kernel<<<256, 256, 0, stream>>>(Q, STATS, 4096, 16, 256 * 4096, 4096, 1.f / 65536.f);
  bn_apply<1, true><<<16384, 256, 0, stream>>>(Q, STATS, bn2_g, bn2_b, out, 255, P1);

  // ---- ODE: 8 steps of predictor + 2 correctors; GN stats flow via partials ----
  float* ycur = out;
  float* yoth = Q;
  const float H = 0.125f;
  for (int i = 0; i < 8; i++) {
    float t = i * H;
    unsigned short* Y1 = (unsigned short*)yoth;   // bf16 y1 overlays low half of yoth

    // predictor eval f(t, ycur)  [ycur fp32, P1 holds its GN1 partials]
    act_transpose<256, 0, 0, false, true><<<1024, 256, 0, stream>>>(ycur, P1, gn1_g, gn1_b, XT);
    gemm_conv<24, 3, 256, true, true, true><<<dim3(512, 2), 256, 0, stream>>>(XT, APK1, TP1, cb1, t, Abf, P2);
    act_transpose<256, 0, 1, true, true><<<1024, 256, 0, stream>>>(Abf, P2, gn2_g, gn2_b, XT);
    gemm_conv<24, 3, 256, true, true, true><<<dim3(512, 2), 256, 0, stream>>>(XT, APK2, TP2, cb2, t, Abf, P3);
    pred_combine<<<EW_BLOCKS, 256, 0, stream>>>(Abf, P3, gn3_g, gn3_b, ycur, Y1, P1);

    // correctors: f(t+h, y1) with y1 bf16
    for (int c = 0; c < 2; c++) {
      act_transpose<256, 0, 0, true, true><<<1024, 256, 0, stream>>>(Y1, P1, gn1_g, gn1_b, XT);
      gemm_conv<24, 3, 256, true, true, true><<<dim3(512, 2), 256, 0, stream>>>(XT, APK1, TP1, cb1, t + H, Abf, P2);
      act_transpose<256, 0, 1, true, true><<<1024, 256, 0, stream>>>(Abf, P2, gn2_g, gn2_b, XT);
      gemm_conv<24, 3, 256, true, true, true><<<dim3(512, 2), 256, 0, stream>>>(XT, APK2, TP2, cb2, t + H, Abf, P3);
      if (c == 0)
        corr_combine<false><<<EW_BLOCKS, 256, 0, stream>>>(Abf, P3, gn3_g, gn3_b, ycur, Y1, P1);
      else
        corr_combine<true><<<EW_BLOCKS, 256, 0, stream>>>(Abf, P3, gn3_g, gn3_b, ycur, yoth, P1);
    }
    float* tmp = ycur;
    ycur = yoth;
    yoth = tmp;
  }
  // after 8 steps (even number of swaps) the final state is in d_out
}

// Round 5
// 3322.789 us; speedup vs baseline: 8.0135x; 1.7073x over previous
//
#include <hip/hip_runtime.h>
#include <math.h>

#define L4 4096

typedef short bf16x8 __attribute__((ext_vector_type(8)));
typedef float f32x4 __attribute__((ext_vector_type(4)));

__device__ __forceinline__ unsigned short f2bf(float f) {
  unsigned u = __builtin_bit_cast(unsigned, f);
  return (unsigned short)((u + 0x7FFFu + ((u >> 16) & 1u)) >> 16);
}
__device__ __forceinline__ float bf2f(unsigned short h) {
  unsigned u = ((unsigned)h) << 16;
  return __builtin_bit_cast(float, u);
}

typedef __attribute__((address_space(3))) unsigned lds_u32_t;
typedef const __attribute__((address_space(1))) unsigned glb_u32_t;
__device__ __forceinline__ void gl2lds16(const void* g, void* l) {
  __builtin_amdgcn_global_load_lds((glb_u32_t*)g, (lds_u32_t*)l, 16, 0, 0);
}

// ---------------- pack big conv weights into A-fragment layout + t-channel ----------------
__global__ __launch_bounds__(256) void pack_big(const float* __restrict__ cw,
                                                unsigned short* __restrict__ Apack,
                                                float* __restrict__ Tpack) {
  int gid = blockIdx.x * 256 + threadIdx.x;
  if (gid < 768) {
    int o = gid & 255, tap = gid >> 8;
    Tpack[tap * 256 + o] = cw[((size_t)o * 257) * 9 + 3 + tap];
  }
  if (gid >= 16 * 24 * 64) return;
  int frow = gid / 1536;
  int rem = gid - frow * 1536;
  int ks = rem >> 6;
  int lane = rem & 63;
  int o = frow * 16 + (lane & 15);
  int tap = ks >> 3;
  int ib = ((ks & 7) << 5) + ((lane >> 4) << 3);
#pragma unroll
  for (int e = 0; e < 8; e++) {
    int i = ib + e;
    Apack[(size_t)gid * 8 + e] = f2bf(cw[((size_t)o * 257 + (i + 1)) * 9 + 3 + tap]);
  }
}

// ---------------- pack stem conv2 weights (64 in-ch, no t-channel) ----------------
__global__ __launch_bounds__(256) void pack_stem(const float* __restrict__ w2,
                                                 unsigned short* __restrict__ Apack) {
  int gid = blockIdx.x * 256 + threadIdx.x;
  if (gid >= 16 * 6 * 64) return;
  int frow = gid / 384;
  int rem = gid - frow * 384;
  int ks = rem >> 6;
  int lane = rem & 63;
  int o = frow * 16 + (lane & 15);
  int tap = ks >> 1;
  int ib = ((ks & 1) << 5) + ((lane >> 4) << 3);
#pragma unroll
  for (int e = 0; e < 8; e++) {
    int i = ib + e;
    Apack[(size_t)gid * 8 + e] = f2bf(w2[((size_t)o * 64 + i) * 3 + tap]);
  }
}

// ---------------- stem conv1: 4 -> 64, k=3, pad 1 (bf16 out) ----------------
__global__ __launch_bounds__(256) void conv1_kernel(const float* __restrict__ x,
                                                    const float* __restrict__ w,
                                                    const float* __restrict__ bias,
                                                    unsigned short* __restrict__ out) {
  int idx = blockIdx.x * 256 + threadIdx.x;
  int l = idx & 4095;
  int c = (idx >> 12) & 63;
  int b = idx >> 18;
  const float* xb = x + (size_t)b * 4 * L4;
  const float* wc = w + c * 12;
  float acc = bias[c];
#pragma unroll
  for (int i = 0; i < 4; i++) {
    float x0 = (l > 0) ? xb[i * L4 + l - 1] : 0.f;
    float x1 = xb[i * L4 + l];
    float x2 = (l < 4095) ? xb[i * L4 + l + 1] : 0.f;
    acc += wc[i * 3] * x0 + wc[i * 3 + 1] * x1 + wc[i * 3 + 2] * x2;
  }
  out[idx] = f2bf(acc);
}

// ---------------- mean/rstd stats (stem only), fp32 ----------------
__global__ __launch_bounds__(256) void stats_kernel(const float* __restrict__ in,
                                                    float* __restrict__ stats,
                                                    int unit_stride, int nrow,
                                                    int row_stride, int rowlen,
                                                    float inv_n) {
  int u = blockIdx.x;
  const float* base = in + (size_t)u * unit_stride;
  float s = 0.f, s2 = 0.f;
  for (int r = 0; r < nrow; r++) {
    const float* rowp = base + (size_t)r * row_stride;
    for (int j = threadIdx.x * 4; j < rowlen; j += 256 * 4) {
      float4 v = *(const float4*)(rowp + j);
      s += v.x + v.y + v.z + v.w;
      s2 += v.x * v.x + v.y * v.y + v.z * v.z + v.w * v.w;
    }
  }
  __shared__ float sh[512];
  sh[threadIdx.x] = s;
  sh[256 + threadIdx.x] = s2;
  __syncthreads();
  for (int off = 128; off > 0; off >>= 1) {
    if (threadIdx.x < off) {
      sh[threadIdx.x] += sh[threadIdx.x + off];
      sh[256 + threadIdx.x] += sh[256 + threadIdx.x + off];
    }
    __syncthreads();
  }
  if (threadIdx.x == 0) {
    float m = sh[0] * inv_n;
    float var = sh[256] * inv_n - m * m;
    stats[u * 2] = m;
    stats[u * 2 + 1] = rsqrtf(var + 1e-5f);
  }
}

// ---------------- mean/rstd stats (stem only), bf16 ----------------
__global__ __launch_bounds__(256) void stats_bf16_kernel(const unsigned short* __restrict__ in,
                                                         float* __restrict__ stats,
                                                         int unit_stride, int nrow,
                                                         int row_stride, int rowlen,
                                                         float inv_n) {
  int u = blockIdx.x;
  const unsigned short* base = in + (size_t)u * unit_stride;
  float s = 0.f, s2 = 0.f;
  for (int r = 0; r < nrow; r++) {
    const unsigned short* rowp = base + (size_t)r * row_stride;
    for (int j = threadIdx.x * 4; j < rowlen; j += 256 * 4) {
      ushort4 v = *(const ushort4*)(rowp + j);
      float va = bf2f(v.x), vb = bf2f(v.y), vc = bf2f(v.z), vd = bf2f(v.w);
      s += va + vb + vc + vd;
      s2 += va * va + vb * vb + vc * vc + vd * vd;
    }
  }
  __shared__ float sh[512];
  sh[threadIdx.x] = s;
  sh[256 + threadIdx.x] = s2;
  __syncthreads();
  for (int off = 128; off > 0; off >>= 1) {
    if (threadIdx.x < off) {
      sh[threadIdx.x] += sh[threadIdx.x + off];
      sh[256 + threadIdx.x] += sh[256 + threadIdx.x + off];
    }
    __syncthreads();
  }
  if (threadIdx.x == 0) {
    float m = sh[0] * inv_n;
    float var = sh[256] * inv_n - m * m;
    stats[u * 2] = m;
    stats[u * 2 + 1] = rsqrtf(var + 1e-5f);
  }
}

// ---------------- BN apply (stem): ACT 0=relu, 1=tanh; WP -> write GN1 partials ----------
template <int ACT, bool WP>
__global__ __launch_bounds__(256) void bn_apply(const float* __restrict__ in,
                                                const float* __restrict__ stats,
                                                const float* __restrict__ gamma,
                                                const float* __restrict__ beta,
                                                float* __restrict__ out, int cmask,
                                                float* __restrict__ P1) {
  int tid = threadIdx.x;
  int idx4 = blockIdx.x * 256 + tid;
  int flat = idx4 << 2;
  int c = (flat >> 12) & cmask;
  float m = stats[2 * c], rs = stats[2 * c + 1];
  float ga = gamma[c] * rs, be = beta[c] - m * ga;
  float4 v = ((const float4*)in)[idx4];
  float4 r;
  float a;
  a = v.x * ga + be; r.x = (ACT == 0) ? fmaxf(a, 0.f) : tanhf(a);
  a = v.y * ga + be; r.y = (ACT == 0) ? fmaxf(a, 0.f) : tanhf(a);
  a = v.z * ga + be; r.z = (ACT == 0) ? fmaxf(a, 0.f) : tanhf(a);
  a = v.w * ga + be; r.w = (ACT == 0) ? fmaxf(a, 0.f) : tanhf(a);
  ((float4*)out)[idx4] = r;
  if (WP) {
    float s = r.x + r.y + r.z + r.w;
    float s2 = r.x * r.x + r.y * r.y + r.z * r.z + r.w * r.w;
    __shared__ float sh[512];
    sh[tid] = s; sh[256 + tid] = s2;
    __syncthreads();
    for (int off = 128; off > 0; off >>= 1) {
      if (tid < off) { sh[tid] += sh[tid + off]; sh[256 + tid] += sh[256 + tid + off]; }
      __syncthreads();
    }
    if (tid == 0) { P1[(size_t)blockIdx.x * 2] = sh[0]; P1[(size_t)blockIdx.x * 2 + 1] = sh[256]; }
  }
}

// ---------------- fused norm-affine + act + bf16 + transpose ----------------
template <int C, int SMODE, int ACT, bool INBF, bool PART>
__global__ __launch_bounds__(256) void act_transpose(const void* __restrict__ inv,
                                                     const float* __restrict__ stats,
                                                     const float* __restrict__ gamma,
                                                     const float* __restrict__ beta,
                                                     unsigned short* __restrict__ Xt) {
  __shared__ unsigned short tile[64 * C];
  __shared__ float gsm[32][2];
  int bidx = blockIdx.x;
  int b = bidx >> 6;
  int lt = bidx & 63;
  int l0 = lt << 6;
  int t = threadIdx.x;
  int lanel = t & 63;
  int cq = t >> 6;
  if (PART) {
    if (t < 32) {
      const float* Pb = stats + (size_t)b * 2048 + (size_t)t * 64;
      float s = 0.f, s2 = 0.f;
      for (int j = 0; j < 32; j++) { s += Pb[j * 2]; s2 += Pb[j * 2 + 1]; }
      float m = s * (1.f / 32768.f);
      float var = s2 * (1.f / 32768.f) - m * m;
      gsm[t][0] = m;
      gsm[t][1] = rsqrtf(var + 1e-5f);
    }
    __syncthreads();
  }
  for (int cp = 0; cp < C / 4; cp++) {
    int c = cp * 4 + cq;
    float m, rs;
    if (PART) {
      m = gsm[c >> 3][0]; rs = gsm[c >> 3][1];
    } else if (SMODE == 0) {
      int grp = (b << 5) + (c >> 3);
      m = stats[2 * grp]; rs = stats[2 * grp + 1];
    } else {
      m = stats[2 * c]; rs = stats[2 * c + 1];
    }
    float ga = gamma[c] * rs, be = beta[c] - m * ga;
    size_t gidx = ((size_t)b * C + c) * 4096 + l0 + lanel;
    float v = INBF ? bf2f(((const unsigned short*)inv)[gidx]) : ((const float*)inv)[gidx];
    float a = v * ga + be;
    float r = (ACT == 0) ? fmaxf(a, 0.f) : (a > 0.f ? a : expm1f(a));
    int sw = (C == 256) ? ((lanel & 31) << 3) : ((lanel & 15) << 2);
    tile[lanel * C + (c ^ sw)] = f2bf(r);
  }
  __syncthreads();
  constexpr int CH = C / 4;
  constexpr int RPP = 256 / CH;
  for (int p = 0; p < 64 / RPP; p++) {
    int r = p * RPP + t / CH;
    int ch = t % CH;
    int sw = (C == 256) ? ((r & 31) << 3) : ((r & 15) << 2);
    ushort4 v = *(const ushort4*)&tile[r * C + ((ch * 4) ^ sw)];
    *(ushort4*)&Xt[((size_t)b * 4098 + 1 + l0 + r) * C + ch * 4] = v;
  }
  if (lt == 0) {
    if (t < C / 4) *(ushort4*)&Xt[((size_t)b * 4098 + 0) * C + t * 4] = make_ushort4(0, 0, 0, 0);
  } else if (lt == 63) {
    if (t < C / 4) *(ushort4*)&Xt[((size_t)b * 4098 + 4097) * C + t * 4] = make_ushort4(0, 0, 0, 0);
  }
}

// ---------------- MFMA conv-GEMM with full-K LDS staging of the B tile ----------------
// 512 thr (8 waves), tile 256o x 128l; wave = 64o x 64l. grid: 16b*32lt = 512 blocks.
// B tile: 130 rows x CIN ch staged to LDS via global_load_lds, XOR-swizzled chunks.
template <int NKS, int KLG, int CIN, bool TCH, bool OBF, bool WP>
__global__ __launch_bounds__(512, 4) void gemm_conv(const unsigned short* __restrict__ Xt,
                                                    const unsigned short* __restrict__ Apack,
                                                    const float* __restrict__ Tpack,
                                                    const float* __restrict__ bias,
                                                    float tval,
                                                    void* __restrict__ outv,
                                                    float* __restrict__ P) {
  constexpr int CPR = CIN / 8;            // 16-B chunks per row
  constexpr int CPRLG = (CIN == 256) ? 5 : 3;
  constexpr int TOT = 130 * CPR;          // total chunks
  __shared__ unsigned short bsm[130 * CIN];
  __shared__ float psh[32][2];

  int tid = threadIdx.x;
  int lane = tid & 63;
  int wv = tid >> 6;
  int b = blockIdx.x >> 5;
  int lt = blockIdx.x & 31;
  int l_base = lt << 7;
  int wo0 = (wv >> 1) << 6;
  int wl0 = (wv & 1) << 6;
  int col = lane & 15;
  int grp = lane >> 4;

  const unsigned short* xb = Xt + (size_t)b * 4098 * CIN + (size_t)l_base * CIN;

  // ---- stage B tile: LDS[row][cb] = global[row][cb ^ (row&7)] ----
#pragma unroll
  for (int it = 0; it < TOT / 512; it++) {
    int chunk = it * 512 + tid;
    int row = chunk >> CPRLG;
    int cb = chunk & (CPR - 1);
    const unsigned short* src = xb + (size_t)row * CIN + ((cb ^ (row & 7)) << 3);
    gl2lds16(src, &bsm[(size_t)chunk * 8]);
  }
  {
    constexpr int REM = TOT & 511;
    if (REM && tid < REM) {
      int chunk = (TOT & ~511) + tid;
      int row = chunk >> CPRLG;
      int cb = chunk & (CPR - 1);
      *(bf16x8*)&bsm[(size_t)chunk * 8] =
          *(const bf16x8*)(xb + (size_t)row * CIN + ((cb ^ (row & 7)) << 3));
    }
  }
  if (WP) {
    if (tid < 32) { psh[tid][0] = 0.f; psh[tid][1] = 0.f; }
  }
  __syncthreads();

  const unsigned short* apk = Apack + ((size_t)(wo0 >> 4) * NKS) * 512 + (size_t)lane * 8;

  f32x4 acc[4][4];
#pragma unroll
  for (int i = 0; i < 4; i++)
#pragma unroll
    for (int j = 0; j < 4; j++) acc[i][j] = (f32x4){0.f, 0.f, 0.f, 0.f};

#pragma unroll 2
  for (int ks = 0; ks < NKS; ks++) {
    int tap = ks >> KLG;
    int cbase = (ks & ((1 << KLG) - 1)) << 2;     // chunk base = i0/8
    bf16x8 bfr[4], afr[4];
#pragma unroll
    for (int fc = 0; fc < 4; fc++) {
      int lr = wl0 + col + fc * 16 + tap;
      int cb = (cbase + grp) ^ (lr & 7);
      bfr[fc] = *(const bf16x8*)&bsm[((size_t)(lr << CPRLG) + cb) * 8];
    }
#pragma unroll
    for (int fo = 0; fo < 4; fo++)
      afr[fo] = *(const bf16x8*)(apk + ((size_t)fo * NKS + ks) * 512);
#pragma unroll
    for (int fo = 0; fo < 4; fo++)
#pragma unroll
      for (int fc = 0; fc < 4; fc++)
        acc[fo][fc] = __builtin_amdgcn_mfma_f32_16x16x32_bf16(afr[fo], bfr[fc], acc[fo][fc], 0, 0, 0);
  }

  float ps_[4], ps2_[4];
#pragma unroll
  for (int fo = 0; fo < 4; fo++) { ps_[fo] = 0.f; ps2_[fo] = 0.f; }

#pragma unroll
  for (int fo = 0; fo < 4; fo++) {
#pragma unroll
    for (int r = 0; r < 4; r++) {
      int o = wo0 + fo * 16 + grp * 4 + r;
      float bs = bias[o];
      float w0t = 0.f, w1t = 0.f, w2t = 0.f;
      if (TCH) { w0t = Tpack[o]; w1t = Tpack[256 + o]; w2t = Tpack[512 + o]; }
#pragma unroll
      for (int fc = 0; fc < 4; fc++) {
        int l = l_base + wl0 + fc * 16 + col;
        float v = acc[fo][fc][r] + bs;
        if (TCH) {
          float tc = w1t + (l > 0 ? w0t : 0.f) + (l < 4095 ? w2t : 0.f);
          v += tval * tc;
        }
        if (WP) { ps_[fo] += v; ps2_[fo] += v * v; }
        size_t oi = ((size_t)b * 256 + o) * 4096 + l;
        if (OBF) ((unsigned short*)outv)[oi] = f2bf(v);
        else ((float*)outv)[oi] = v;
      }
    }
  }

  if (WP) {
#pragma unroll
    for (int fo = 0; fo < 4; fo++) {
      float s = ps_[fo], s2 = ps2_[fo];
#pragma unroll
      for (int off = 8; off; off >>= 1) {
        s += __shfl_down(s, off, 16);
        s2 += __shfl_down(s2, off, 16);
      }
      if ((lane & 15) == 0) {
        int g = (wo0 >> 3) + fo * 2 + (grp >> 1);
        atomicAdd(&psh[g][0], s);
        atomicAdd(&psh[g][1], s2);
      }
    }
    __syncthreads();
    if (tid < 32) {
      size_t pi = ((size_t)b * 32 + tid) * 64 + (size_t)lt * 2;
      P[pi] = psh[tid][0];
      P[pi + 1] = psh[tid][1];
    }
  }
}

// ---------------- combines: GN3-affine(f) with partial stats, Heun update ----------------
__global__ __launch_bounds__(256) void pred_combine(const unsigned short* __restrict__ f,
                                                    const float* __restrict__ P3,
                                                    const float* __restrict__ gamma,
                                                    const float* __restrict__ beta,
                                                    float* __restrict__ y,
                                                    unsigned short* __restrict__ y1,
                                                    float* __restrict__ P1) {
  int tid = threadIdx.x;
  int idx4 = blockIdx.x * 256 + tid;
  int flat = idx4 << 2;
  int c = (flat >> 12) & 255;
  int b = flat >> 20;
  __shared__ float smr[2];
  {
    const float* Pg = P3 + ((size_t)b * 32 + (c >> 3)) * 64;
    float s = (tid < 32) ? Pg[tid * 2] : 0.f;
    float s2 = (tid < 32) ? Pg[tid * 2 + 1] : 0.f;
#pragma unroll
    for (int off = 16; off; off >>= 1) { s += __shfl_down(s, off, 32); s2 += __shfl_down(s2, off, 32); }
    if (tid == 0) {
      float m = s * (1.f / 32768.f);
      float var = s2 * (1.f / 32768.f) - m * m;
      smr[0] = m; smr[1] = rsqrtf(var + 1e-5f);
    }
  }
  __syncthreads();
  float ga = gamma[c] * smr[1], be = beta[c] - smr[0] * ga;
  ushort4 fv = ((const ushort4*)f)[idx4];
  float4 yv = ((const float4*)y)[idx4];
  float4 yb;
  ushort4 yo;
  float fa, yn, s = 0.f, s2 = 0.f;
  fa = bf2f(fv.x) * ga + be; yn = yv.x + 0.125f * fa; yb.x = yv.x + 0.0625f * fa; yo.x = f2bf(yn); s += yn; s2 += yn * yn;
  fa = bf2f(fv.y) * ga + be; yn = yv.y + 0.125f * fa; yb.y = yv.y + 0.0625f * fa; yo.y = f2bf(yn); s += yn; s2 += yn * yn;
  fa = bf2f(fv.z) * ga + be; yn = yv.z + 0.125f * fa; yb.z = yv.z + 0.0625f * fa; yo.z = f2bf(yn); s += yn; s2 += yn * yn;
  fa = bf2f(fv.w) * ga + be; yn = yv.w + 0.125f * fa; yb.w = yv.w + 0.0625f * fa; yo.w = f2bf(yn); s += yn; s2 += yn * yn;
  ((float4*)y)[idx4] = yb;
  ((ushort4*)y1)[idx4] = yo;
  __shared__ float sh[512];
  sh[tid] = s; sh[256 + tid] = s2;
  __syncthreads();
  for (int off = 128; off > 0; off >>= 1) {
    if (tid < off) { sh[tid] += sh[tid + off]; sh[256 + tid] += sh[256 + tid + off]; }
    __syncthreads();
  }
  if (tid == 0) { P1[(size_t)blockIdx.x * 2] = sh[0]; P1[(size_t)blockIdx.x * 2 + 1] = sh[256]; }
}

template <bool FIN>
__global__ __launch_bounds__(256) void corr_combine(const unsigned short* __restrict__ f,
                                                    const float* __restrict__ P3,
                                                    const float* __restrict__ gamma,
                                                    const float* __restrict__ beta,
                                                    const float* __restrict__ ybase,
                                                    void* __restrict__ yout,
                                                    float* __restrict__ P1) {
  int tid = threadIdx.x;
  int idx4 = blockIdx.x * 256 + tid;
  int flat = idx4 << 2;
  int c = (flat >> 12) & 255;
  int b = flat >> 20;
  __shared__ float smr[2];
  {
    const float* Pg = P3 + ((size_t)b * 32 + (c >> 3)) * 64;
    float s = (tid < 32) ? Pg[tid * 2] : 0.f;
    float s2 = (tid < 32) ? Pg[tid * 2 + 1] : 0.f;
#pragma unroll
    for (int off = 16; off; off >>= 1) { s += __shfl_down(s, off, 32); s2 += __shfl_down(s2, off, 32); }
    if (tid == 0) {
      float m = s * (1.f / 32768.f);
      float var = s2 * (1.f / 32768.f) - m * m;
      smr[0] = m; smr[1] = rsqrtf(var + 1e-5f);
    }
  }
  __syncthreads();
  float ga = gamma[c] * smr[1], be = beta[c] - smr[0] * ga;
  ushort4 fv = ((const ushort4*)f)[idx4];
  float4 yb = ((const float4*)ybase)[idx4];
  float4 yn;
  yn.x = yb.x + 0.0625f * (bf2f(fv.x) * ga + be);
  yn.y = yb.y + 0.0625f * (bf2f(fv.y) * ga + be);
  yn.z = yb.z + 0.0625f * (bf2f(fv.z) * ga + be);
  yn.w = yb.w + 0.0625f * (bf2f(fv.w) * ga + be);
  if (FIN) {
    ((float4*)yout)[idx4] = yn;
  } else {
    ushort4 yo;
    yo.x = f2bf(yn.x); yo.y = f2bf(yn.y); yo.z = f2bf(yn.z); yo.w = f2bf(yn.w);
    ((ushort4*)yout)[idx4] = yo;
  }
  float s = yn.x + yn.y + yn.z + yn.w;
  float s2 = yn.x * yn.x + yn.y * yn.y + yn.z * yn.z + yn.w * yn.w;
  __shared__ float sh[512];
  sh[tid] = s; sh[256 + tid] = s2;
  __syncthreads();
  for (int off = 128; off > 0; off >>= 1) {
    if (tid < off) { sh[tid] += sh[tid + off]; sh[256 + tid] += sh[256 + tid + off]; }
    __syncthreads();
  }
  if (tid == 0) { P1[(size_t)blockIdx.x * 2] = sh[0]; P1[(size_t)blockIdx.x * 2 + 1] = sh[256]; }
}

extern "C" void kernel_launch(void* const* d_in, const int* in_sizes, int n_in,
                              void* d_out, int out_size, void* d_ws, size_t ws_size,
                              hipStream_t stream) {
  const float* x = (const float*)d_in[0];
  const float* w1 = (const float*)d_in[1];
  const float* b1 = (const float*)d_in[2];
  const float* bn1_g = (const float*)d_in[3];
  const float* bn1_b = (const float*)d_in[4];
  const float* w2 = (const float*)d_in[5];
  const float* b2 = (const float*)d_in[6];
  const float* bn2_g = (const float*)d_in[7];
  const float* bn2_b = (const float*)d_in[8];
  const float* cw1 = (const float*)d_in[9];
  const float* cb1 = (const float*)d_in[10];
  const float* gn1_g = (const float*)d_in[11];
  const float* gn1_b = (const float*)d_in[12];
  const float* gn2_g = (const float*)d_in[13];
  const float* gn2_b = (const float*)d_in[14];
  const float* cw2 = (const float*)d_in[15];
  const float* cb2 = (const float*)d_in[16];
  const float* gn3_g = (const float*)d_in[17];
  const float* gn3_b = (const float*)d_in[18];

  float* out = (float*)d_out;
  const size_t SZ = (size_t)16 * 256 * 4096;

  char* p = (char*)d_ws;
  unsigned short* Abf = (unsigned short*)p;  p += SZ * 2;
  float* Q = (float*)p;                      p += SZ * 4;
  unsigned short* XT = (unsigned short*)p;   p += (size_t)16 * 4098 * 256 * 2;
  unsigned short* APK1 = (unsigned short*)p; p += (size_t)16 * 24 * 64 * 8 * 2;
  unsigned short* APK2 = (unsigned short*)p; p += (size_t)16 * 24 * 64 * 8 * 2;
  unsigned short* APKS = (unsigned short*)p; p += (size_t)16 * 6 * 64 * 8 * 2;
  float* TP1 = (float*)p;                    p += 768 * 4;
  float* TP2 = (float*)p;                    p += 768 * 4;
  float* STATS = (float*)p;                  p += 1024 * 4;
  float* P1 = (float*)p;                     p += 32768 * 4;
  float* P2 = (float*)p;                     p += 32768 * 4;
  float* P3 = (float*)p;                     p += 32768 * 4;

  const int EW_BLOCKS = (int)(SZ / 4 / 256);  // 16384

  // ---- weight packing ----
  pack_big<<<96, 256, 0, stream>>>(cw1, APK1, TP1);
  pack_big<<<96, 256, 0, stream>>>(cw2, APK2, TP2);
  pack_stem<<<24, 256, 0, stream>>>(w2, APKS);

  // ---- stem ----
  conv1_kernel<<<16384, 256, 0, stream>>>(x, w1, b1, Abf);
  stats_bf16_kernel<<<64, 256, 0, stream>>>(Abf, STATS, 4096, 16, 64 * 4096, 4096, 1.f / 65536.f);
  act_transpose<64, 1, 0, true, false><<<1024, 256, 0, stream>>>(Abf, STATS, bn1_g, bn1_b, XT);
  gemm_conv<6, 1, 64, false, false, false><<<512, 512, 0, stream>>>(XT, APKS, nullptr, b2, 0.f, Q, nullptr);
  stats_kernel<<<256, 256, 0, stream>>>(Q, STATS, 4096, 16, 256 * 4096, 4096, 1.f / 65536.f);
  bn_apply<1, true><<<16384, 256, 0, stream>>>(Q, STATS, bn2_g, bn2_b, out, 255, P1);

  // ---- ODE: 8 steps of predictor + 2 correctors; GN stats flow via partials ----
  float* ycur = out;
  float* yoth = Q;
  const float H = 0.125f;
  for (int i = 0; i < 8; i++) {
    float t = i * H;
    unsigned short* Y1 = (unsigned short*)yoth;   // bf16 y1 overlays low half of yoth

    act_transpose<256, 0, 0, false, true><<<1024, 256, 0, stream>>>(ycur, P1, gn1_g, gn1_b, XT);
    gemm_conv<24, 3, 256, true, true, true><<<512, 512, 0, stream>>>(XT, APK1, TP1, cb1, t, Abf, P2);
    act_transpose<256, 0, 1, true, true><<<1024, 256, 0, stream>>>(Abf, P2, gn2_g, gn2_b, XT);
    gemm_conv<24, 3, 256, true, true, true><<<512, 512, 0, stream>>>(XT, APK2, TP2, cb2, t, Abf, P3);
    pred_combine<<<EW_BLOCKS, 256, 0, stream>>>(Abf, P3, gn3_g, gn3_b, ycur, Y1, P1);

    for (int c = 0; c < 2; c++) {
      act_transpose<256, 0, 0, true, true><<<1024, 256, 0, stream>>>(Y1, P1, gn1_g, gn1_b, XT);
      gemm_conv<24, 3, 256, true, true, true><<<512, 512, 0, stream>>>(XT, APK1, TP1, cb1, t + H, Abf, P2);
      act_transpose<256, 0, 1, true, true><<<1024, 256, 0, stream>>>(Abf, P2, gn2_g, gn2_b, XT);
      gemm_conv<24, 3, 256, true, true, true><<<512, 512, 0, stream>>>(XT, APK2, TP2, cb2, t + H, Abf, P3);
      if (c == 0)
        corr_combine<false><<<EW_BLOCKS, 256, 0, stream>>>(Abf, P3, gn3_g, gn3_b, ycur, Y1, P1);
      else
        corr_combine<true><<<EW_BLOCKS, 256, 0, stream>>>(Abf, P3, gn3_g, gn3_b, ycur, yoth, P1);
    }
    float* tmp = ycur;
    ycur = yoth;
    yoth = tmp;
  }
  // after 8 steps (even number of swaps) the final state is in d_out
}

// Round 6
// 2715.439 us; speedup vs baseline: 9.8058x; 1.2237x over previous
//
#include <hip/hip_runtime.h>
#include <math.h>

#define L4 4096

typedef short bf16x8 __attribute__((ext_vector_type(8)));
typedef float f32x4 __attribute__((ext_vector_type(4)));

__device__ __forceinline__ unsigned short f2bf(float f) {
  unsigned u = __builtin_bit_cast(unsigned, f);
  return (unsigned short)((u + 0x7FFFu + ((u >> 16) & 1u)) >> 16);
}
__device__ __forceinline__ float bf2f(unsigned short h) {
  unsigned u = ((unsigned)h) << 16;
  return __builtin_bit_cast(float, u);
}

// ---------------- pack big conv weights into A-fragment layout + t-channel ----------------
__global__ __launch_bounds__(256) void pack_big(const float* __restrict__ cw,
                                                unsigned short* __restrict__ Apack,
                                                float* __restrict__ Tpack) {
  int gid = blockIdx.x * 256 + threadIdx.x;
  if (gid < 768) {
    int o = gid & 255, tap = gid >> 8;
    Tpack[tap * 256 + o] = cw[((size_t)o * 257) * 9 + 3 + tap];
  }
  if (gid >= 16 * 24 * 64) return;
  int frow = gid / 1536;
  int rem = gid - frow * 1536;
  int ks = rem >> 6;
  int lane = rem & 63;
  int o = frow * 16 + (lane & 15);
  int tap = ks >> 3;
  int ib = ((ks & 7) << 5) + ((lane >> 4) << 3);
#pragma unroll
  for (int e = 0; e < 8; e++) {
    int i = ib + e;
    Apack[(size_t)gid * 8 + e] = f2bf(cw[((size_t)o * 257 + (i + 1)) * 9 + 3 + tap]);
  }
}

// ---------------- pack stem conv2 weights (64 in-ch) ----------------
__global__ __launch_bounds__(256) void pack_stem(const float* __restrict__ w2,
                                                 unsigned short* __restrict__ Apack) {
  int gid = blockIdx.x * 256 + threadIdx.x;
  if (gid >= 16 * 6 * 64) return;
  int frow = gid / 384;
  int rem = gid - frow * 384;
  int ks = rem >> 6;
  int lane = rem & 63;
  int o = frow * 16 + (lane & 15);
  int tap = ks >> 1;
  int ib = ((ks & 1) << 5) + ((lane >> 4) << 3);
#pragma unroll
  for (int e = 0; e < 8; e++) {
    int i = ib + e;
    Apack[(size_t)gid * 8 + e] = f2bf(w2[((size_t)o * 64 + i) * 3 + tap]);
  }
}

// ---------------- stem conv1: 4 -> 64, k=3, pad 1 (bf16 out) ----------------
__global__ __launch_bounds__(256) void conv1_kernel(const float* __restrict__ x,
                                                    const float* __restrict__ w,
                                                    const float* __restrict__ bias,
                                                    unsigned short* __restrict__ out) {
  int idx = blockIdx.x * 256 + threadIdx.x;
  int l = idx & 4095;
  int c = (idx >> 12) & 63;
  int b = idx >> 18;
  const float* xb = x + (size_t)b * 4 * L4;
  const float* wc = w + c * 12;
  float acc = bias[c];
#pragma unroll
  for (int i = 0; i < 4; i++) {
    float x0 = (l > 0) ? xb[i * L4 + l - 1] : 0.f;
    float x1 = xb[i * L4 + l];
    float x2 = (l < 4095) ? xb[i * L4 + l + 1] : 0.f;
    acc += wc[i * 3] * x0 + wc[i * 3 + 1] * x1 + wc[i * 3 + 2] * x2;
  }
  out[idx] = f2bf(acc);
}

// ---------------- mean/rstd stats (stem only), fp32 ----------------
__global__ __launch_bounds__(256) void stats_kernel(const float* __restrict__ in,
                                                    float* __restrict__ stats,
                                                    int unit_stride, int nrow,
                                                    int row_stride, int rowlen,
                                                    float inv_n) {
  int u = blockIdx.x;
  const float* base = in + (size_t)u * unit_stride;
  float s = 0.f, s2 = 0.f;
  for (int r = 0; r < nrow; r++) {
    const float* rowp = base + (size_t)r * row_stride;
    for (int j = threadIdx.x * 4; j < rowlen; j += 256 * 4) {
      float4 v = *(const float4*)(rowp + j);
      s += v.x + v.y + v.z + v.w;
      s2 += v.x * v.x + v.y * v.y + v.z * v.z + v.w * v.w;
    }
  }
  __shared__ float sh[512];
  sh[threadIdx.x] = s;
  sh[256 + threadIdx.x] = s2;
  __syncthreads();
  for (int off = 128; off > 0; off >>= 1) {
    if (threadIdx.x < off) {
      sh[threadIdx.x] += sh[threadIdx.x + off];
      sh[256 + threadIdx.x] += sh[256 + threadIdx.x + off];
    }
    __syncthreads();
  }
  if (threadIdx.x == 0) {
    float m = sh[0] * inv_n;
    float var = sh[256] * inv_n - m * m;
    stats[u * 2] = m;
    stats[u * 2 + 1] = rsqrtf(var + 1e-5f);
  }
}

// ---------------- mean/rstd stats (stem only), bf16 ----------------
__global__ __launch_bounds__(256) void stats_bf16_kernel(const unsigned short* __restrict__ in,
                                                         float* __restrict__ stats,
                                                         int unit_stride, int nrow,
                                                         int row_stride, int rowlen,
                                                         float inv_n) {
  int u = blockIdx.x;
  const unsigned short* base = in + (size_t)u * unit_stride;
  float s = 0.f, s2 = 0.f;
  for (int r = 0; r < nrow; r++) {
    const unsigned short* rowp = base + (size_t)r * row_stride;
    for (int j = threadIdx.x * 4; j < rowlen; j += 256 * 4) {
      ushort4 v = *(const ushort4*)(rowp + j);
      float va = bf2f(v.x), vb = bf2f(v.y), vc = bf2f(v.z), vd = bf2f(v.w);
      s += va + vb + vc + vd;
      s2 += va * va + vb * vb + vc * vc + vd * vd;
    }
  }
  __shared__ float sh[512];
  sh[threadIdx.x] = s;
  sh[256 + threadIdx.x] = s2;
  __syncthreads();
  for (int off = 128; off > 0; off >>= 1) {
    if (threadIdx.x < off) {
      sh[threadIdx.x] += sh[threadIdx.x + off];
      sh[256 + threadIdx.x] += sh[256 + threadIdx.x + off];
    }
    __syncthreads();
  }
  if (threadIdx.x == 0) {
    float m = sh[0] * inv_n;
    float var = sh[256] * inv_n - m * m;
    stats[u * 2] = m;
    stats[u * 2 + 1] = rsqrtf(var + 1e-5f);
  }
}

// ---------------- stem: BN1-affine + relu + bf16 + transpose to padded XT64 ----------------
__global__ __launch_bounds__(256) void act_transpose64(const unsigned short* __restrict__ inv,
                                                       const float* __restrict__ stats,
                                                       const float* __restrict__ gamma,
                                                       const float* __restrict__ beta,
                                                       unsigned short* __restrict__ Xt) {
  constexpr int C = 64;
  __shared__ unsigned short tile[64 * C];
  int bidx = blockIdx.x;
  int b = bidx >> 6;
  int lt = bidx & 63;
  int l0 = lt << 6;
  int t = threadIdx.x;
  int lanel = t & 63;
  int cq = t >> 6;
  for (int cp = 0; cp < C / 4; cp++) {
    int c = cp * 4 + cq;
    float m = stats[2 * c], rs = stats[2 * c + 1];
    float ga = gamma[c] * rs, be = beta[c] - m * ga;
    size_t gidx = ((size_t)b * C + c) * 4096 + l0 + lanel;
    float v = bf2f(inv[gidx]);
    float a = v * ga + be;
    float r = fmaxf(a, 0.f);
    int sw = (lanel & 15) << 2;
    tile[lanel * C + (c ^ sw)] = f2bf(r);
  }
  __syncthreads();
  constexpr int CH = C / 4;
  constexpr int RPP = 256 / CH;
  for (int p = 0; p < 64 / RPP; p++) {
    int r = p * RPP + t / CH;
    int ch = t % CH;
    int sw = (r & 15) << 2;
    ushort4 v = *(const ushort4*)&tile[r * C + ((ch * 4) ^ sw)];
    *(ushort4*)&Xt[((size_t)b * 4098 + 1 + l0 + r) * C + ch * 4] = v;
  }
  if (lt == 0) {
    if (t < C / 4) *(ushort4*)&Xt[((size_t)b * 4098 + 0) * C + t * 4] = make_ushort4(0, 0, 0, 0);
  } else if (lt == 63) {
    if (t < C / 4) *(ushort4*)&Xt[((size_t)b * 4098 + 4097) * C + t * 4] = make_ushort4(0, 0, 0, 0);
  }
}

// ---------------- fused MFMA conv-GEMM --------------------------------------------------
// Tile 256o x 64l, 512 thr (8 waves, wave = 32o x 64l). grid = 16b * 64 lt = 1024.
// NORM=1: B staged from raw T tensor [16][4096][CIN] with GN affine (from partials Pin,
//         NCH chunks) + activation (ACT 0=relu 1=elu) + boundary zeros, reg-staged.
// NORM=0: B staged from padded pre-activated XT [16][4098][CIN] bf16 (stem).
// OUT=0: epilogue writes T-layout bf16 [16][4096][256] + per-(b,g,lt) partials Pout.
// OUT=1: epilogue writes C-layout fp32 [16][256][4096] (stem).
template <int NKS, int KLG, int CIN, int NORM, int ACT, int NCH, bool INBF, bool TCH, int OUT>
__global__ __launch_bounds__(512, 4) void gemm_T(const void* __restrict__ Bsrc,
                                                 const unsigned short* __restrict__ Apack,
                                                 const float* __restrict__ Pin,
                                                 const float* __restrict__ gng,
                                                 const float* __restrict__ gnb,
                                                 const float* __restrict__ Tpack,
                                                 const float* __restrict__ bias,
                                                 float tval,
                                                 void* __restrict__ outv,
                                                 float* __restrict__ Pout) {
  constexpr int CPR = CIN / 8;
  constexpr int CPRLG = (CIN == 256) ? 5 : 3;
  constexpr int ROWS = 66;
  constexpr int TOT = ROWS * CPR;
  __shared__ unsigned short bsm[ROWS * CIN];
  __shared__ float gsm[32][2];
  __shared__ float gabe[NORM ? CIN : 1][2];
  __shared__ float psh[32][2];

  int tid = threadIdx.x;
  int lane = tid & 63;
  int wv = tid >> 6;
  int b = blockIdx.x >> 6;
  int lt = blockIdx.x & 63;
  int l_base = lt << 6;
  int wo0 = wv << 5;
  int col = lane & 15;
  int grp = lane >> 4;

  if (NORM) {
    if (tid < 32) {
      const float* Pg = Pin + ((size_t)b * 32 + tid) * 128;
      float s = 0.f, s2 = 0.f;
      for (int j = 0; j < NCH; j++) { s += Pg[j * 2]; s2 += Pg[j * 2 + 1]; }
      float m = s * (1.f / 32768.f);
      float var = s2 * (1.f / 32768.f) - m * m;
      gsm[tid][0] = m;
      gsm[tid][1] = rsqrtf(var + 1e-5f);
    }
    if (OUT == 0 && tid >= 64 && tid < 96) { psh[tid - 64][0] = 0.f; psh[tid - 64][1] = 0.f; }
    __syncthreads();
    if (tid < CIN) {
      float m = gsm[tid >> 3][0], rs = gsm[tid >> 3][1];
      float ga = gng[tid] * rs;
      gabe[tid][0] = ga;
      gabe[tid][1] = gnb[tid] - m * ga;
    }
    __syncthreads();
  } else {
    if (OUT == 0 && tid < 32) { psh[tid][0] = 0.f; psh[tid][1] = 0.f; }
  }

  // ---- stage B tile (66 rows), swizzled: LDS pos p holds global chunk p^(row&7) ----
  for (int it = 0; it < (TOT + 511) / 512; it++) {
    int chunk = it * 512 + tid;
    if (chunk < TOT) {
      int row = chunk >> CPRLG;
      int p = chunk & (CPR - 1);
      bf16x8 o8;
      if (NORM) {
        int g = p ^ (row & 7);
        int gl = l_base - 1 + row;
        if (gl >= 0 && gl < 4096) {
          size_t base = ((size_t)b * 4096 + gl) * CIN + g * 8;
          float vv[8];
          if (INBF) {
            bf16x8 raw = *(const bf16x8*)((const unsigned short*)Bsrc + base);
#pragma unroll
            for (int e = 0; e < 8; e++) vv[e] = bf2f((unsigned short)raw[e]);
          } else {
            float4 r0 = *(const float4*)((const float*)Bsrc + base);
            float4 r1 = *(const float4*)((const float*)Bsrc + base + 4);
            vv[0] = r0.x; vv[1] = r0.y; vv[2] = r0.z; vv[3] = r0.w;
            vv[4] = r1.x; vv[5] = r1.y; vv[6] = r1.z; vv[7] = r1.w;
          }
#pragma unroll
          for (int e = 0; e < 8; e++) {
            float a = vv[e] * gabe[g * 8 + e][0] + gabe[g * 8 + e][1];
            float r = (ACT == 0) ? fmaxf(a, 0.f) : (a > 0.f ? a : expm1f(a));
            o8[e] = (short)f2bf(r);
          }
        } else {
          o8 = (bf16x8){0, 0, 0, 0, 0, 0, 0, 0};
        }
      } else {
        int c = p ^ (row & 7);
        o8 = *(const bf16x8*)((const unsigned short*)Bsrc +
                              ((size_t)b * 4098 + l_base + row) * CIN + c * 8);
      }
      *(bf16x8*)&bsm[(size_t)chunk * 8] = o8;
    }
  }
  __syncthreads();

  const unsigned short* apk = Apack + ((size_t)(wv * 2) * NKS) * 512 + (size_t)lane * 8;

  f32x4 acc[2][4];
#pragma unroll
  for (int i = 0; i < 2; i++)
#pragma unroll
    for (int j = 0; j < 4; j++) acc[i][j] = (f32x4){0.f, 0.f, 0.f, 0.f};

#pragma unroll 2
  for (int ks = 0; ks < NKS; ks++) {
    int tap = ks >> KLG;
    int cbase = (ks & ((1 << KLG) - 1)) << 2;
    bf16x8 bfr[4], afr[2];
#pragma unroll
    for (int fc = 0; fc < 4; fc++) {
      int lr = col + fc * 16 + tap;
      int cb = (cbase + grp) ^ (lr & 7);
      bfr[fc] = *(const bf16x8*)&bsm[((size_t)(lr << CPRLG) + cb) * 8];
    }
#pragma unroll
    for (int fo = 0; fo < 2; fo++)
      afr[fo] = *(const bf16x8*)(apk + ((size_t)fo * NKS + ks) * 512);
#pragma unroll
    for (int fo = 0; fo < 2; fo++)
#pragma unroll
      for (int fc = 0; fc < 4; fc++)
        acc[fo][fc] = __builtin_amdgcn_mfma_f32_16x16x32_bf16(afr[fo], bfr[fc], acc[fo][fc], 0, 0, 0);
  }

  // ---- epilogue ----
  float ps = 0.f, ps2 = 0.f;
#pragma unroll
  for (int fo = 0; fo < 2; fo++) {
    int o0 = wo0 + fo * 16 + grp * 4;
    float bs[4], w0t[4], w1t[4], w2t[4];
#pragma unroll
    for (int r = 0; r < 4; r++) {
      bs[r] = bias[o0 + r];
      if (TCH) { w0t[r] = Tpack[o0 + r]; w1t[r] = Tpack[256 + o0 + r]; w2t[r] = Tpack[512 + o0 + r]; }
    }
#pragma unroll
    for (int fc = 0; fc < 4; fc++) {
      int l = l_base + fc * 16 + col;
      float v[4];
#pragma unroll
      for (int r = 0; r < 4; r++) {
        v[r] = acc[fo][fc][r] + bs[r];
        if (TCH) {
          float tc = w1t[r] + (l > 0 ? w0t[r] : 0.f) + (l < 4095 ? w2t[r] : 0.f);
          v[r] += tval * tc;
        }
        if (OUT == 0) { ps += v[r]; ps2 += v[r] * v[r]; }
      }
      if (OUT == 0) {
        ushort4 pk;
        pk.x = f2bf(v[0]); pk.y = f2bf(v[1]); pk.z = f2bf(v[2]); pk.w = f2bf(v[3]);
        *(ushort4*)((unsigned short*)outv + ((size_t)b * 4096 + l) * 256 + o0) = pk;
      } else {
#pragma unroll
        for (int r = 0; r < 4; r++)
          ((float*)outv)[((size_t)b * 256 + o0 + r) * 4096 + l] = v[r];
      }
    }
    if (OUT == 0) {
      // all 16 of this lane's v's (this fo) are in group g:
      float s = ps, s2 = ps2;
#pragma unroll
      for (int off = 8; off; off >>= 1) {
        s += __shfl_down(s, off, 16);
        s2 += __shfl_down(s2, off, 16);
      }
      if (col == 0) {
        int g = wv * 4 + fo * 2 + (grp >> 1);
        atomicAdd(&psh[g][0], s);
        atomicAdd(&psh[g][1], s2);
      }
      ps = 0.f; ps2 = 0.f;
    }
  }

  if (OUT == 0) {
    __syncthreads();
    if (tid < 32) {
      size_t pi = ((size_t)b * 32 + tid) * 128 + (size_t)lt * 2;
      Pout[pi] = psh[tid][0];
      Pout[pi + 1] = psh[tid][1];
    }
  }
}

// ---------------- stem: BN2-affine + tanh, C->T transpose, y0 fp32 + P1 partials --------
__global__ __launch_bounds__(512) void bn_tanh_T(const float* __restrict__ Q,
                                                 const float* __restrict__ stats,
                                                 const float* __restrict__ gamma,
                                                 const float* __restrict__ beta,
                                                 float* __restrict__ Y,
                                                 float* __restrict__ P1) {
  int tid = threadIdx.x;
  int b = blockIdx.x >> 5;
  int seg = blockIdx.x & 31;
  int c = tid >> 1;
  float m = stats[2 * c], rs = stats[2 * c + 1];
  float ga = gamma[c] * rs, be = beta[c] - m * ga;
  __shared__ float psh[32][2];
  if (tid < 32) { psh[tid][0] = 0.f; psh[tid][1] = 0.f; }
  __syncthreads();
  float s = 0.f, s2 = 0.f;
  for (int it = 0; it < 16; it++) {
    int l4 = (tid & 1) + it * 2;
    int l0 = seg * 128 + l4 * 4;
    float4 v = *(const float4*)&Q[((size_t)b * 256 + c) * 4096 + l0];
    float r0 = tanhf(v.x * ga + be);
    float r1 = tanhf(v.y * ga + be);
    float r2 = tanhf(v.z * ga + be);
    float r3 = tanhf(v.w * ga + be);
    Y[((size_t)b * 4096 + l0 + 0) * 256 + c] = r0;
    Y[((size_t)b * 4096 + l0 + 1) * 256 + c] = r1;
    Y[((size_t)b * 4096 + l0 + 2) * 256 + c] = r2;
    Y[((size_t)b * 4096 + l0 + 3) * 256 + c] = r3;
    s += r0 + r1 + r2 + r3;
    s2 += r0 * r0 + r1 * r1 + r2 * r2 + r3 * r3;
  }
#pragma unroll
  for (int off = 8; off; off >>= 1) { s += __shfl_down(s, off, 16); s2 += __shfl_down(s2, off, 16); }
  if ((tid & 15) == 0) {
    int g = c >> 3;
    atomicAdd(&psh[g][0], s);
    atomicAdd(&psh[g][1], s2);
  }
  __syncthreads();
  if (tid < 32) {
    size_t pi = ((size_t)b * 32 + tid) * 128 + (size_t)seg * 2;
    P1[pi] = psh[tid][0];
    P1[pi + 1] = psh[tid][1];
  }
}

// ---------------- combine (T layout): GN3-affine(F) + Heun update + P1 partials ----------
// MODE 0 (pred):  ybase = Y + h/2*f (in-place Y);  y1 = Y + h*f -> Y1 bf16; partials of y1
// MODE 1 (corr):  yn = Y(=ybase) + h/2*f -> Y1 bf16; partials of yn
// MODE 2 (final): yn = Y(=ybase) + h/2*f -> Y fp32 in-place; partials of yn
template <int MODE>
__global__ __launch_bounds__(512) void combine_T(const unsigned short* __restrict__ F,
                                                 const float* __restrict__ P3,
                                                 const float* __restrict__ gng,
                                                 const float* __restrict__ gnb,
                                                 float* __restrict__ Y,
                                                 unsigned short* __restrict__ Y1,
                                                 float* __restrict__ P1) {
  __shared__ float gsm[32][2];
  __shared__ float gabe[256][2];
  __shared__ float psh[32][2];
  int tid = threadIdx.x;
  int b = blockIdx.x >> 5;
  int seg = blockIdx.x & 31;
  if (tid < 32) {
    const float* Pg = P3 + ((size_t)b * 32 + tid) * 128;
    float s = 0.f, s2 = 0.f;
    for (int j = 0; j < 64; j++) { s += Pg[j * 2]; s2 += Pg[j * 2 + 1]; }
    float m = s * (1.f / 32768.f);
    float var = s2 * (1.f / 32768.f) - m * m;
    gsm[tid][0] = m;
    gsm[tid][1] = rsqrtf(var + 1e-5f);
  }
  if (tid >= 64 && tid < 96) { psh[tid - 64][0] = 0.f; psh[tid - 64][1] = 0.f; }
  __syncthreads();
  if (tid < 256) {
    float m = gsm[tid >> 3][0], rs = gsm[tid >> 3][1];
    float ga = gng[tid] * rs;
    gabe[tid][0] = ga;
    gabe[tid][1] = gnb[tid] - m * ga;
  }
  __syncthreads();

  size_t base4 = ((size_t)b * 4096 + seg * 128) * 64;
  int c0 = (tid << 2) & 255;
  int g = c0 >> 3;
  float ga0 = gabe[c0][0], be0 = gabe[c0][1];
  float ga1 = gabe[c0 + 1][0], be1 = gabe[c0 + 1][1];
  float ga2 = gabe[c0 + 2][0], be2 = gabe[c0 + 2][1];
  float ga3 = gabe[c0 + 3][0], be3 = gabe[c0 + 3][1];
  float s = 0.f, s2 = 0.f;
  for (int i = tid; i < 8192; i += 512) {
    size_t idx4 = base4 + i;
    ushort4 fv = ((const ushort4*)F)[idx4];
    float4 yv = ((const float4*)Y)[idx4];
    float f0 = bf2f(fv.x) * ga0 + be0;
    float f1 = bf2f(fv.y) * ga1 + be1;
    float f2 = bf2f(fv.z) * ga2 + be2;
    float f3 = bf2f(fv.w) * ga3 + be3;
    float4 yn;
    yn.x = yv.x + (MODE == 0 ? 0.125f : 0.0625f) * f0;
    yn.y = yv.y + (MODE == 0 ? 0.125f : 0.0625f) * f1;
    yn.z = yv.z + (MODE == 0 ? 0.125f : 0.0625f) * f2;
    yn.w = yv.w + (MODE == 0 ? 0.125f : 0.0625f) * f3;
    if (MODE == 0) {
      float4 yb;
      yb.x = yv.x + 0.0625f * f0;
      yb.y = yv.y + 0.0625f * f1;
      yb.z = yv.z + 0.0625f * f2;
      yb.w = yv.w + 0.0625f * f3;
      ((float4*)Y)[idx4] = yb;
    }
    if (MODE == 2) {
      ((float4*)Y)[idx4] = yn;
    } else {
      ushort4 pk;
      pk.x = f2bf(yn.x); pk.y = f2bf(yn.y); pk.z = f2bf(yn.z); pk.w = f2bf(yn.w);
      ((ushort4*)Y1)[idx4] = pk;
    }
    s += yn.x + yn.y + yn.z + yn.w;
    s2 += yn.x * yn.x + yn.y * yn.y + yn.z * yn.z + yn.w * yn.w;
  }
  s += __shfl_xor(s, 1);
  s2 += __shfl_xor(s2, 1);
  if ((tid & 1) == 0) {
    atomicAdd(&psh[g][0], s);
    atomicAdd(&psh[g][1], s2);
  }
  __syncthreads();
  if (tid < 32) {
    size_t pi = ((size_t)b * 32 + tid) * 128 + (size_t)seg * 2;
    P1[pi] = psh[tid][0];
    P1[pi + 1] = psh[tid][1];
  }
}

// ---------------- final: T-layout fp32 -> C-layout fp32 (d_out) ----------------
__global__ __launch_bounds__(256) void transpose_final(const float* __restrict__ Y,
                                                       float* __restrict__ out) {
  __shared__ float tile[64 * 260];
  int b = blockIdx.x >> 6;
  int lt = blockIdx.x & 63;
  int t = threadIdx.x;
  for (int i = t; i < 4096; i += 256) {
    int r = i >> 6;
    int c4 = (i & 63) << 2;
    float4 v = *(const float4*)&Y[((size_t)b * 4096 + lt * 64 + r) * 256 + c4];
    *(float4*)&tile[r * 260 + c4] = v;
  }
  __syncthreads();
  for (int i = t; i < 4096; i += 256) {
    int c = i >> 4;
    int l4 = (i & 15) << 2;
    float4 v;
    v.x = tile[(l4 + 0) * 260 + c];
    v.y = tile[(l4 + 1) * 260 + c];
    v.z = tile[(l4 + 2) * 260 + c];
    v.w = tile[(l4 + 3) * 260 + c];
    *(float4*)&out[((size_t)b * 256 + c) * 4096 + lt * 64 + l4] = v;
  }
}

extern "C" void kernel_launch(void* const* d_in, const int* in_sizes, int n_in,
                              void* d_out, int out_size, void* d_ws, size_t ws_size,
                              hipStream_t stream) {
  const float* x = (const float*)d_in[0];
  const float* w1 = (const float*)d_in[1];
  const float* b1 = (const float*)d_in[2];
  const float* bn1_g = (const float*)d_in[3];
  const float* bn1_b = (const float*)d_in[4];
  const float* w2 = (const float*)d_in[5];
  const float* b2 = (const float*)d_in[6];
  const float* bn2_g = (const float*)d_in[7];
  const float* bn2_b = (const float*)d_in[8];
  const float* cw1 = (const float*)d_in[9];
  const float* cb1 = (const float*)d_in[10];
  const float* gn1_g = (const float*)d_in[11];
  const float* gn1_b = (const float*)d_in[12];
  const float* gn2_g = (const float*)d_in[13];
  const float* gn2_b = (const float*)d_in[14];
  const float* cw2 = (const float*)d_in[15];
  const float* cb2 = (const float*)d_in[16];
  const float* gn3_g = (const float*)d_in[17];
  const float* gn3_b = (const float*)d_in[18];

  const size_t SZ = (size_t)16 * 256 * 4096;

  char* p = (char*)d_ws;
  float* Ybuf = (float*)p;                   p += SZ * 4;          // fp32 T state
  unsigned short* C1 = (unsigned short*)p;   p += SZ * 2;          // bf16 T conv1-out
  unsigned short* Fb = (unsigned short*)p;   p += SZ * 2;          // bf16 T conv2-out / stem XT64
  unsigned short* APK1 = (unsigned short*)p; p += (size_t)16 * 24 * 64 * 8 * 2;
  unsigned short* APK2 = (unsigned short*)p; p += (size_t)16 * 24 * 64 * 8 * 2;
  unsigned short* APKS = (unsigned short*)p; p += (size_t)16 * 6 * 64 * 8 * 2;
  float* TP1 = (float*)p;                    p += 768 * 4;
  float* TP2 = (float*)p;                    p += 768 * 4;
  float* STATS = (float*)p;                  p += 1024 * 4;
  float* P1 = (float*)p;                     p += (size_t)16 * 32 * 128 * 4;
  float* P2 = (float*)p;                     p += (size_t)16 * 32 * 128 * 4;
  float* P3 = (float*)p;                     p += (size_t)16 * 32 * 128 * 4;
  // total ~130 MB

  float* Q = (float*)d_out;                  // stem conv2-out scratch (C layout fp32)
  unsigned short* Y1 = (unsigned short*)d_out;  // ODE bf16 y1 scratch (first 32MB)

  // ---- weight packing ----
  pack_big<<<96, 256, 0, stream>>>(cw1, APK1, TP1);
  pack_big<<<96, 256, 0, stream>>>(cw2, APK2, TP2);
  pack_stem<<<24, 256, 0, stream>>>(w2, APKS);

  // ---- stem ----
  conv1_kernel<<<16384, 256, 0, stream>>>(x, w1, b1, C1);
  stats_bf16_kernel<<<64, 256, 0, stream>>>(C1, STATS, 4096, 16, 64 * 4096, 4096, 1.f / 65536.f);
  act_transpose64<<<1024, 256, 0, stream>>>(C1, STATS, bn1_g, bn1_b, Fb);
  gemm_T<6, 1, 64, 0, 0, 32, true, false, 1><<<1024, 512, 0, stream>>>(
      Fb, APKS, nullptr, nullptr, nullptr, nullptr, b2, 0.f, Q, nullptr);
  stats_kernel<<<256, 256, 0, stream>>>(Q, STATS, 4096, 16, 256 * 4096, 4096, 1.f / 65536.f);
  bn_tanh_T<<<512, 512, 0, stream>>>(Q, STATS, bn2_g, bn2_b, Ybuf, P1);

  // ---- ODE: 8 steps (pred + 2 corr), all in T layout; state fixed in Ybuf ----
  const float H = 0.125f;
  for (int i = 0; i < 8; i++) {
    float t = i * H;
    // predictor: f(t, y)  [y fp32 in Ybuf, GN1 partials in P1]
    gemm_T<24, 3, 256, 1, 0, 32, false, true, 0><<<1024, 512, 0, stream>>>(
        Ybuf, APK1, P1, gn1_g, gn1_b, TP1, cb1, t, C1, P2);
    gemm_T<24, 3, 256, 1, 1, 64, true, true, 0><<<1024, 512, 0, stream>>>(
        C1, APK2, P2, gn2_g, gn2_b, TP2, cb2, t, Fb, P3);
    combine_T<0><<<512, 512, 0, stream>>>(Fb, P3, gn3_g, gn3_b, Ybuf, Y1, P1);
    // correctors: f(t+h, y1)  [y1 bf16 in Y1]
    for (int c = 0; c < 2; c++) {
      gemm_T<24, 3, 256, 1, 0, 32, true, true, 0><<<1024, 512, 0, stream>>>(
          Y1, APK1, P1, gn1_g, gn1_b, TP1, cb1, t + H, C1, P2);
      gemm_T<24, 3, 256, 1, 1, 64, true, true, 0><<<1024, 512, 0, stream>>>(
          C1, APK2, P2, gn2_g, gn2_b, TP2, cb2, t + H, Fb, P3);
      if (c == 0)
        combine_T<1><<<512, 512, 0, stream>>>(Fb, P3, gn3_g, gn3_b, Ybuf, Y1, P1);
      else
        combine_T<2><<<512, 512, 0, stream>>>(Fb, P3, gn3_g, gn3_b, Ybuf, Y1, P1);
    }
  }

  // ---- final: transpose T state -> d_out C layout ----
  transpose_final<<<1024, 256, 0, stream>>>(Ybuf, (float*)d_out);
}

// Round 7
// 2649.946 us; speedup vs baseline: 10.0482x; 1.0247x over previous
//
#include <hip/hip_runtime.h>
#include <math.h>

#define L4 4096

typedef short bf16x8 __attribute__((ext_vector_type(8)));
typedef float f32x4 __attribute__((ext_vector_type(4)));

__device__ __forceinline__ unsigned short f2bf(float f) {
  unsigned u = __builtin_bit_cast(unsigned, f);
  return (unsigned short)((u + 0x7FFFu + ((u >> 16) & 1u)) >> 16);
}
__device__ __forceinline__ float bf2f(unsigned short h) {
  unsigned u = ((unsigned)h) << 16;
  return __builtin_bit_cast(float, u);
}

// ---------------- pack big conv weights into A-fragment layout + t-channel ----------------
__global__ __launch_bounds__(256) void pack_big(const float* __restrict__ cw,
                                                unsigned short* __restrict__ Apack,
                                                float* __restrict__ Tpack) {
  int gid = blockIdx.x * 256 + threadIdx.x;
  if (gid < 768) {
    int o = gid & 255, tap = gid >> 8;
    Tpack[tap * 256 + o] = cw[((size_t)o * 257) * 9 + 3 + tap];
  }
  if (gid >= 16 * 24 * 64) return;
  int frow = gid / 1536;
  int rem = gid - frow * 1536;
  int ks = rem >> 6;
  int lane = rem & 63;
  int o = frow * 16 + (lane & 15);
  int tap = ks >> 3;
  int ib = ((ks & 7) << 5) + ((lane >> 4) << 3);
#pragma unroll
  for (int e = 0; e < 8; e++) {
    int i = ib + e;
    Apack[(size_t)gid * 8 + e] = f2bf(cw[((size_t)o * 257 + (i + 1)) * 9 + 3 + tap]);
  }
}

// ---------------- pack stem conv2 weights (64 in-ch) ----------------
__global__ __launch_bounds__(256) void pack_stem(const float* __restrict__ w2,
                                                 unsigned short* __restrict__ Apack) {
  int gid = blockIdx.x * 256 + threadIdx.x;
  if (gid >= 16 * 6 * 64) return;
  int frow = gid / 384;
  int rem = gid - frow * 384;
  int ks = rem >> 6;
  int lane = rem & 63;
  int o = frow * 16 + (lane & 15);
  int tap = ks >> 1;
  int ib = ((ks & 1) << 5) + ((lane >> 4) << 3);
#pragma unroll
  for (int e = 0; e < 8; e++) {
    int i = ib + e;
    Apack[(size_t)gid * 8 + e] = f2bf(w2[((size_t)o * 64 + i) * 3 + tap]);
  }
}

// ---------------- stem conv1: 4 -> 64, k=3, pad 1 (bf16 out) ----------------
__global__ __launch_bounds__(256) void conv1_kernel(const float* __restrict__ x,
                                                    const float* __restrict__ w,
                                                    const float* __restrict__ bias,
                                                    unsigned short* __restrict__ out) {
  int idx = blockIdx.x * 256 + threadIdx.x;
  int l = idx & 4095;
  int c = (idx >> 12) & 63;
  int b = idx >> 18;
  const float* xb = x + (size_t)b * 4 * L4;
  const float* wc = w + c * 12;
  float acc = bias[c];
#pragma unroll
  for (int i = 0; i < 4; i++) {
    float x0 = (l > 0) ? xb[i * L4 + l - 1] : 0.f;
    float x1 = xb[i * L4 + l];
    float x2 = (l < 4095) ? xb[i * L4 + l + 1] : 0.f;
    acc += wc[i * 3] * x0 + wc[i * 3 + 1] * x1 + wc[i * 3 + 2] * x2;
  }
  out[idx] = f2bf(acc);
}

// ---------------- mean/rstd stats (stem only), fp32 ----------------
__global__ __launch_bounds__(256) void stats_kernel(const float* __restrict__ in,
                                                    float* __restrict__ stats,
                                                    int unit_stride, int nrow,
                                                    int row_stride, int rowlen,
                                                    float inv_n) {
  int u = blockIdx.x;
  const float* base = in + (size_t)u * unit_stride;
  float s = 0.f, s2 = 0.f;
  for (int r = 0; r < nrow; r++) {
    const float* rowp = base + (size_t)r * row_stride;
    for (int j = threadIdx.x * 4; j < rowlen; j += 256 * 4) {
      float4 v = *(const float4*)(rowp + j);
      s += v.x + v.y + v.z + v.w;
      s2 += v.x * v.x + v.y * v.y + v.z * v.z + v.w * v.w;
    }
  }
  __shared__ float sh[512];
  sh[threadIdx.x] = s;
  sh[256 + threadIdx.x] = s2;
  __syncthreads();
  for (int off = 128; off > 0; off >>= 1) {
    if (threadIdx.x < off) {
      sh[threadIdx.x] += sh[threadIdx.x + off];
      sh[256 + threadIdx.x] += sh[256 + threadIdx.x + off];
    }
    __syncthreads();
  }
  if (threadIdx.x == 0) {
    float m = sh[0] * inv_n;
    float var = sh[256] * inv_n - m * m;
    stats[u * 2] = m;
    stats[u * 2 + 1] = rsqrtf(var + 1e-5f);
  }
}

// ---------------- mean/rstd stats (stem only), bf16 ----------------
__global__ __launch_bounds__(256) void stats_bf16_kernel(const unsigned short* __restrict__ in,
                                                         float* __restrict__ stats,
                                                         int unit_stride, int nrow,
                                                         int row_stride, int rowlen,
                                                         float inv_n) {
  int u = blockIdx.x;
  const unsigned short* base = in + (size_t)u * unit_stride;
  float s = 0.f, s2 = 0.f;
  for (int r = 0; r < nrow; r++) {
    const unsigned short* rowp = base + (size_t)r * row_stride;
    for (int j = threadIdx.x * 4; j < rowlen; j += 256 * 4) {
      ushort4 v = *(const ushort4*)(rowp + j);
      float va = bf2f(v.x), vb = bf2f(v.y), vc = bf2f(v.z), vd = bf2f(v.w);
      s += va + vb + vc + vd;
      s2 += va * va + vb * vb + vc * vc + vd * vd;
    }
  }
  __shared__ float sh[512];
  sh[threadIdx.x] = s;
  sh[256 + threadIdx.x] = s2;
  __syncthreads();
  for (int off = 128; off > 0; off >>= 1) {
    if (threadIdx.x < off) {
      sh[threadIdx.x] += sh[threadIdx.x + off];
      sh[256 + threadIdx.x] += sh[256 + threadIdx.x + off];
    }
    __syncthreads();
  }
  if (threadIdx.x == 0) {
    float m = sh[0] * inv_n;
    float var = sh[256] * inv_n - m * m;
    stats[u * 2] = m;
    stats[u * 2 + 1] = rsqrtf(var + 1e-5f);
  }
}

// ---------------- stem: BN1-affine + relu + bf16 + transpose to padded XT64 ----------------
__global__ __launch_bounds__(256) void act_transpose64(const unsigned short* __restrict__ inv,
                                                       const float* __restrict__ stats,
                                                       const float* __restrict__ gamma,
                                                       const float* __restrict__ beta,
                                                       unsigned short* __restrict__ Xt) {
  constexpr int C = 64;
  __shared__ unsigned short tile[64 * C];
  int bidx = blockIdx.x;
  int b = bidx >> 6;
  int lt = bidx & 63;
  int l0 = lt << 6;
  int t = threadIdx.x;
  int lanel = t & 63;
  int cq = t >> 6;
  for (int cp = 0; cp < C / 4; cp++) {
    int c = cp * 4 + cq;
    float m = stats[2 * c], rs = stats[2 * c + 1];
    float ga = gamma[c] * rs, be = beta[c] - m * ga;
    size_t gidx = ((size_t)b * C + c) * 4096 + l0 + lanel;
    float v = bf2f(inv[gidx]);
    float a = v * ga + be;
    float r = fmaxf(a, 0.f);
    int sw = (lanel & 15) << 2;
    tile[lanel * C + (c ^ sw)] = f2bf(r);
  }
  __syncthreads();
  constexpr int CH = C / 4;
  constexpr int RPP = 256 / CH;
  for (int p = 0; p < 64 / RPP; p++) {
    int r = p * RPP + t / CH;
    int ch = t % CH;
    int sw = (r & 15) << 2;
    ushort4 v = *(const ushort4*)&tile[r * C + ((ch * 4) ^ sw)];
    *(ushort4*)&Xt[((size_t)b * 4098 + 1 + l0 + r) * C + ch * 4] = v;
  }
  if (lt == 0) {
    if (t < C / 4) *(ushort4*)&Xt[((size_t)b * 4098 + 0) * C + t * 4] = make_ushort4(0, 0, 0, 0);
  } else if (lt == 63) {
    if (t < C / 4) *(ushort4*)&Xt[((size_t)b * 4098 + 4097) * C + t * 4] = make_ushort4(0, 0, 0, 0);
  }
}

// ---------------- fused MFMA conv-GEMM --------------------------------------------------
// Tile 256o x 64l, 512 thr (8 waves, wave = 32o x 64l). grid = 16b * 64 lt = 1024.
// NORM=1: B staged from raw T tensor with GN affine (gamma/beta in REGISTERS, fixed
//         channel chunk per lane) + activation + boundary zeros; swizzle on WRITE side.
// OUT=0: T-layout bf16 out + per-(b,g,lt) partials.  OUT=1: C-layout fp32 out (stem).
template <int NKS, int KLG, int CIN, int NORM, int ACT, int NCH, bool INBF, bool TCH, int OUT>
__global__ __launch_bounds__(512, 4) void gemm_T(const void* __restrict__ Bsrc,
                                                 const unsigned short* __restrict__ Apack,
                                                 const float* __restrict__ Pin,
                                                 const float* __restrict__ gng,
                                                 const float* __restrict__ gnb,
                                                 const float* __restrict__ Tpack,
                                                 const float* __restrict__ bias,
                                                 float tval,
                                                 void* __restrict__ outv,
                                                 float* __restrict__ Pout) {
  constexpr int CPR = CIN / 8;
  constexpr int CPRLG = (CIN == 256) ? 5 : 3;
  constexpr int ROWS = 66;
  constexpr int RPI = 512 >> CPRLG;   // rows staged per iteration
  __shared__ unsigned short bsm[ROWS * CIN];
  __shared__ float gsm[32][2];
  __shared__ float ebias[256];
  __shared__ float psh[32][2];

  int tid = threadIdx.x;
  int lane = tid & 63;
  int wv = tid >> 6;
  int b = blockIdx.x >> 6;
  int lt = blockIdx.x & 63;
  int l_base = lt << 6;
  int wo0 = wv << 5;
  int col = lane & 15;
  int grp = lane >> 4;

  // ---- phase 0: parallel GN-stat reduce + ebias precompute ----
  if (NORM) {
    int g = tid >> 4, j0 = tid & 15;
    const float* Pg = Pin + ((size_t)b * 32 + g) * 128;
    float s = 0.f, s2 = 0.f;
    for (int j = j0; j < NCH; j += 16) { s += Pg[j * 2]; s2 += Pg[j * 2 + 1]; }
#pragma unroll
    for (int off = 8; off; off >>= 1) { s += __shfl_down(s, off, 16); s2 += __shfl_down(s2, off, 16); }
    if (j0 == 0) {
      float m = s * (1.f / 32768.f);
      float var = s2 * (1.f / 32768.f) - m * m;
      gsm[g][0] = m;
      gsm[g][1] = rsqrtf(var + 1e-5f);
    }
  }
  if (tid < 256) {
    float e = bias[tid];
    if (TCH) e += tval * (Tpack[tid] + Tpack[256 + tid] + Tpack[512 + tid]);
    ebias[tid] = e;
  }
  if (OUT == 0 && tid >= 256 && tid < 288) { psh[tid - 256][0] = 0.f; psh[tid - 256][1] = 0.f; }
  __syncthreads();

  // ---- phase 1: stage B tile; lane owns fixed channel-chunk pl, swizzle on write ----
  {
    int pl = tid & (CPR - 1);
    int rowbase = tid >> CPRLG;
    float ga[8], be[8];
    if (NORM) {
      float m = gsm[pl][0], rs = gsm[pl][1];
      float4 g0 = *(const float4*)&gng[pl * 8];
      float4 g1 = *(const float4*)&gng[pl * 8 + 4];
      float4 b0 = *(const float4*)&gnb[pl * 8];
      float4 b1 = *(const float4*)&gnb[pl * 8 + 4];
      const float* gp = &g0.x;
      const float* bp = &b0.x;
      ga[0] = g0.x * rs; ga[1] = g0.y * rs; ga[2] = g0.z * rs; ga[3] = g0.w * rs;
      ga[4] = g1.x * rs; ga[5] = g1.y * rs; ga[6] = g1.z * rs; ga[7] = g1.w * rs;
      be[0] = b0.x - m * ga[0]; be[1] = b0.y - m * ga[1];
      be[2] = b0.z - m * ga[2]; be[3] = b0.w - m * ga[3];
      be[4] = b1.x - m * ga[4]; be[5] = b1.y - m * ga[5];
      be[6] = b1.z - m * ga[6]; be[7] = b1.w - m * ga[7];
      (void)gp; (void)bp;
    }
#pragma unroll
    for (int it = 0; it < (ROWS + RPI - 1) / RPI; it++) {
      int row = rowbase + it * RPI;
      if (row < ROWS) {
        int wchunk = (row << CPRLG) | (pl ^ (row & 7));
        bf16x8 o8;
        if (NORM) {
          int gl = l_base - 1 + row;
          if (gl >= 0 && gl < 4096) {
            size_t base = ((size_t)b * 4096 + gl) * CIN + pl * 8;
            float vv[8];
            if (INBF) {
              bf16x8 raw = *(const bf16x8*)((const unsigned short*)Bsrc + base);
#pragma unroll
              for (int e = 0; e < 8; e++) vv[e] = bf2f((unsigned short)raw[e]);
            } else {
              float4 r0 = *(const float4*)((const float*)Bsrc + base);
              float4 r1 = *(const float4*)((const float*)Bsrc + base + 4);
              vv[0] = r0.x; vv[1] = r0.y; vv[2] = r0.z; vv[3] = r0.w;
              vv[4] = r1.x; vv[5] = r1.y; vv[6] = r1.z; vv[7] = r1.w;
            }
#pragma unroll
            for (int e = 0; e < 8; e++) {
              float a = vv[e] * ga[e] + be[e];
              float r = (ACT == 0) ? fmaxf(a, 0.f) : (a > 0.f ? a : expm1f(a));
              o8[e] = (short)f2bf(r);
            }
          } else {
            o8 = (bf16x8){0, 0, 0, 0, 0, 0, 0, 0};
          }
        } else {
          o8 = *(const bf16x8*)((const unsigned short*)Bsrc +
                                ((size_t)b * 4098 + l_base + row) * CIN + pl * 8);
        }
        *(bf16x8*)&bsm[(size_t)wchunk * 8] = o8;
      }
    }
  }
  __syncthreads();

  // ---- phase 2: MFMA loop ----
  const unsigned short* apk = Apack + ((size_t)(wv * 2) * NKS) * 512 + (size_t)lane * 8;

  f32x4 acc[2][4];
#pragma unroll
  for (int i = 0; i < 2; i++)
#pragma unroll
    for (int j = 0; j < 4; j++) acc[i][j] = (f32x4){0.f, 0.f, 0.f, 0.f};

#pragma unroll 2
  for (int ks = 0; ks < NKS; ks++) {
    int tap = ks >> KLG;
    int cbase = (ks & ((1 << KLG) - 1)) << 2;
    bf16x8 bfr[4], afr[2];
#pragma unroll
    for (int fc = 0; fc < 4; fc++) {
      int lr = col + fc * 16 + tap;
      int cb = (cbase + grp) ^ (lr & 7);
      bfr[fc] = *(const bf16x8*)&bsm[((size_t)(lr << CPRLG) + cb) * 8];
    }
#pragma unroll
    for (int fo = 0; fo < 2; fo++)
      afr[fo] = *(const bf16x8*)(apk + ((size_t)fo * NKS + ks) * 512);
#pragma unroll
    for (int fo = 0; fo < 2; fo++)
#pragma unroll
      for (int fc = 0; fc < 4; fc++)
        acc[fo][fc] = __builtin_amdgcn_mfma_f32_16x16x32_bf16(afr[fo], bfr[fc], acc[fo][fc], 0, 0, 0);
  }

  // ---- epilogue ----
  float ps = 0.f, ps2 = 0.f;
#pragma unroll
  for (int fo = 0; fo < 2; fo++) {
    int o0 = wo0 + fo * 16 + grp * 4;
    float eb[4], w0c[4], w2c[4];
#pragma unroll
    for (int r = 0; r < 4; r++) { eb[r] = ebias[o0 + r]; w0c[r] = 0.f; w2c[r] = 0.f; }
    if (TCH && lt == 0) {
#pragma unroll
      for (int r = 0; r < 4; r++) w0c[r] = tval * Tpack[o0 + r];
    }
    if (TCH && lt == 63) {
#pragma unroll
      for (int r = 0; r < 4; r++) w2c[r] = tval * Tpack[512 + o0 + r];
    }
#pragma unroll
    for (int fc = 0; fc < 4; fc++) {
      int l = l_base + fc * 16 + col;
      float v[4];
#pragma unroll
      for (int r = 0; r < 4; r++) {
        v[r] = acc[fo][fc][r] + eb[r];
        if (TCH) {
          if (lt == 0) v[r] -= (l == 0) ? w0c[r] : 0.f;
          if (lt == 63) v[r] -= (l == 4095) ? w2c[r] : 0.f;
        }
        if (OUT == 0) { ps += v[r]; ps2 += v[r] * v[r]; }
      }
      if (OUT == 0) {
        ushort4 pk;
        pk.x = f2bf(v[0]); pk.y = f2bf(v[1]); pk.z = f2bf(v[2]); pk.w = f2bf(v[3]);
        *(ushort4*)((unsigned short*)outv + ((size_t)b * 4096 + l) * 256 + o0) = pk;
      } else {
#pragma unroll
        for (int r = 0; r < 4; r++)
          ((float*)outv)[((size_t)b * 256 + o0 + r) * 4096 + l] = v[r];
      }
    }
    if (OUT == 0) {
      float s = ps, s2 = ps2;
#pragma unroll
      for (int off = 8; off; off >>= 1) {
        s += __shfl_down(s, off, 16);
        s2 += __shfl_down(s2, off, 16);
      }
      if (col == 0) {
        int g = wv * 4 + fo * 2 + (grp >> 1);
        atomicAdd(&psh[g][0], s);
        atomicAdd(&psh[g][1], s2);
      }
      ps = 0.f; ps2 = 0.f;
    }
  }

  if (OUT == 0) {
    __syncthreads();
    if (tid < 32) {
      size_t pi = ((size_t)b * 32 + tid) * 128 + (size_t)lt * 2;
      Pout[pi] = psh[tid][0];
      Pout[pi + 1] = psh[tid][1];
    }
  }
}

// ---------------- stem: BN2-affine + tanh, C->T transpose, y0 fp32 + P1 partials --------
__global__ __launch_bounds__(512) void bn_tanh_T(const float* __restrict__ Q,
                                                 const float* __restrict__ stats,
                                                 const float* __restrict__ gamma,
                                                 const float* __restrict__ beta,
                                                 float* __restrict__ Y,
                                                 float* __restrict__ P1) {
  int tid = threadIdx.x;
  int b = blockIdx.x >> 5;
  int seg = blockIdx.x & 31;
  int c = tid >> 1;
  float m = stats[2 * c], rs = stats[2 * c + 1];
  float ga = gamma[c] * rs, be = beta[c] - m * ga;
  __shared__ float psh[32][2];
  if (tid < 32) { psh[tid][0] = 0.f; psh[tid][1] = 0.f; }
  __syncthreads();
  float s = 0.f, s2 = 0.f;
  for (int it = 0; it < 16; it++) {
    int l4 = (tid & 1) + it * 2;
    int l0 = seg * 128 + l4 * 4;
    float4 v = *(const float4*)&Q[((size_t)b * 256 + c) * 4096 + l0];
    float r0 = tanhf(v.x * ga + be);
    float r1 = tanhf(v.y * ga + be);
    float r2 = tanhf(v.z * ga + be);
    float r3 = tanhf(v.w * ga + be);
    Y[((size_t)b * 4096 + l0 + 0) * 256 + c] = r0;
    Y[((size_t)b * 4096 + l0 + 1) * 256 + c] = r1;
    Y[((size_t)b * 4096 + l0 + 2) * 256 + c] = r2;
    Y[((size_t)b * 4096 + l0 + 3) * 256 + c] = r3;
    s += r0 + r1 + r2 + r3;
    s2 += r0 * r0 + r1 * r1 + r2 * r2 + r3 * r3;
  }
#pragma unroll
  for (int off = 8; off; off >>= 1) { s += __shfl_down(s, off, 16); s2 += __shfl_down(s2, off, 16); }
  if ((tid & 15) == 0) {
    int g = c >> 3;
    atomicAdd(&psh[g][0], s);
    atomicAdd(&psh[g][1], s2);
  }
  __syncthreads();
  if (tid < 32) {
    size_t pi = ((size_t)b * 32 + tid) * 128 + (size_t)seg * 2;
    P1[pi] = psh[tid][0];
    P1[pi + 1] = psh[tid][1];
  }
}

// ---------------- combine (T layout): GN3-affine(F) + Heun update + P1 partials ----------
template <int MODE>
__global__ __launch_bounds__(512) void combine_T(const unsigned short* __restrict__ F,
                                                 const float* __restrict__ P3,
                                                 const float* __restrict__ gng,
                                                 const float* __restrict__ gnb,
                                                 float* __restrict__ Y,
                                                 unsigned short* __restrict__ Y1,
                                                 float* __restrict__ P1) {
  __shared__ float gsm[32][2];
  __shared__ float gabe[256][2];
  __shared__ float psh[32][2];
  int tid = threadIdx.x;
  int b = blockIdx.x >> 5;
  int seg = blockIdx.x & 31;
  {
    int g = tid >> 4, j0 = tid & 15;
    const float* Pg = P3 + ((size_t)b * 32 + g) * 128;
    float s = 0.f, s2 = 0.f;
    for (int j = j0; j < 64; j += 16) { s += Pg[j * 2]; s2 += Pg[j * 2 + 1]; }
#pragma unroll
    for (int off = 8; off; off >>= 1) { s += __shfl_down(s, off, 16); s2 += __shfl_down(s2, off, 16); }
    if (j0 == 0) {
      float m = s * (1.f / 32768.f);
      float var = s2 * (1.f / 32768.f) - m * m;
      gsm[g][0] = m;
      gsm[g][1] = rsqrtf(var + 1e-5f);
    }
  }
  __syncthreads();
  if (tid < 256) {
    float m = gsm[tid >> 3][0], rs = gsm[tid >> 3][1];
    float ga = gng[tid] * rs;
    gabe[tid][0] = ga;
    gabe[tid][1] = gnb[tid] - m * ga;
  }
  if (tid >= 256 && tid < 288) { psh[tid - 256][0] = 0.f; psh[tid - 256][1] = 0.f; }
  __syncthreads();

  size_t base4 = ((size_t)b * 4096 + seg * 128) * 64;
  int c0 = (tid << 2) & 255;
  int g = c0 >> 3;
  float ga0 = gabe[c0][0], be0 = gabe[c0][1];
  float ga1 = gabe[c0 + 1][0], be1 = gabe[c0 + 1][1];
  float ga2 = gabe[c0 + 2][0], be2 = gabe[c0 + 2][1];
  float ga3 = gabe[c0 + 3][0], be3 = gabe[c0 + 3][1];
  float s = 0.f, s2 = 0.f;
  for (int i = tid; i < 8192; i += 512) {
    size_t idx4 = base4 + i;
    ushort4 fv = ((const ushort4*)F)[idx4];
    float4 yv = ((const float4*)Y)[idx4];
    float f0 = bf2f(fv.x) * ga0 + be0;
    float f1 = bf2f(fv.y) * ga1 + be1;
    float f2 = bf2f(fv.z) * ga2 + be2;
    float f3 = bf2f(fv.w) * ga3 + be3;
    float4 yn;
    yn.x = yv.x + (MODE == 0 ? 0.125f : 0.0625f) * f0;
    yn.y = yv.y + (MODE == 0 ? 0.125f : 0.0625f) * f1;
    yn.z = yv.z + (MODE == 0 ? 0.125f : 0.0625f) * f2;
    yn.w = yv.w + (MODE == 0 ? 0.125f : 0.0625f) * f3;
    if (MODE == 0) {
      float4 yb;
      yb.x = yv.x + 0.0625f * f0;
      yb.y = yv.y + 0.0625f * f1;
      yb.z = yv.z + 0.0625f * f2;
      yb.w = yv.w + 0.0625f * f3;
      ((float4*)Y)[idx4] = yb;
    }
    if (MODE == 2) {
      ((float4*)Y)[idx4] = yn;
    } else {
      ushort4 pk;
      pk.x = f2bf(yn.x); pk.y = f2bf(yn.y); pk.z = f2bf(yn.z); pk.w = f2bf(yn.w);
      ((ushort4*)Y1)[idx4] = pk;
    }
    s += yn.x + yn.y + yn.z + yn.w;
    s2 += yn.x * yn.x + yn.y * yn.y + yn.z * yn.z + yn.w * yn.w;
  }
  s += __shfl_xor(s, 1);
  s2 += __shfl_xor(s2, 1);
  if ((tid & 1) == 0) {
    atomicAdd(&psh[g][0], s);
    atomicAdd(&psh[g][1], s2);
  }
  __syncthreads();
  if (tid < 32) {
    size_t pi = ((size_t)b * 32 + tid) * 128 + (size_t)seg * 2;
    P1[pi] = psh[tid][0];
    P1[pi + 1] = psh[tid][1];
  }
}

// ---------------- final: T-layout fp32 -> C-layout fp32 (d_out) ----------------
__global__ __launch_bounds__(256) void transpose_final(const float* __restrict__ Y,
                                                       float* __restrict__ out) {
  __shared__ float tile[64 * 260];
  int b = blockIdx.x >> 6;
  int lt = blockIdx.x & 63;
  int t = threadIdx.x;
  for (int i = t; i < 4096; i += 256) {
    int r = i >> 6;
    int c4 = (i & 63) << 2;
    float4 v = *(const float4*)&Y[((size_t)b * 4096 + lt * 64 + r) * 256 + c4];
    *(float4*)&tile[r * 260 + c4] = v;
  }
  __syncthreads();
  for (int i = t; i < 4096; i += 256) {
    int c = i >> 4;
    int l4 = (i & 15) << 2;
    float4 v;
    v.x = tile[(l4 + 0) * 260 + c];
    v.y = tile[(l4 + 1) * 260 + c];
    v.z = tile[(l4 + 2) * 260 + c];
    v.w = tile[(l4 + 3) * 260 + c];
    *(float4*)&out[((size_t)b * 256 + c) * 4096 + lt * 64 + l4] = v;
  }
}

extern "C" void kernel_launch(void* const* d_in, const int* in_sizes, int n_in,
                              void* d_out, int out_size, void* d_ws, size_t ws_size,
                              hipStream_t stream) {
  const float* x = (const float*)d_in[0];
  const float* w1 = (const float*)d_in[1];
  const float* b1 = (const float*)d_in[2];
  const float* bn1_g = (const float*)d_in[3];
  const float* bn1_b = (const float*)d_in[4];
  const float* w2 = (const float*)d_in[5];
  const float* b2 = (const float*)d_in[6];
  const float* bn2_g = (const float*)d_in[7];
  const float* bn2_b = (const float*)d_in[8];
  const float* cw1 = (const float*)d_in[9];
  const float* cb1 = (const float*)d_in[10];
  const float* gn1_g = (const float*)d_in[11];
  const float* gn1_b = (const float*)d_in[12];
  const float* gn2_g = (const float*)d_in[13];
  const float* gn2_b = (const float*)d_in[14];
  const float* cw2 = (const float*)d_in[15];
  const float* cb2 = (const float*)d_in[16];
  const float* gn3_g = (const float*)d_in[17];
  const float* gn3_b = (const float*)d_in[18];

  const size_t SZ = (size_t)16 * 256 * 4096;

  char* p = (char*)d_ws;
  float* Ybuf = (float*)p;                   p += SZ * 4;
  unsigned short* C1 = (unsigned short*)p;   p += SZ * 2;
  unsigned short* Fb = (unsigned short*)p;   p += SZ * 2;
  unsigned short* APK1 = (unsigned short*)p; p += (size_t)16 * 24 * 64 * 8 * 2;
  unsigned short* APK2 = (unsigned short*)p; p += (size_t)16 * 24 * 64 * 8 * 2;
  unsigned short* APKS = (unsigned short*)p; p += (size_t)16 * 6 * 64 * 8 * 2;
  float* TP1 = (float*)p;                    p += 768 * 4;
  float* TP2 = (float*)p;                    p += 768 * 4;
  float* STATS = (float*)p;                  p += 1024 * 4;
  float* P1 = (float*)p;                     p += (size_t)16 * 32 * 128 * 4;
  float* P2 = (float*)p;                     p += (size_t)16 * 32 * 128 * 4;
  float* P3 = (float*)p;                     p += (size_t)16 * 32 * 128 * 4;

  float* Q = (float*)d_out;
  unsigned short* Y1 = (unsigned short*)d_out;

  // ---- weight packing ----
  pack_big<<<96, 256, 0, stream>>>(cw1, APK1, TP1);
  pack_big<<<96, 256, 0, stream>>>(cw2, APK2, TP2);
  pack_stem<<<24, 256, 0, stream>>>(w2, APKS);

  // ---- stem ----
  conv1_kernel<<<16384, 256, 0, stream>>>(x, w1, b1, C1);
  stats_bf16_kernel<<<64, 256, 0, stream>>>(C1, STATS, 4096, 16, 64 * 4096, 4096, 1.f / 65536.f);
  act_transpose64<<<1024, 256, 0, stream>>>(C1, STATS, bn1_g, bn1_b, Fb);
  gemm_T<6, 1, 64, 0, 0, 32, true, false, 1><<<1024, 512, 0, stream>>>(
      Fb, APKS, nullptr, nullptr, nullptr, nullptr, b2, 0.f, Q, nullptr);
  stats_kernel<<<256, 256, 0, stream>>>(Q, STATS, 4096, 16, 256 * 4096, 4096, 1.f / 65536.f);
  bn_tanh_T<<<512, 512, 0, stream>>>(Q, STATS, bn2_g, bn2_b, Ybuf, P1);

  // ---- ODE: 8 steps (pred + 2 corr), all in T layout; state fixed in Ybuf ----
  const float H = 0.125f;
  for (int i = 0; i < 8; i++) {
    float t = i * H;
    gemm_T<24, 3, 256, 1, 0, 32, false, true, 0><<<1024, 512, 0, stream>>>(
        Ybuf, APK1, P1, gn1_g, gn1_b, TP1, cb1, t, C1, P2);
    gemm_T<24, 3, 256, 1, 1, 64, true, true, 0><<<1024, 512, 0, stream>>>(
        C1, APK2, P2, gn2_g, gn2_b, TP2, cb2, t, Fb, P3);
    combine_T<0><<<512, 512, 0, stream>>>(Fb, P3, gn3_g, gn3_b, Ybuf, Y1, P1);
    for (int c = 0; c < 2; c++) {
      gemm_T<24, 3, 256, 1, 0, 32, true, true, 0><<<1024, 512, 0, stream>>>(
          Y1, APK1, P1, gn1_g, gn1_b, TP1, cb1, t + H, C1, P2);
      gemm_T<24, 3, 256, 1, 1, 64, true, true, 0><<<1024, 512, 0, stream>>>(
          C1, APK2, P2, gn2_g, gn2_b, TP2, cb2, t + H, Fb, P3);
      if (c == 0)
        combine_T<1><<<512, 512, 0, stream>>>(Fb, P3, gn3_g, gn3_b, Ybuf, Y1, P1);
      else
        combine_T<2><<<512, 512, 0, stream>>>(Fb, P3, gn3_g, gn3_b, Ybuf, Y1, P1);
    }
  }

  // ---- final: transpose T state -> d_out C layout ----
  transpose_final<<<1024, 256, 0, stream>>>(Ybuf, (float*)d_out);
}

// Round 8
// 2617.260 us; speedup vs baseline: 10.1736x; 1.0125x over previous
//
#include <hip/hip_runtime.h>
#include <math.h>

#define L4 4096

typedef short bf16x8 __attribute__((ext_vector_type(8)));
typedef float f32x4 __attribute__((ext_vector_type(4)));

__device__ __forceinline__ unsigned short f2bf(float f) {
  unsigned u = __builtin_bit_cast(unsigned, f);
  return (unsigned short)((u + 0x7FFFu + ((u >> 16) & 1u)) >> 16);
}
__device__ __forceinline__ float bf2f(unsigned short h) {
  unsigned u = ((unsigned)h) << 16;
  return __builtin_bit_cast(float, u);
}
// hardware RTNE pack of 2 floats -> 2 bf16 in one instruction
__device__ __forceinline__ unsigned pk2(float lo, float hi) {
  unsigned d;
  asm("v_cvt_pk_bf16_f32 %0, %1, %2" : "=v"(d) : "v"(lo), "v"(hi));
  return d;
}
__device__ __forceinline__ float fast_tanh(float x) {
  float e = __expf(2.f * x);
  return 1.f - 2.f * __builtin_amdgcn_rcpf(e + 1.f);
}

// ---------------- pack big conv weights: Apack[ks][frow][lane][8] + t-channel ----------------
__global__ __launch_bounds__(256) void pack_big(const float* __restrict__ cw,
                                                unsigned short* __restrict__ Apack,
                                                float* __restrict__ Tpack) {
  int gid = blockIdx.x * 256 + threadIdx.x;
  if (gid < 768) {
    int o = gid & 255, tap = gid >> 8;
    Tpack[tap * 256 + o] = cw[((size_t)o * 257) * 9 + 3 + tap];
  }
  if (gid >= 24 * 16 * 64) return;
  int ks = gid >> 10;
  int frow = (gid >> 6) & 15;
  int lane = gid & 63;
  int o = frow * 16 + (lane & 15);
  int tap = ks >> 3;
  int ib = ((ks & 7) << 5) + ((lane >> 4) << 3);
#pragma unroll
  for (int e = 0; e < 8; e++) {
    int i = ib + e;
    Apack[(size_t)gid * 8 + e] = f2bf(cw[((size_t)o * 257 + (i + 1)) * 9 + 3 + tap]);
  }
}

// ---------------- pack stem conv2 weights: Apack[ks][frow][lane][8] ----------------
__global__ __launch_bounds__(256) void pack_stem(const float* __restrict__ w2,
                                                 unsigned short* __restrict__ Apack) {
  int gid = blockIdx.x * 256 + threadIdx.x;
  if (gid >= 6 * 16 * 64) return;
  int ks = gid >> 10;
  int frow = (gid >> 6) & 15;
  int lane = gid & 63;
  int o = frow * 16 + (lane & 15);
  int tap = ks >> 1;
  int ib = ((ks & 1) << 5) + ((lane >> 4) << 3);
#pragma unroll
  for (int e = 0; e < 8; e++) {
    int i = ib + e;
    Apack[(size_t)gid * 8 + e] = f2bf(w2[((size_t)o * 64 + i) * 3 + tap]);
  }
}

// ---------------- stem conv1: 4 -> 64, k=3, pad 1 (bf16 out) ----------------
__global__ __launch_bounds__(256) void conv1_kernel(const float* __restrict__ x,
                                                    const float* __restrict__ w,
                                                    const float* __restrict__ bias,
                                                    unsigned short* __restrict__ out) {
  int idx = blockIdx.x * 256 + threadIdx.x;
  int l = idx & 4095;
  int c = (idx >> 12) & 63;
  int b = idx >> 18;
  const float* xb = x + (size_t)b * 4 * L4;
  const float* wc = w + c * 12;
  float acc = bias[c];
#pragma unroll
  for (int i = 0; i < 4; i++) {
    float x0 = (l > 0) ? xb[i * L4 + l - 1] : 0.f;
    float x1 = xb[i * L4 + l];
    float x2 = (l < 4095) ? xb[i * L4 + l + 1] : 0.f;
    acc += wc[i * 3] * x0 + wc[i * 3 + 1] * x1 + wc[i * 3 + 2] * x2;
  }
  out[idx] = f2bf(acc);
}

// ---------------- mean/rstd stats (stem only), fp32 ----------------
__global__ __launch_bounds__(256) void stats_kernel(const float* __restrict__ in,
                                                    float* __restrict__ stats,
                                                    int unit_stride, int nrow,
                                                    int row_stride, int rowlen,
                                                    float inv_n) {
  int u = blockIdx.x;
  const float* base = in + (size_t)u * unit_stride;
  float s = 0.f, s2 = 0.f;
  for (int r = 0; r < nrow; r++) {
    const float* rowp = base + (size_t)r * row_stride;
    for (int j = threadIdx.x * 4; j < rowlen; j += 256 * 4) {
      float4 v = *(const float4*)(rowp + j);
      s += v.x + v.y + v.z + v.w;
      s2 += v.x * v.x + v.y * v.y + v.z * v.z + v.w * v.w;
    }
  }
  __shared__ float sh[512];
  sh[threadIdx.x] = s;
  sh[256 + threadIdx.x] = s2;
  __syncthreads();
  for (int off = 128; off > 0; off >>= 1) {
    if (threadIdx.x < off) {
      sh[threadIdx.x] += sh[threadIdx.x + off];
      sh[256 + threadIdx.x] += sh[256 + threadIdx.x + off];
    }
    __syncthreads();
  }
  if (threadIdx.x == 0) {
    float m = sh[0] * inv_n;
    float var = sh[256] * inv_n - m * m;
    stats[u * 2] = m;
    stats[u * 2 + 1] = rsqrtf(var + 1e-5f);
  }
}

// ---------------- mean/rstd stats (stem only), bf16 ----------------
__global__ __launch_bounds__(256) void stats_bf16_kernel(const unsigned short* __restrict__ in,
                                                         float* __restrict__ stats,
                                                         int unit_stride, int nrow,
                                                         int row_stride, int rowlen,
                                                         float inv_n) {
  int u = blockIdx.x;
  const unsigned short* base = in + (size_t)u * unit_stride;
  float s = 0.f, s2 = 0.f;
  for (int r = 0; r < nrow; r++) {
    const unsigned short* rowp = base + (size_t)r * row_stride;
    for (int j = threadIdx.x * 4; j < rowlen; j += 256 * 4) {
      ushort4 v = *(const ushort4*)(rowp + j);
      float va = bf2f(v.x), vb = bf2f(v.y), vc = bf2f(v.z), vd = bf2f(v.w);
      s += va + vb + vc + vd;
      s2 += va * va + vb * vb + vc * vc + vd * vd;
    }
  }
  __shared__ float sh[512];
  sh[threadIdx.x] = s;
  sh[256 + threadIdx.x] = s2;
  __syncthreads();
  for (int off = 128; off > 0; off >>= 1) {
    if (threadIdx.x < off) {
      sh[threadIdx.x] += sh[threadIdx.x + off];
      sh[256 + threadIdx.x] += sh[256 + threadIdx.x + off];
    }
    __syncthreads();
  }
  if (threadIdx.x == 0) {
    float m = sh[0] * inv_n;
    float var = sh[256] * inv_n - m * m;
    stats[u * 2] = m;
    stats[u * 2 + 1] = rsqrtf(var + 1e-5f);
  }
}

// ---------------- stem: BN1-affine + relu + bf16 + transpose to padded XT64 ----------------
__global__ __launch_bounds__(256) void act_transpose64(const unsigned short* __restrict__ inv,
                                                       const float* __restrict__ stats,
                                                       const float* __restrict__ gamma,
                                                       const float* __restrict__ beta,
                                                       unsigned short* __restrict__ Xt) {
  constexpr int C = 64;
  __shared__ unsigned short tile[64 * C];
  int bidx = blockIdx.x;
  int b = bidx >> 6;
  int lt = bidx & 63;
  int l0 = lt << 6;
  int t = threadIdx.x;
  int lanel = t & 63;
  int cq = t >> 6;
  for (int cp = 0; cp < C / 4; cp++) {
    int c = cp * 4 + cq;
    float m = stats[2 * c], rs = stats[2 * c + 1];
    float ga = gamma[c] * rs, be = beta[c] - m * ga;
    size_t gidx = ((size_t)b * C + c) * 4096 + l0 + lanel;
    float v = bf2f(inv[gidx]);
    float a = v * ga + be;
    float r = fmaxf(a, 0.f);
    int sw = (lanel & 15) << 2;
    tile[lanel * C + (c ^ sw)] = f2bf(r);
  }
  __syncthreads();
  constexpr int CH = C / 4;
  constexpr int RPP = 256 / CH;
  for (int p = 0; p < 64 / RPP; p++) {
    int r = p * RPP + t / CH;
    int ch = t % CH;
    int sw = (r & 15) << 2;
    ushort4 v = *(const ushort4*)&tile[r * C + ((ch * 4) ^ sw)];
    *(ushort4*)&Xt[((size_t)b * 4098 + 1 + l0 + r) * C + ch * 4] = v;
  }
  if (lt == 0) {
    if (t < C / 4) *(ushort4*)&Xt[((size_t)b * 4098 + 0) * C + t * 4] = make_ushort4(0, 0, 0, 0);
  } else if (lt == 63) {
    if (t < C / 4) *(ushort4*)&Xt[((size_t)b * 4098 + 4097) * C + t * 4] = make_ushort4(0, 0, 0, 0);
  }
}

// ---------------- fused MFMA conv-GEMM --------------------------------------------------
// Tile 256o x 64l, 512 thr (8 waves, wave = 32o x 64l). grid = 16b * 64 lt = 1024.
// Staging: LINEAR ds_writes (lane -> chunk tid), swizzle applied on the GLOBAL source:
// lane's fixed channel-chunk gch = pl ^ (row0&7); row advances by RPI (multiple of 8)
// so gch (and gamma/beta registers) stay constant across iterations.
template <int NKS, int KLG, int CIN, int NORM, int ACT, int NCH, bool INBF, bool TCH, int OUT>
__global__ __launch_bounds__(512, 4) void gemm_T(const void* __restrict__ Bsrc,
                                                 const unsigned short* __restrict__ Apack,
                                                 const float* __restrict__ Pin,
                                                 const float* __restrict__ gng,
                                                 const float* __restrict__ gnb,
                                                 const float* __restrict__ Tpack,
                                                 const float* __restrict__ bias,
                                                 float tval,
                                                 void* __restrict__ outv,
                                                 float* __restrict__ Pout) {
  constexpr int CPR = CIN / 8;
  constexpr int CPRLG = (CIN == 256) ? 5 : 3;
  constexpr int ROWS = 66;
  constexpr int RPI = 512 >> CPRLG;   // rows per staging iteration (16 or 64; both %8==0)
  constexpr int TOT = ROWS * CPR;
  __shared__ unsigned short bsm[ROWS * CIN];
  __shared__ float gsm[32][2];
  __shared__ float ebias[256];
  __shared__ float psh[32][2];

  int tid = threadIdx.x;
  int lane = tid & 63;
  int wv = tid >> 6;
  int b = blockIdx.x >> 6;
  int lt = blockIdx.x & 63;
  int l_base = lt << 6;
  int wo0 = wv << 5;
  int col = lane & 15;
  int grp = lane >> 4;

  // ---- phase 0: parallel GN-stat reduce + ebias precompute ----
  if (NORM) {
    int g = tid >> 4, j0 = tid & 15;
    const float* Pg = Pin + ((size_t)b * 32 + g) * 128;
    float s = 0.f, s2 = 0.f;
    for (int j = j0; j < NCH; j += 16) { s += Pg[j * 2]; s2 += Pg[j * 2 + 1]; }
#pragma unroll
    for (int off = 8; off; off >>= 1) { s += __shfl_down(s, off, 16); s2 += __shfl_down(s2, off, 16); }
    if (j0 == 0) {
      float m = s * (1.f / 32768.f);
      float var = s2 * (1.f / 32768.f) - m * m;
      gsm[g][0] = m;
      gsm[g][1] = rsqrtf(var + 1e-5f);
    }
  }
  if (tid < 256) {
    float e = bias[tid];
    if (TCH) e += tval * (Tpack[tid] + Tpack[256 + tid] + Tpack[512 + tid]);
    ebias[tid] = e;
  }
  if (OUT == 0 && tid >= 256 && tid < 288) { psh[tid - 256][0] = 0.f; psh[tid - 256][1] = 0.f; }
  __syncthreads();

  // ---- phase 1: stage B tile; linear LDS writes, source pre-swizzled ----
  {
    int pl = tid & (CPR - 1);
    int row0 = tid >> CPRLG;
    int gch = pl ^ (row0 & 7);        // fixed global channel-chunk for this lane
    float ga[8], be[8];
    if (NORM) {
      float m = gsm[gch][0], rs = gsm[gch][1];
      float4 g0 = *(const float4*)&gng[gch * 8];
      float4 g1 = *(const float4*)&gng[gch * 8 + 4];
      float4 b0 = *(const float4*)&gnb[gch * 8];
      float4 b1 = *(const float4*)&gnb[gch * 8 + 4];
      ga[0] = g0.x * rs; ga[1] = g0.y * rs; ga[2] = g0.z * rs; ga[3] = g0.w * rs;
      ga[4] = g1.x * rs; ga[5] = g1.y * rs; ga[6] = g1.z * rs; ga[7] = g1.w * rs;
      be[0] = b0.x - m * ga[0]; be[1] = b0.y - m * ga[1];
      be[2] = b0.z - m * ga[2]; be[3] = b0.w - m * ga[3];
      be[4] = b1.x - m * ga[4]; be[5] = b1.y - m * ga[5];
      be[6] = b1.z - m * ga[6]; be[7] = b1.w - m * ga[7];
    }
#pragma unroll
    for (int it = 0; it < (TOT + 511) / 512; it++) {
      int chunk = it * 512 + tid;
      if (chunk < TOT) {
        int row = row0 + it * RPI;
        uint4 w4;
        if (NORM) {
          int gl = l_base - 1 + row;
          if (gl >= 0 && gl < 4096) {
            size_t base = ((size_t)b * 4096 + gl) * CIN + gch * 8;
            float vv[8];
            if (INBF) {
              bf16x8 raw = *(const bf16x8*)((const unsigned short*)Bsrc + base);
#pragma unroll
              for (int e = 0; e < 8; e++) vv[e] = bf2f((unsigned short)raw[e]);
            } else {
              float4 r0 = *(const float4*)((const float*)Bsrc + base);
              float4 r1 = *(const float4*)((const float*)Bsrc + base + 4);
              vv[0] = r0.x; vv[1] = r0.y; vv[2] = r0.z; vv[3] = r0.w;
              vv[4] = r1.x; vv[5] = r1.y; vv[6] = r1.z; vv[7] = r1.w;
            }
            float rr[8];
#pragma unroll
            for (int e = 0; e < 8; e++) {
              float a = vv[e] * ga[e] + be[e];
              rr[e] = (ACT == 0) ? fmaxf(a, 0.f) : (a > 0.f ? a : __expf(a) - 1.f);
            }
            w4.x = pk2(rr[0], rr[1]); w4.y = pk2(rr[2], rr[3]);
            w4.z = pk2(rr[4], rr[5]); w4.w = pk2(rr[6], rr[7]);
          } else {
            w4 = make_uint4(0, 0, 0, 0);
          }
        } else {
          w4 = *(const uint4*)((const unsigned short*)Bsrc +
                               ((size_t)b * 4098 + l_base + row) * CIN + gch * 8);
        }
        *(uint4*)&bsm[(size_t)chunk * 8] = w4;   // LINEAR write
      }
    }
  }
  __syncthreads();

  // ---- phase 2: MFMA loop (ds_read base + folded constant offsets) ----
  const unsigned short* apk = Apack + (size_t)(wv * 2) * 512 + (size_t)lane * 8;

  f32x4 acc[2][4];
#pragma unroll
  for (int i = 0; i < 2; i++)
#pragma unroll
    for (int j = 0; j < 4; j++) acc[i][j] = (f32x4){0.f, 0.f, 0.f, 0.f};

#pragma unroll
  for (int ks = 0; ks < NKS; ks++) {
    int tap = ks >> KLG;
    int cbase = (ks & ((1 << KLG) - 1)) << 2;
    int lr0 = col + tap;
    int cb = (cbase + grp) ^ (lr0 & 7);
    const unsigned short* bp = &bsm[((size_t)(lr0 << CPRLG) + cb) * 8];
    const unsigned short* ap = apk + (size_t)ks * 16 * 512;
    bf16x8 bfr[4], afr[2];
#pragma unroll
    for (int fc = 0; fc < 4; fc++) bfr[fc] = *(const bf16x8*)(bp + fc * 16 * CIN);
#pragma unroll
    for (int fo = 0; fo < 2; fo++) afr[fo] = *(const bf16x8*)(ap + fo * 512);
#pragma unroll
    for (int fo = 0; fo < 2; fo++)
#pragma unroll
      for (int fc = 0; fc < 4; fc++)
        acc[fo][fc] = __builtin_amdgcn_mfma_f32_16x16x32_bf16(afr[fo], bfr[fc], acc[fo][fc], 0, 0, 0);
  }

  // ---- epilogue ----
  float ps = 0.f, ps2 = 0.f;
#pragma unroll
  for (int fo = 0; fo < 2; fo++) {
    int o0 = wo0 + fo * 16 + grp * 4;
    float eb[4], w0c[4], w2c[4];
#pragma unroll
    for (int r = 0; r < 4; r++) { eb[r] = ebias[o0 + r]; w0c[r] = 0.f; w2c[r] = 0.f; }
    if (TCH && lt == 0) {
#pragma unroll
      for (int r = 0; r < 4; r++) w0c[r] = tval * Tpack[o0 + r];
    }
    if (TCH && lt == 63) {
#pragma unroll
      for (int r = 0; r < 4; r++) w2c[r] = tval * Tpack[512 + o0 + r];
    }
#pragma unroll
    for (int fc = 0; fc < 4; fc++) {
      int l = l_base + fc * 16 + col;
      float v[4];
#pragma unroll
      for (int r = 0; r < 4; r++) {
        v[r] = acc[fo][fc][r] + eb[r];
        if (TCH) {
          if (lt == 0) v[r] -= (l == 0) ? w0c[r] : 0.f;
          if (lt == 63) v[r] -= (l == 4095) ? w2c[r] : 0.f;
        }
        if (OUT == 0) { ps += v[r]; ps2 += v[r] * v[r]; }
      }
      if (OUT == 0) {
        uint2 pk = make_uint2(pk2(v[0], v[1]), pk2(v[2], v[3]));
        *(uint2*)((unsigned short*)outv + ((size_t)b * 4096 + l) * 256 + o0) = pk;
      } else {
#pragma unroll
        for (int r = 0; r < 4; r++)
          ((float*)outv)[((size_t)b * 256 + o0 + r) * 4096 + l] = v[r];
      }
    }
    if (OUT == 0) {
      float s = ps, s2 = ps2;
#pragma unroll
      for (int off = 8; off; off >>= 1) {
        s += __shfl_down(s, off, 16);
        s2 += __shfl_down(s2, off, 16);
      }
      if (col == 0) {
        int g = wv * 4 + fo * 2 + (grp >> 1);
        atomicAdd(&psh[g][0], s);
        atomicAdd(&psh[g][1], s2);
      }
      ps = 0.f; ps2 = 0.f;
    }
  }

  if (OUT == 0) {
    __syncthreads();
    if (tid < 32) {
      size_t pi = ((size_t)b * 32 + tid) * 128 + (size_t)lt * 2;
      Pout[pi] = psh[tid][0];
      Pout[pi + 1] = psh[tid][1];
    }
  }
}

// ---------------- stem: BN2-affine + fast-tanh, C->T transpose, y0 fp32 + P1 partials ----
__global__ __launch_bounds__(512) void bn_tanh_T(const float* __restrict__ Q,
                                                 const float* __restrict__ stats,
                                                 const float* __restrict__ gamma,
                                                 const float* __restrict__ beta,
                                                 float* __restrict__ Y,
                                                 float* __restrict__ P1) {
  int tid = threadIdx.x;
  int b = blockIdx.x >> 5;
  int seg = blockIdx.x & 31;
  int c = tid >> 1;
  float m = stats[2 * c], rs = stats[2 * c + 1];
  float ga = gamma[c] * rs, be = beta[c] - m * ga;
  __shared__ float psh[32][2];
  if (tid < 32) { psh[tid][0] = 0.f; psh[tid][1] = 0.f; }
  __syncthreads();
  float s = 0.f, s2 = 0.f;
  for (int it = 0; it < 16; it++) {
    int l4 = (tid & 1) + it * 2;
    int l0 = seg * 128 + l4 * 4;
    float4 v = *(const float4*)&Q[((size_t)b * 256 + c) * 4096 + l0];
    float r0 = fast_tanh(v.x * ga + be);
    float r1 = fast_tanh(v.y * ga + be);
    float r2 = fast_tanh(v.z * ga + be);
    float r3 = fast_tanh(v.w * ga + be);
    Y[((size_t)b * 4096 + l0 + 0) * 256 + c] = r0;
    Y[((size_t)b * 4096 + l0 + 1) * 256 + c] = r1;
    Y[((size_t)b * 4096 + l0 + 2) * 256 + c] = r2;
    Y[((size_t)b * 4096 + l0 + 3) * 256 + c] = r3;
    s += r0 + r1 + r2 + r3;
    s2 += r0 * r0 + r1 * r1 + r2 * r2 + r3 * r3;
  }
#pragma unroll
  for (int off = 8; off; off >>= 1) { s += __shfl_down(s, off, 16); s2 += __shfl_down(s2, off, 16); }
  if ((tid & 15) == 0) {
    int g = c >> 3;
    atomicAdd(&psh[g][0], s);
    atomicAdd(&psh[g][1], s2);
  }
  __syncthreads();
  if (tid < 32) {
    size_t pi = ((size_t)b * 32 + tid) * 128 + (size_t)seg * 2;
    P1[pi] = psh[tid][0];
    P1[pi + 1] = psh[tid][1];
  }
}

// ---------------- combine (T layout): GN3-affine(F) + Heun update + P1 partials ----------
template <int MODE>
__global__ __launch_bounds__(512) void combine_T(const unsigned short* __restrict__ F,
                                                 const float* __restrict__ P3,
                                                 const float* __restrict__ gng,
                                                 const float* __restrict__ gnb,
                                                 float* __restrict__ Y,
                                                 unsigned short* __restrict__ Y1,
                                                 float* __restrict__ P1) {
  __shared__ float gsm[32][2];
  __shared__ float gabe[256][2];
  __shared__ float psh[32][2];
  int tid = threadIdx.x;
  int b = blockIdx.x >> 5;
  int seg = blockIdx.x & 31;
  {
    int g = tid >> 4, j0 = tid & 15;
    const float* Pg = P3 + ((size_t)b * 32 + g) * 128;
    float s = 0.f, s2 = 0.f;
    for (int j = j0; j < 64; j += 16) { s += Pg[j * 2]; s2 += Pg[j * 2 + 1]; }
#pragma unroll
    for (int off = 8; off; off >>= 1) { s += __shfl_down(s, off, 16); s2 += __shfl_down(s2, off, 16); }
    if (j0 == 0) {
      float m = s * (1.f / 32768.f);
      float var = s2 * (1.f / 32768.f) - m * m;
      gsm[g][0] = m;
      gsm[g][1] = rsqrtf(var + 1e-5f);
    }
  }
  __syncthreads();
  if (tid < 256) {
    float m = gsm[tid >> 3][0], rs = gsm[tid >> 3][1];
    float ga = gng[tid] * rs;
    gabe[tid][0] = ga;
    gabe[tid][1] = gnb[tid] - m * ga;
  }
  if (tid >= 256 && tid < 288) { psh[tid - 256][0] = 0.f; psh[tid - 256][1] = 0.f; }
  __syncthreads();

  size_t base4 = ((size_t)b * 4096 + seg * 128) * 64;
  int c0 = (tid << 2) & 255;
  int g = c0 >> 3;
  float ga0 = gabe[c0][0], be0 = gabe[c0][1];
  float ga1 = gabe[c0 + 1][0], be1 = gabe[c0 + 1][1];
  float ga2 = gabe[c0 + 2][0], be2 = gabe[c0 + 2][1];
  float ga3 = gabe[c0 + 3][0], be3 = gabe[c0 + 3][1];
  float s = 0.f, s2 = 0.f;
  for (int i = tid; i < 8192; i += 512) {
    size_t idx4 = base4 + i;
    ushort4 fv = ((const ushort4*)F)[idx4];
    float4 yv = ((const float4*)Y)[idx4];
    float f0 = bf2f(fv.x) * ga0 + be0;
    float f1 = bf2f(fv.y) * ga1 + be1;
    float f2 = bf2f(fv.z) * ga2 + be2;
    float f3 = bf2f(fv.w) * ga3 + be3;
    float4 yn;
    yn.x = yv.x + (MODE == 0 ? 0.125f : 0.0625f) * f0;
    yn.y = yv.y + (MODE == 0 ? 0.125f : 0.0625f) * f1;
    yn.z = yv.z + (MODE == 0 ? 0.125f : 0.0625f) * f2;
    yn.w = yv.w + (MODE == 0 ? 0.125f : 0.0625f) * f3;
    if (MODE == 0) {
      float4 yb;
      yb.x = yv.x + 0.0625f * f0;
      yb.y = yv.y + 0.0625f * f1;
      yb.z = yv.z + 0.0625f * f2;
      yb.w = yv.w + 0.0625f * f3;
      ((float4*)Y)[idx4] = yb;
    }
    if (MODE == 2) {
      ((float4*)Y)[idx4] = yn;
    } else {
      uint2 pk = make_uint2(pk2(yn.x, yn.y), pk2(yn.z, yn.w));
      ((uint2*)Y1)[idx4] = pk;
    }
    s += yn.x + yn.y + yn.z + yn.w;
    s2 += yn.x * yn.x + yn.y * yn.y + yn.z * yn.z + yn.w * yn.w;
  }
  s += __shfl_xor(s, 1);
  s2 += __shfl_xor(s2, 1);
  if ((tid & 1) == 0) {
    atomicAdd(&psh[g][0], s);
    atomicAdd(&psh[g][1], s2);
  }
  __syncthreads();
  if (tid < 32) {
    size_t pi = ((size_t)b * 32 + tid) * 128 + (size_t)seg * 2;
    P1[pi] = psh[tid][0];
    P1[pi + 1] = psh[tid][1];
  }
}

// ---------------- final: T-layout fp32 -> C-layout fp32 (d_out) ----------------
__global__ __launch_bounds__(256) void transpose_final(const float* __restrict__ Y,
                                                       float* __restrict__ out) {
  __shared__ float tile[64 * 260];
  int b = blockIdx.x >> 6;
  int lt = blockIdx.x & 63;
  int t = threadIdx.x;
  for (int i = t; i < 4096; i += 256) {
    int r = i >> 6;
    int c4 = (i & 63) << 2;
    float4 v = *(const float4*)&Y[((size_t)b * 4096 + lt * 64 + r) * 256 + c4];
    *(float4*)&tile[r * 260 + c4] = v;
  }
  __syncthreads();
  for (int i = t; i < 4096; i += 256) {
    int c = i >> 4;
    int l4 = (i & 15) << 2;
    float4 v;
    v.x = tile[(l4 + 0) * 260 + c];
    v.y = tile[(l4 + 1) * 260 + c];
    v.z = tile[(l4 + 2) * 260 + c];
    v.w = tile[(l4 + 3) * 260 + c];
    *(float4*)&out[((size_t)b * 256 + c) * 4096 + lt * 64 + l4] = v;
  }
}

extern "C" void kernel_launch(void* const* d_in, const int* in_sizes, int n_in,
                              void* d_out, int out_size, void* d_ws, size_t ws_size,
                              hipStream_t stream) {
  const float* x = (const float*)d_in[0];
  const float* w1 = (const float*)d_in[1];
  const float* b1 = (const float*)d_in[2];
  const float* bn1_g = (const float*)d_in[3];
  const float* bn1_b = (const float*)d_in[4];
  const float* w2 = (const float*)d_in[5];
  const float* b2 = (const float*)d_in[6];
  const float* bn2_g = (const float*)d_in[7];
  const float* bn2_b = (const float*)d_in[8];
  const float* cw1 = (const float*)d_in[9];
  const float* cb1 = (const float*)d_in[10];
  const float* gn1_g = (const float*)d_in[11];
  const float* gn1_b = (const float*)d_in[12];
  const float* gn2_g = (const float*)d_in[13];
  const float* gn2_b = (const float*)d_in[14];
  const float* cw2 = (const float*)d_in[15];
  const float* cb2 = (const float*)d_in[16];
  const float* gn3_g = (const float*)d_in[17];
  const float* gn3_b = (const float*)d_in[18];

  const size_t SZ = (size_t)16 * 256 * 4096;

  char* p = (char*)d_ws;
  float* Ybuf = (float*)p;                   p += SZ * 4;
  unsigned short* C1 = (unsigned short*)p;   p += SZ * 2;
  unsigned short* Fb = (unsigned short*)p;   p += SZ * 2;
  unsigned short* APK1 = (unsigned short*)p; p += (size_t)24 * 16 * 64 * 8 * 2;
  unsigned short* APK2 = (unsigned short*)p; p += (size_t)24 * 16 * 64 * 8 * 2;
  unsigned short* APKS = (unsigned short*)p; p += (size_t)6 * 16 * 64 * 8 * 2;
  float* TP1 = (float*)p;                    p += 768 * 4;
  float* TP2 = (float*)p;                    p += 768 * 4;
  float* STATS = (float*)p;                  p += 1024 * 4;
  float* P1 = (float*)p;                     p += (size_t)16 * 32 * 128 * 4;
  float* P2 = (float*)p;                     p += (size_t)16 * 32 * 128 * 4;
  float* P3 = (float*)p;                     p += (size_t)16 * 32 * 128 * 4;

  float* Q = (float*)d_out;
  unsigned short* Y1 = (unsigned short*)d_out;

  // ---- weight packing ----
  pack_big<<<96, 256, 0, stream>>>(cw1, APK1, TP1);
  pack_big<<<96, 256, 0, stream>>>(cw2, APK2, TP2);
  pack_stem<<<24, 256, 0, stream>>>(w2, APKS);

  // ---- stem ----
  conv1_kernel<<<16384, 256, 0, stream>>>(x, w1, b1, C1);
  stats_bf16_kernel<<<64, 256, 0, stream>>>(C1, STATS, 4096, 16, 64 * 4096, 4096, 1.f / 65536.f);
  act_transpose64<<<1024, 256, 0, stream>>>(C1, STATS, bn1_g, bn1_b, Fb);
  gemm_T<6, 1, 64, 0, 0, 32, true, false, 1><<<1024, 512, 0, stream>>>(
      Fb, APKS, nullptr, nullptr, nullptr, nullptr, b2, 0.f, Q, nullptr);
  stats_kernel<<<256, 256, 0, stream>>>(Q, STATS, 4096, 16, 256 * 4096, 4096, 1.f / 65536.f);
  bn_tanh_T<<<512, 512, 0, stream>>>(Q, STATS, bn2_g, bn2_b, Ybuf, P1);

  // ---- ODE: 8 steps (pred + 2 corr), all in T layout; state fixed in Ybuf ----
  const float H = 0.125f;
  for (int i = 0; i < 8; i++) {
    float t = i * H;
    gemm_T<24, 3, 256, 1, 0, 32, false, true, 0><<<1024, 512, 0, stream>>>(
        Ybuf, APK1, P1, gn1_g, gn1_b, TP1, cb1, t, C1, P2);
    gemm_T<24, 3, 256, 1, 1, 64, true, true, 0><<<1024, 512, 0, stream>>>(
        C1, APK2, P2, gn2_g, gn2_b, TP2, cb2, t, Fb, P3);
    combine_T<0><<<512, 512, 0, stream>>>(Fb, P3, gn3_g, gn3_b, Ybuf, Y1, P1);
    for (int c = 0; c < 2; c++) {
      gemm_T<24, 3, 256, 1, 0, 32, true, true, 0><<<1024, 512, 0, stream>>>(
          Y1, APK1, P1, gn1_g, gn1_b, TP1, cb1, t + H, C1, P2);
      gemm_T<24, 3, 256, 1, 1, 64, true, true, 0><<<1024, 512, 0, stream>>>(
          C1, APK2, P2, gn2_g, gn2_b, TP2, cb2, t + H, Fb, P3);
      if (c == 0)
        combine_T<1><<<512, 512, 0, stream>>>(Fb, P3, gn3_g, gn3_b, Ybuf, Y1, P1);
      else
        combine_T<2><<<512, 512, 0, stream>>>(Fb, P3, gn3_g, gn3_b, Ybuf, Y1, P1);
    }
  }

  // ---- final: transpose T state -> d_out C layout ----
  transpose_final<<<1024, 256, 0, stream>>>(Ybuf, (float*)d_out);
}

// Round 9
// 2575.676 us; speedup vs baseline: 10.3379x; 1.0161x over previous
//
#include <hip/hip_runtime.h>
#include <math.h>

#define L4 4096

typedef short bf16x8 __attribute__((ext_vector_type(8)));
typedef float f32x4 __attribute__((ext_vector_type(4)));

__device__ __forceinline__ unsigned short f2bf(float f) {
  unsigned u = __builtin_bit_cast(unsigned, f);
  return (unsigned short)((u + 0x7FFFu + ((u >> 16) & 1u)) >> 16);
}
__device__ __forceinline__ float bf2f(unsigned short h) {
  unsigned u = ((unsigned)h) << 16;
  return __builtin_bit_cast(float, u);
}
// hardware RTNE pack of 2 floats -> 2 bf16 in one instruction
__device__ __forceinline__ unsigned pk2(float lo, float hi) {
  unsigned d;
  asm("v_cvt_pk_bf16_f32 %0, %1, %2" : "=v"(d) : "v"(lo), "v"(hi));
  return d;
}
__device__ __forceinline__ float fast_tanh(float x) {
  float e = __expf(2.f * x);
  return 1.f - 2.f * __builtin_amdgcn_rcpf(e + 1.f);
}

// ---------------- pack big conv weights: Apack[ks][frow][lane][8] + t-channel ----------------
__global__ __launch_bounds__(256) void pack_big(const float* __restrict__ cw,
                                                unsigned short* __restrict__ Apack,
                                                float* __restrict__ Tpack) {
  int gid = blockIdx.x * 256 + threadIdx.x;
  if (gid < 768) {
    int o = gid & 255, tap = gid >> 8;
    Tpack[tap * 256 + o] = cw[((size_t)o * 257) * 9 + 3 + tap];
  }
  if (gid >= 24 * 16 * 64) return;
  int ks = gid >> 10;
  int frow = (gid >> 6) & 15;
  int lane = gid & 63;
  int o = frow * 16 + (lane & 15);
  int tap = ks >> 3;
  int ib = ((ks & 7) << 5) + ((lane >> 4) << 3);
#pragma unroll
  for (int e = 0; e < 8; e++) {
    int i = ib + e;
    Apack[(size_t)gid * 8 + e] = f2bf(cw[((size_t)o * 257 + (i + 1)) * 9 + 3 + tap]);
  }
}

// ---------------- pack stem conv2 weights: Apack[ks][frow][lane][8] ----------------
__global__ __launch_bounds__(256) void pack_stem(const float* __restrict__ w2,
                                                 unsigned short* __restrict__ Apack) {
  int gid = blockIdx.x * 256 + threadIdx.x;
  if (gid >= 6 * 16 * 64) return;
  int ks = gid >> 10;
  int frow = (gid >> 6) & 15;
  int lane = gid & 63;
  int o = frow * 16 + (lane & 15);
  int tap = ks >> 1;
  int ib = ((ks & 1) << 5) + ((lane >> 4) << 3);
#pragma unroll
  for (int e = 0; e < 8; e++) {
    int i = ib + e;
    Apack[(size_t)gid * 8 + e] = f2bf(w2[((size_t)o * 64 + i) * 3 + tap]);
  }
}

// ---------------- stem conv1: 4 -> 64, k=3, pad 1 (bf16 out) ----------------
__global__ __launch_bounds__(256) void conv1_kernel(const float* __restrict__ x,
                                                    const float* __restrict__ w,
                                                    const float* __restrict__ bias,
                                                    unsigned short* __restrict__ out) {
  int idx = blockIdx.x * 256 + threadIdx.x;
  int l = idx & 4095;
  int c = (idx >> 12) & 63;
  int b = idx >> 18;
  const float* xb = x + (size_t)b * 4 * L4;
  const float* wc = w + c * 12;
  float acc = bias[c];
#pragma unroll
  for (int i = 0; i < 4; i++) {
    float x0 = (l > 0) ? xb[i * L4 + l - 1] : 0.f;
    float x1 = xb[i * L4 + l];
    float x2 = (l < 4095) ? xb[i * L4 + l + 1] : 0.f;
    acc += wc[i * 3] * x0 + wc[i * 3 + 1] * x1 + wc[i * 3 + 2] * x2;
  }
  out[idx] = f2bf(acc);
}

// ---------------- mean/rstd stats (stem only), fp32 ----------------
__global__ __launch_bounds__(256) void stats_kernel(const float* __restrict__ in,
                                                    float* __restrict__ stats,
                                                    int unit_stride, int nrow,
                                                    int row_stride, int rowlen,
                                                    float inv_n) {
  int u = blockIdx.x;
  const float* base = in + (size_t)u * unit_stride;
  float s = 0.f, s2 = 0.f;
  for (int r = 0; r < nrow; r++) {
    const float* rowp = base + (size_t)r * row_stride;
    for (int j = threadIdx.x * 4; j < rowlen; j += 256 * 4) {
      float4 v = *(const float4*)(rowp + j);
      s += v.x + v.y + v.z + v.w;
      s2 += v.x * v.x + v.y * v.y + v.z * v.z + v.w * v.w;
    }
  }
  __shared__ float sh[512];
  sh[threadIdx.x] = s;
  sh[256 + threadIdx.x] = s2;
  __syncthreads();
  for (int off = 128; off > 0; off >>= 1) {
    if (threadIdx.x < off) {
      sh[threadIdx.x] += sh[threadIdx.x + off];
      sh[256 + threadIdx.x] += sh[256 + threadIdx.x + off];
    }
    __syncthreads();
  }
  if (threadIdx.x == 0) {
    float m = sh[0] * inv_n;
    float var = sh[256] * inv_n - m * m;
    stats[u * 2] = m;
    stats[u * 2 + 1] = rsqrtf(var + 1e-5f);
  }
}

// ---------------- mean/rstd stats (stem only), bf16 ----------------
__global__ __launch_bounds__(256) void stats_bf16_kernel(const unsigned short* __restrict__ in,
                                                         float* __restrict__ stats,
                                                         int unit_stride, int nrow,
                                                         int row_stride, int rowlen,
                                                         float inv_n) {
  int u = blockIdx.x;
  const unsigned short* base = in + (size_t)u * unit_stride;
  float s = 0.f, s2 = 0.f;
  for (int r = 0; r < nrow; r++) {
    const unsigned short* rowp = base + (size_t)r * row_stride;
    for (int j = threadIdx.x * 4; j < rowlen; j += 256 * 4) {
      ushort4 v = *(const ushort4*)(rowp + j);
      float va = bf2f(v.x), vb = bf2f(v.y), vc = bf2f(v.z), vd = bf2f(v.w);
      s += va + vb + vc + vd;
      s2 += va * va + vb * vb + vc * vc + vd * vd;
    }
  }
  __shared__ float sh[512];
  sh[threadIdx.x] = s;
  sh[256 + threadIdx.x] = s2;
  __syncthreads();
  for (int off = 128; off > 0; off >>= 1) {
    if (threadIdx.x < off) {
      sh[threadIdx.x] += sh[threadIdx.x + off];
      sh[256 + threadIdx.x] += sh[256 + threadIdx.x + off];
    }
    __syncthreads();
  }
  if (threadIdx.x == 0) {
    float m = sh[0] * inv_n;
    float var = sh[256] * inv_n - m * m;
    stats[u * 2] = m;
    stats[u * 2 + 1] = rsqrtf(var + 1e-5f);
  }
}

// ---------------- stem: BN1-affine + relu + bf16 + transpose to padded XT64 ----------------
__global__ __launch_bounds__(256) void act_transpose64(const unsigned short* __restrict__ inv,
                                                       const float* __restrict__ stats,
                                                       const float* __restrict__ gamma,
                                                       const float* __restrict__ beta,
                                                       unsigned short* __restrict__ Xt) {
  constexpr int C = 64;
  __shared__ unsigned short tile[64 * C];
  int bidx = blockIdx.x;
  int b = bidx >> 6;
  int lt = bidx & 63;
  int l0 = lt << 6;
  int t = threadIdx.x;
  int lanel = t & 63;
  int cq = t >> 6;
  for (int cp = 0; cp < C / 4; cp++) {
    int c = cp * 4 + cq;
    float m = stats[2 * c], rs = stats[2 * c + 1];
    float ga = gamma[c] * rs, be = beta[c] - m * ga;
    size_t gidx = ((size_t)b * C + c) * 4096 + l0 + lanel;
    float v = bf2f(inv[gidx]);
    float a = v * ga + be;
    float r = fmaxf(a, 0.f);
    int sw = (lanel & 15) << 2;
    tile[lanel * C + (c ^ sw)] = f2bf(r);
  }
  __syncthreads();
  constexpr int CH = C / 4;
  constexpr int RPP = 256 / CH;
  for (int p = 0; p < 64 / RPP; p++) {
    int r = p * RPP + t / CH;
    int ch = t % CH;
    int sw = (r & 15) << 2;
    ushort4 v = *(const ushort4*)&tile[r * C + ((ch * 4) ^ sw)];
    *(ushort4*)&Xt[((size_t)b * 4098 + 1 + l0 + r) * C + ch * 4] = v;
  }
  if (lt == 0) {
    if (t < C / 4) *(ushort4*)&Xt[((size_t)b * 4098 + 0) * C + t * 4] = make_ushort4(0, 0, 0, 0);
  } else if (lt == 63) {
    if (t < C / 4) *(ushort4*)&Xt[((size_t)b * 4098 + 4097) * C + t * 4] = make_ushort4(0, 0, 0, 0);
  }
}

// ---------------- fused MFMA conv-GEMM --------------------------------------------------
// Tile 256o x 128l, 512 thr (8 waves, wave = 32o x 128l = 2fo x 8fc). grid = 16b*32lt = 512.
// 2 blocks/CU co-resident (LDS ~67KB). Per ks: 2 A-loads (L2) feed 16 MFMAs.
template <int NKS, int KLG, int CIN, int NORM, int ACT, int NCH, bool INBF, bool TCH, int OUT>
__global__ __launch_bounds__(512, 2) void gemm_T(const void* __restrict__ Bsrc,
                                                 const unsigned short* __restrict__ Apack,
                                                 const float* __restrict__ Pin,
                                                 const float* __restrict__ gng,
                                                 const float* __restrict__ gnb,
                                                 const float* __restrict__ Tpack,
                                                 const float* __restrict__ bias,
                                                 float tval,
                                                 void* __restrict__ outv,
                                                 float* __restrict__ Pout) {
  constexpr int CPR = CIN / 8;
  constexpr int CPRLG = (CIN == 256) ? 5 : 3;
  constexpr int ROWS = 130;
  constexpr int RPI = 512 >> CPRLG;   // rows per staging iteration (16 or 64; both %8==0)
  constexpr int TOT = ROWS * CPR;
  __shared__ unsigned short bsm[ROWS * CIN];
  __shared__ float gsm[32][2];
  __shared__ float ebias[256];
  __shared__ float psh[32][2];

  int tid = threadIdx.x;
  int lane = tid & 63;
  int wv = tid >> 6;
  int b = blockIdx.x >> 5;
  int lt = blockIdx.x & 31;
  int l_base = lt << 7;
  int wo0 = wv << 5;
  int col = lane & 15;
  int grp = lane >> 4;

  // ---- phase 0: parallel GN-stat reduce + ebias precompute ----
  if (NORM) {
    int g = tid >> 4, j0 = tid & 15;
    const float* Pg = Pin + ((size_t)b * 32 + g) * 128;
    float s = 0.f, s2 = 0.f;
    for (int j = j0; j < NCH; j += 16) { s += Pg[j * 2]; s2 += Pg[j * 2 + 1]; }
#pragma unroll
    for (int off = 8; off; off >>= 1) { s += __shfl_down(s, off, 16); s2 += __shfl_down(s2, off, 16); }
    if (j0 == 0) {
      float m = s * (1.f / 32768.f);
      float var = s2 * (1.f / 32768.f) - m * m;
      gsm[g][0] = m;
      gsm[g][1] = rsqrtf(var + 1e-5f);
    }
  }
  if (tid < 256) {
    float e = bias[tid];
    if (TCH) e += tval * (Tpack[tid] + Tpack[256 + tid] + Tpack[512 + tid]);
    ebias[tid] = e;
  }
  if (OUT == 0 && tid >= 256 && tid < 288) { psh[tid - 256][0] = 0.f; psh[tid - 256][1] = 0.f; }
  __syncthreads();

  // ---- phase 1: stage B tile; linear LDS writes, source pre-swizzled ----
  {
    int pl = tid & (CPR - 1);
    int row0 = tid >> CPRLG;
    int gch = pl ^ (row0 & 7);        // fixed global channel-chunk for this lane
    float ga[8], be[8];
    if (NORM) {
      float m = gsm[gch][0], rs = gsm[gch][1];
      float4 g0 = *(const float4*)&gng[gch * 8];
      float4 g1 = *(const float4*)&gng[gch * 8 + 4];
      float4 b0 = *(const float4*)&gnb[gch * 8];
      float4 b1 = *(const float4*)&gnb[gch * 8 + 4];
      ga[0] = g0.x * rs; ga[1] = g0.y * rs; ga[2] = g0.z * rs; ga[3] = g0.w * rs;
      ga[4] = g1.x * rs; ga[5] = g1.y * rs; ga[6] = g1.z * rs; ga[7] = g1.w * rs;
      be[0] = b0.x - m * ga[0]; be[1] = b0.y - m * ga[1];
      be[2] = b0.z - m * ga[2]; be[3] = b0.w - m * ga[3];
      be[4] = b1.x - m * ga[4]; be[5] = b1.y - m * ga[5];
      be[6] = b1.z - m * ga[6]; be[7] = b1.w - m * ga[7];
    }
#pragma unroll
    for (int it = 0; it < (TOT + 511) / 512; it++) {
      int chunk = it * 512 + tid;
      if (chunk < TOT) {
        int row = row0 + it * RPI;
        uint4 w4;
        if (NORM) {
          int gl = l_base - 1 + row;
          if (gl >= 0 && gl < 4096) {
            size_t base = ((size_t)b * 4096 + gl) * CIN + gch * 8;
            float vv[8];
            if (INBF) {
              bf16x8 raw = *(const bf16x8*)((const unsigned short*)Bsrc + base);
#pragma unroll
              for (int e = 0; e < 8; e++) vv[e] = bf2f((unsigned short)raw[e]);
            } else {
              float4 r0 = *(const float4*)((const float*)Bsrc + base);
              float4 r1 = *(const float4*)((const float*)Bsrc + base + 4);
              vv[0] = r0.x; vv[1] = r0.y; vv[2] = r0.z; vv[3] = r0.w;
              vv[4] = r1.x; vv[5] = r1.y; vv[6] = r1.z; vv[7] = r1.w;
            }
            float rr[8];
#pragma unroll
            for (int e = 0; e < 8; e++) {
              float a = vv[e] * ga[e] + be[e];
              rr[e] = (ACT == 0) ? fmaxf(a, 0.f) : (a > 0.f ? a : __expf(a) - 1.f);
            }
            w4.x = pk2(rr[0], rr[1]); w4.y = pk2(rr[2], rr[3]);
            w4.z = pk2(rr[4], rr[5]); w4.w = pk2(rr[6], rr[7]);
          } else {
            w4 = make_uint4(0, 0, 0, 0);
          }
        } else {
          w4 = *(const uint4*)((const unsigned short*)Bsrc +
                               ((size_t)b * 4098 + l_base + row) * CIN + gch * 8);
        }
        *(uint4*)&bsm[(size_t)chunk * 8] = w4;   // LINEAR write
      }
    }
  }
  __syncthreads();

  // ---- phase 2: MFMA loop (2 A-loads : 16 MFMAs per ks) ----
  const unsigned short* apk = Apack + (size_t)(wv * 2) * 512 + (size_t)lane * 8;

  f32x4 acc[2][8];
#pragma unroll
  for (int i = 0; i < 2; i++)
#pragma unroll
    for (int j = 0; j < 8; j++) acc[i][j] = (f32x4){0.f, 0.f, 0.f, 0.f};

#pragma unroll
  for (int ks = 0; ks < NKS; ks++) {
    int tap = ks >> KLG;
    int cbase = (ks & ((1 << KLG) - 1)) << 2;
    int lr0 = col + tap;
    int cb = (cbase + grp) ^ (lr0 & 7);
    const unsigned short* bp = &bsm[((size_t)(lr0 << CPRLG) + cb) * 8];
    const unsigned short* ap = apk + (size_t)ks * 16 * 512;
    bf16x8 bfr[8], afr[2];
#pragma unroll
    for (int fc = 0; fc < 8; fc++) bfr[fc] = *(const bf16x8*)(bp + fc * 16 * CIN);
#pragma unroll
    for (int fo = 0; fo < 2; fo++) afr[fo] = *(const bf16x8*)(ap + fo * 512);
#pragma unroll
    for (int fo = 0; fo < 2; fo++)
#pragma unroll
      for (int fc = 0; fc < 8; fc++)
        acc[fo][fc] = __builtin_amdgcn_mfma_f32_16x16x32_bf16(afr[fo], bfr[fc], acc[fo][fc], 0, 0, 0);
  }

  // ---- epilogue ----
  float ps = 0.f, ps2 = 0.f;
#pragma unroll
  for (int fo = 0; fo < 2; fo++) {
    int o0 = wo0 + fo * 16 + grp * 4;
    float eb[4], w0c[4], w2c[4];
#pragma unroll
    for (int r = 0; r < 4; r++) { eb[r] = ebias[o0 + r]; w0c[r] = 0.f; w2c[r] = 0.f; }
    if (TCH && lt == 0) {
#pragma unroll
      for (int r = 0; r < 4; r++) w0c[r] = tval * Tpack[o0 + r];
    }
    if (TCH && lt == 31) {
#pragma unroll
      for (int r = 0; r < 4; r++) w2c[r] = tval * Tpack[512 + o0 + r];
    }
#pragma unroll
    for (int fc = 0; fc < 8; fc++) {
      int l = l_base + fc * 16 + col;
      float v[4];
#pragma unroll
      for (int r = 0; r < 4; r++) {
        v[r] = acc[fo][fc][r] + eb[r];
        if (TCH) {
          if (lt == 0) v[r] -= (l == 0) ? w0c[r] : 0.f;
          if (lt == 31) v[r] -= (l == 4095) ? w2c[r] : 0.f;
        }
        if (OUT == 0) { ps += v[r]; ps2 += v[r] * v[r]; }
      }
      if (OUT == 0) {
        uint2 pk = make_uint2(pk2(v[0], v[1]), pk2(v[2], v[3]));
        *(uint2*)((unsigned short*)outv + ((size_t)b * 4096 + l) * 256 + o0) = pk;
      } else {
#pragma unroll
        for (int r = 0; r < 4; r++)
          ((float*)outv)[((size_t)b * 256 + o0 + r) * 4096 + l] = v[r];
      }
    }
    if (OUT == 0) {
      float s = ps, s2 = ps2;
#pragma unroll
      for (int off = 8; off; off >>= 1) {
        s += __shfl_down(s, off, 16);
        s2 += __shfl_down(s2, off, 16);
      }
      if (col == 0) {
        int g = wv * 4 + fo * 2 + (grp >> 1);
        atomicAdd(&psh[g][0], s);
        atomicAdd(&psh[g][1], s2);
      }
      ps = 0.f; ps2 = 0.f;
    }
  }

  if (OUT == 0) {
    __syncthreads();
    if (tid < 32) {
      size_t pi = ((size_t)b * 32 + tid) * 128 + (size_t)lt * 2;
      Pout[pi] = psh[tid][0];
      Pout[pi + 1] = psh[tid][1];
    }
  }
}

// ---------------- stem: BN2-affine + fast-tanh, C->T transpose, y0 fp32 + P1 partials ----
__global__ __launch_bounds__(512) void bn_tanh_T(const float* __restrict__ Q,
                                                 const float* __restrict__ stats,
                                                 const float* __restrict__ gamma,
                                                 const float* __restrict__ beta,
                                                 float* __restrict__ Y,
                                                 float* __restrict__ P1) {
  int tid = threadIdx.x;
  int b = blockIdx.x >> 5;
  int seg = blockIdx.x & 31;
  int c = tid >> 1;
  float m = stats[2 * c], rs = stats[2 * c + 1];
  float ga = gamma[c] * rs, be = beta[c] - m * ga;
  __shared__ float psh[32][2];
  if (tid < 32) { psh[tid][0] = 0.f; psh[tid][1] = 0.f; }
  __syncthreads();
  float s = 0.f, s2 = 0.f;
  for (int it = 0; it < 16; it++) {
    int l4 = (tid & 1) + it * 2;
    int l0 = seg * 128 + l4 * 4;
    float4 v = *(const float4*)&Q[((size_t)b * 256 + c) * 4096 + l0];
    float r0 = fast_tanh(v.x * ga + be);
    float r1 = fast_tanh(v.y * ga + be);
    float r2 = fast_tanh(v.z * ga + be);
    float r3 = fast_tanh(v.w * ga + be);
    Y[((size_t)b * 4096 + l0 + 0) * 256 + c] = r0;
    Y[((size_t)b * 4096 + l0 + 1) * 256 + c] = r1;
    Y[((size_t)b * 4096 + l0 + 2) * 256 + c] = r2;
    Y[((size_t)b * 4096 + l0 + 3) * 256 + c] = r3;
    s += r0 + r1 + r2 + r3;
    s2 += r0 * r0 + r1 * r1 + r2 * r2 + r3 * r3;
  }
#pragma unroll
  for (int off = 8; off; off >>= 1) { s += __shfl_down(s, off, 16); s2 += __shfl_down(s2, off, 16); }
  if ((tid & 15) == 0) {
    int g = c >> 3;
    atomicAdd(&psh[g][0], s);
    atomicAdd(&psh[g][1], s2);
  }
  __syncthreads();
  if (tid < 32) {
    size_t pi = ((size_t)b * 32 + tid) * 128 + (size_t)seg * 2;
    P1[pi] = psh[tid][0];
    P1[pi + 1] = psh[tid][1];
  }
}

// ---------------- combine (T layout): GN3-affine(F) + Heun update + P1 partials ----------
template <int MODE>
__global__ __launch_bounds__(512) void combine_T(const unsigned short* __restrict__ F,
                                                 const float* __restrict__ P3,
                                                 const float* __restrict__ gng,
                                                 const float* __restrict__ gnb,
                                                 float* __restrict__ Y,
                                                 unsigned short* __restrict__ Y1,
                                                 float* __restrict__ P1) {
  __shared__ float gsm[32][2];
  __shared__ float gabe[256][2];
  __shared__ float psh[32][2];
  int tid = threadIdx.x;
  int b = blockIdx.x >> 5;
  int seg = blockIdx.x & 31;
  {
    int g = tid >> 4, j0 = tid & 15;
    const float* Pg = P3 + ((size_t)b * 32 + g) * 128;
    float s = 0.f, s2 = 0.f;
    for (int j = j0; j < 32; j += 16) { s += Pg[j * 2]; s2 += Pg[j * 2 + 1]; }
#pragma unroll
    for (int off = 8; off; off >>= 1) { s += __shfl_down(s, off, 16); s2 += __shfl_down(s2, off, 16); }
    if (j0 == 0) {
      float m = s * (1.f / 32768.f);
      float var = s2 * (1.f / 32768.f) - m * m;
      gsm[g][0] = m;
      gsm[g][1] = rsqrtf(var + 1e-5f);
    }
  }
  __syncthreads();
  if (tid < 256) {
    float m = gsm[tid >> 3][0], rs = gsm[tid >> 3][1];
    float ga = gng[tid] * rs;
    gabe[tid][0] = ga;
    gabe[tid][1] = gnb[tid] - m * ga;
  }
  if (tid >= 256 && tid < 288) { psh[tid - 256][0] = 0.f; psh[tid - 256][1] = 0.f; }
  __syncthreads();

  size_t base4 = ((size_t)b * 4096 + seg * 128) * 64;
  int c0 = (tid << 2) & 255;
  int g = c0 >> 3;
  float ga0 = gabe[c0][0], be0 = gabe[c0][1];
  float ga1 = gabe[c0 + 1][0], be1 = gabe[c0 + 1][1];
  float ga2 = gabe[c0 + 2][0], be2 = gabe[c0 + 2][1];
  float ga3 = gabe[c0 + 3][0], be3 = gabe[c0 + 3][1];
  float s = 0.f, s2 = 0.f;
  for (int i = tid; i < 8192; i += 512) {
    size_t idx4 = base4 + i;
    ushort4 fv = ((const ushort4*)F)[idx4];
    float4 yv = ((const float4*)Y)[idx4];
    float f0 = bf2f(fv.x) * ga0 + be0;
    float f1 = bf2f(fv.y) * ga1 + be1;
    float f2 = bf2f(fv.z) * ga2 + be2;
    float f3 = bf2f(fv.w) * ga3 + be3;
    float4 yn;
    yn.x = yv.x + (MODE == 0 ? 0.125f : 0.0625f) * f0;
    yn.y = yv.y + (MODE == 0 ? 0.125f : 0.0625f) * f1;
    yn.z = yv.z + (MODE == 0 ? 0.125f : 0.0625f) * f2;
    yn.w = yv.w + (MODE == 0 ? 0.125f : 0.0625f) * f3;
    if (MODE == 0) {
      float4 yb;
      yb.x = yv.x + 0.0625f * f0;
      yb.y = yv.y + 0.0625f * f1;
      yb.z = yv.z + 0.0625f * f2;
      yb.w = yv.w + 0.0625f * f3;
      ((float4*)Y)[idx4] = yb;
    }
    if (MODE == 2) {
      ((float4*)Y)[idx4] = yn;
    } else {
      uint2 pk = make_uint2(pk2(yn.x, yn.y), pk2(yn.z, yn.w));
      ((uint2*)Y1)[idx4] = pk;
    }
    s += yn.x + yn.y + yn.z + yn.w;
    s2 += yn.x * yn.x + yn.y * yn.y + yn.z * yn.z + yn.w * yn.w;
  }
  s += __shfl_xor(s, 1);
  s2 += __shfl_xor(s2, 1);
  if ((tid & 1) == 0) {
    atomicAdd(&psh[g][0], s);
    atomicAdd(&psh[g][1], s2);
  }
  __syncthreads();
  if (tid < 32) {
    size_t pi = ((size_t)b * 32 + tid) * 128 + (size_t)seg * 2;
    P1[pi] = psh[tid][0];
    P1[pi + 1] = psh[tid][1];
  }
}

// ---------------- final: T-layout fp32 -> C-layout fp32 (d_out) ----------------
__global__ __launch_bounds__(256) void transpose_final(const float* __restrict__ Y,
                                                       float* __restrict__ out) {
  __shared__ float tile[64 * 260];
  int b = blockIdx.x >> 6;
  int lt = blockIdx.x & 63;
  int t = threadIdx.x;
  for (int i = t; i < 4096; i += 256) {
    int r = i >> 6;
    int c4 = (i & 63) << 2;
    float4 v = *(const float4*)&Y[((size_t)b * 4096 + lt * 64 + r) * 256 + c4];
    *(float4*)&tile[r * 260 + c4] = v;
  }
  __syncthreads();
  for (int i = t; i < 4096; i += 256) {
    int c = i >> 4;
    int l4 = (i & 15) << 2;
    float4 v;
    v.x = tile[(l4 + 0) * 260 + c];
    v.y = tile[(l4 + 1) * 260 + c];
    v.z = tile[(l4 + 2) * 260 + c];
    v.w = tile[(l4 + 3) * 260 + c];
    *(float4*)&out[((size_t)b * 256 + c) * 4096 + lt * 64 + l4] = v;
  }
}

extern "C" void kernel_launch(void* const* d_in, const int* in_sizes, int n_in,
                              void* d_out, int out_size, void* d_ws, size_t ws_size,
                              hipStream_t stream) {
  const float* x = (const float*)d_in[0];
  const float* w1 = (const float*)d_in[1];
  const float* b1 = (const float*)d_in[2];
  const float* bn1_g = (const float*)d_in[3];
  const float* bn1_b = (const float*)d_in[4];
  const float* w2 = (const float*)d_in[5];
  const float* b2 = (const float*)d_in[6];
  const float* bn2_g = (const float*)d_in[7];
  const float* bn2_b = (const float*)d_in[8];
  const float* cw1 = (const float*)d_in[9];
  const float* cb1 = (const float*)d_in[10];
  const float* gn1_g = (const float*)d_in[11];
  const float* gn1_b = (const float*)d_in[12];
  const float* gn2_g = (const float*)d_in[13];
  const float* gn2_b = (const float*)d_in[14];
  const float* cw2 = (const float*)d_in[15];
  const float* cb2 = (const float*)d_in[16];
  const float* gn3_g = (const float*)d_in[17];
  const float* gn3_b = (const float*)d_in[18];

  const size_t SZ = (size_t)16 * 256 * 4096;

  char* p = (char*)d_ws;
  float* Ybuf = (float*)p;                   p += SZ * 4;
  unsigned short* C1 = (unsigned short*)p;   p += SZ * 2;
  unsigned short* Fb = (unsigned short*)p;   p += SZ * 2;
  unsigned short* APK1 = (unsigned short*)p; p += (size_t)24 * 16 * 64 * 8 * 2;
  unsigned short* APK2 = (unsigned short*)p; p += (size_t)24 * 16 * 64 * 8 * 2;
  unsigned short* APKS = (unsigned short*)p; p += (size_t)6 * 16 * 64 * 8 * 2;
  float* TP1 = (float*)p;                    p += 768 * 4;
  float* TP2 = (float*)p;                    p += 768 * 4;
  float* STATS = (float*)p;                  p += 1024 * 4;
  float* P1 = (float*)p;                     p += (size_t)16 * 32 * 128 * 4;
  float* P2 = (float*)p;                     p += (size_t)16 * 32 * 128 * 4;
  float* P3 = (float*)p;                     p += (size_t)16 * 32 * 128 * 4;

  float* Q = (float*)d_out;
  unsigned short* Y1 = (unsigned short*)d_out;

  // ---- weight packing ----
  pack_big<<<96, 256, 0, stream>>>(cw1, APK1, TP1);
  pack_big<<<96, 256, 0, stream>>>(cw2, APK2, TP2);
  pack_stem<<<24, 256, 0, stream>>>(w2, APKS);

  // ---- stem ----
  conv1_kernel<<<16384, 256, 0, stream>>>(x, w1, b1, C1);
  stats_bf16_kernel<<<64, 256, 0, stream>>>(C1, STATS, 4096, 16, 64 * 4096, 4096, 1.f / 65536.f);
  act_transpose64<<<1024, 256, 0, stream>>>(C1, STATS, bn1_g, bn1_b, Fb);
  gemm_T<6, 1, 64, 0, 0, 32, true, false, 1><<<512, 512, 0, stream>>>(
      Fb, APKS, nullptr, nullptr, nullptr, nullptr, b2, 0.f, Q, nullptr);
  stats_kernel<<<256, 256, 0, stream>>>(Q, STATS, 4096, 16, 256 * 4096, 4096, 1.f / 65536.f);
  bn_tanh_T<<<512, 512, 0, stream>>>(Q, STATS, bn2_g, bn2_b, Ybuf, P1);

  // ---- ODE: 8 steps (pred + 2 corr), all in T layout; state fixed in Ybuf ----
  const float H = 0.125f;
  for (int i = 0; i < 8; i++) {
    float t = i * H;
    gemm_T<24, 3, 256, 1, 0, 32, false, true, 0><<<512, 512, 0, stream>>>(
        Ybuf, APK1, P1, gn1_g, gn1_b, TP1, cb1, t, C1, P2);
    gemm_T<24, 3, 256, 1, 1, 32, true, true, 0><<<512, 512, 0, stream>>>(
        C1, APK2, P2, gn2_g, gn2_b, TP2, cb2, t, Fb, P3);
    combine_T<0><<<512, 512, 0, stream>>>(Fb, P3, gn3_g, gn3_b, Ybuf, Y1, P1);
    for (int c = 0; c < 2; c++) {
      gemm_T<24, 3, 256, 1, 0, 32, true, true, 0><<<512, 512, 0, stream>>>(
          Y1, APK1, P1, gn1_g, gn1_b, TP1, cb1, t + H, C1, P2);
      gemm_T<24, 3, 256, 1, 1, 32, true, true, 0><<<512, 512, 0, stream>>>(
          C1, APK2, P2, gn2_g, gn2_b, TP2, cb2, t + H, Fb, P3);
      if (c == 0)
        combine_T<1><<<512, 512, 0, stream>>>(Fb, P3, gn3_g, gn3_b, Ybuf, Y1, P1);
      else
        combine_T<2><<<512, 512, 0, stream>>>(Fb, P3, gn3_g, gn3_b, Ybuf, Y1, P1);
    }
  }

  // ---- final: transpose T state -> d_out C layout ----
  transpose_final<<<1024, 256, 0, stream>>>(Ybuf, (float*)d_out);
}